// Round 2
// baseline (1343.603 us; speedup 1.0000x reference)
//
#include <hip/hip_runtime.h>

using u16 = unsigned short;

static constexpr int NPIX = 4096;                    // 64*64
static constexpr float BN_SC = 0.9999950000374997f;  // 1/sqrt(1+1e-5)
static constexpr float ATT_EPS = 1e-15f;

__device__ __forceinline__ float b2f(u16 u) {
  union { unsigned int i; float f; } v; v.i = ((unsigned int)u) << 16; return v.f;
}
__device__ __forceinline__ u16 f2b(float f) {
  union { float f; unsigned int i; } v; v.f = f;
  unsigned int r = v.i + 0x7FFFu + ((v.i >> 16) & 1u);   // RNE
  return (u16)(r >> 16);
}
__device__ __forceinline__ float hswish_f(float v) {
  return v * fminf(fmaxf(v + 3.0f, 0.0f), 6.0f) * (1.0f / 6.0f);
}

__device__ __forceinline__ float4 load4v(const float* p) { return *(const float4*)p; }
__device__ __forceinline__ float4 load4v(const u16* p) {
  ushort4 u = *(const ushort4*)p;
  return make_float4(b2f(u.x), b2f(u.y), b2f(u.z), b2f(u.w));
}
__device__ __forceinline__ float loadElem(const float* p) { return *p; }
__device__ __forceinline__ float loadElem(const u16* p) { return b2f(*p); }
__device__ __forceinline__ void store8(float* p, const float* v) {
  *(float4*)p = *(const float4*)&v[0];
  *(float4*)(p + 4) = *(const float4*)&v[4];
}
__device__ __forceinline__ void store8(u16* p, const float* v) {
  ushort4 a, b;
  a.x = f2b(v[0]); a.y = f2b(v[1]); a.z = f2b(v[2]); a.w = f2b(v[3]);
  b.x = f2b(v[4]); b.y = f2b(v[5]); b.z = f2b(v[6]); b.w = f2b(v[7]);
  *(ushort4*)p = a;
  *(ushort4*)(p + 4) = b;
}

// ---------------- weight transpose: Wt[i][o] = W[o][i] (f32) ----------------
__global__ void transpose_kernel(const float* __restrict__ W, float* __restrict__ Wt,
                                 int O, int I) {
  int idx = blockIdx.x * 256 + threadIdx.x;
  if (idx < O * I) {
    int o = idx / I, i = idx - o * I;
    Wt[i * O + o] = W[idx];
  }
}

// ---------------- GEMM: Y[b][m][n] = sum_k Wt[k][m] * X[b][k][n] ----------------
// EPI 0: none   EPI 1: BN+residual   EPI 2: bias+hswish
template<int EPI, typename TIN, typename TOUT, typename TRES>
__global__ __launch_bounds__(256)
void gemm_kernel(const float* __restrict__ Wt, const TIN* __restrict__ X,
                 TOUT* __restrict__ Y, int M, int K,
                 const float* __restrict__ p0, const float* __restrict__ p1,
                 const TRES* __restrict__ res)
{
  constexpr int TK = 16;
  __shared__ float la[TK][128];
  __shared__ float lb[TK][128];
  const int b = blockIdx.z;
  const TIN* Xb = X + (size_t)b * K * NPIX;
  const int m0 = blockIdx.y * 128;
  const int n0 = blockIdx.x * 128;
  const int tid = threadIdx.x;
  const int tx = tid & 15, ty = tid >> 4;
  const int lrow = tid >> 5;           // 0..7
  const int lcol = (tid & 31) << 2;    // 0..124 step 4
  float acc[8][8] = {};
  for (int k0 = 0; k0 < K; k0 += TK) {
    *(float4*)&la[lrow][lcol]     = *(const float4*)&Wt[(size_t)(k0 + lrow) * M + m0 + lcol];
    *(float4*)&la[lrow + 8][lcol] = *(const float4*)&Wt[(size_t)(k0 + lrow + 8) * M + m0 + lcol];
    *(float4*)&lb[lrow][lcol]     = load4v(&Xb[(size_t)(k0 + lrow) * NPIX + n0 + lcol]);
    *(float4*)&lb[lrow + 8][lcol] = load4v(&Xb[(size_t)(k0 + lrow + 8) * NPIX + n0 + lcol]);
    __syncthreads();
#pragma unroll
    for (int kk = 0; kk < TK; ++kk) {
      float a[8], bb[8];
      *(float4*)&a[0]  = *(float4*)&la[kk][ty * 8];
      *(float4*)&a[4]  = *(float4*)&la[kk][ty * 8 + 4];
      *(float4*)&bb[0] = *(float4*)&lb[kk][tx * 8];
      *(float4*)&bb[4] = *(float4*)&lb[kk][tx * 8 + 4];
#pragma unroll
      for (int i = 0; i < 8; ++i)
#pragma unroll
        for (int j = 0; j < 8; ++j)
          acc[i][j] = fmaf(a[i], bb[j], acc[i][j]);
    }
    __syncthreads();
  }
  TOUT* Yb = Y + (size_t)b * M * NPIX;
  const TRES* Rb = (EPI == 1) ? (res + (size_t)b * M * NPIX) : nullptr;
#pragma unroll
  for (int i = 0; i < 8; ++i) {
    const int m = m0 + ty * 8 + i;
    float alpha = 1.0f, bet = 0.0f;
    if (EPI == 1) { alpha = p0[m] * BN_SC; bet = p1[m]; }
    if (EPI == 2) { bet = p0[m]; }
    const size_t off = (size_t)m * NPIX + n0 + tx * 8;
    float v[8];
#pragma unroll
    for (int j = 0; j < 8; ++j) {
      float t = acc[i][j];
      if (EPI == 1) t = alpha * t + bet + loadElem(&Rb[off + j]);
      if (EPI == 2) t = hswish_f(t + bet);
      v[j] = t;
    }
    store8(&Yb[off], v);
  }
}

// ---------------- fused dwconv5x5 (pad 2) + per-group 32x32 pointwise ----------------
// grid (16 pixel-tiles, 24 groups, nb) ; block 256
__global__ __launch_bounds__(256)
void dw5pw_kernel(const u16* __restrict__ qkv, const float* __restrict__ W_dw5,
                  const float* __restrict__ W_pw, u16* __restrict__ ag) {
  const int g = blockIdx.y, b = blockIdx.z;
  __shared__ float sW5[32 * 25];
  __shared__ float sPwT[32 * 32];   // [d][e]
  const int tid = threadIdx.x;
  for (int i = tid; i < 800; i += 256) sW5[i] = W_dw5[g * 800 + i];
  for (int i = tid; i < 1024; i += 256) {
    int d = i & 31, e = i >> 5;
    sPwT[d * 32 + e] = W_pw[g * 1024 + i];
  }
  __syncthreads();
  const int n = blockIdx.x * 256 + tid;
  const int row = n >> 6, col = n & 63;
  const u16* inb = qkv + ((size_t)(b * 768 + g * 32)) * NPIX;
  float acc[32] = {};
  for (int c = 0; c < 32; ++c) {
    const float* wc = &sW5[c * 25];
    const u16* ip = inb + (size_t)c * NPIX;
    float s = 0.0f;
#pragma unroll
    for (int ky = 0; ky < 5; ++ky) {
      int hh = row + ky - 2;
      if (hh < 0 || hh > 63) continue;
#pragma unroll
      for (int kx = 0; kx < 5; ++kx) {
        int ww = col + kx - 2;
        if (ww < 0 || ww > 63) continue;
        s += wc[ky * 5 + kx] * b2f(ip[hh * 64 + ww]);
      }
    }
#pragma unroll
    for (int e = 0; e < 32; ++e) acc[e] += sPwT[c * 32 + e] * s;
  }
  u16* ob = ag + ((size_t)(b * 768 + g * 32)) * NPIX + n;
#pragma unroll
  for (int e = 0; e < 32; ++e) ob[(size_t)e * NPIX] = f2b(acc[e]);
}

// ---------------- depthwise 3x3, pad 1 (1024 ch), bias + hswish, bf16 ----------------
__global__ void dw3_kernel(const u16* __restrict__ in, const float* __restrict__ w3,
                           const float* __restrict__ bias, u16* __restrict__ out) {
  size_t idx = (size_t)blockIdx.x * 256 + threadIdx.x;
  int wq = (int)(idx & 63), hq = (int)((idx >> 6) & 63);
  size_t bc = idx >> 12;
  int c = (int)(bc & 1023);
  const u16* ip = in + (bc << 12);
  const float* wc = w3 + c * 9;
  float s = bias[c];
#pragma unroll
  for (int ky = 0; ky < 3; ++ky) {
    int hh = hq + ky - 1;
    if (hh < 0 || hh > 63) continue;
#pragma unroll
    for (int kx = 0; kx < 3; ++kx) {
      int ww = wq + kx - 1;
      if (ww < 0 || ww > 63) continue;
      s += wc[ky * 3 + kx] * b2f(ip[hh * 64 + ww]);
    }
  }
  out[idx] = f2b(hswish_f(s));
}

// ---------------- attention stage 1: vk[b][h][33][32] ----------------
__global__ __launch_bounds__(256)
void vk_kernel(const u16* __restrict__ qkv, const u16* __restrict__ ag,
               float* __restrict__ vk) {
  const int chunk = blockIdx.x, h = blockIdx.y, b = blockIdx.z;
  const u16* base = (h < 8) ? (qkv + ((size_t)(b * 768 + h * 96)) * NPIX)
                            : (ag + ((size_t)(b * 768 + (h - 8) * 96)) * NPIX);
  const u16* kbase = base + (size_t)32 * NPIX;
  const u16* vbase = base + (size_t)64 * NPIX;
  __shared__ float sk[32][65];
  __shared__ float sv[32][65];
  const int tid = threadIdx.x;
  const int col = tid & 63;
  const int e = tid & 31, dg = tid >> 5;   // e 0..31, dg 0..7
  float acc[4] = {};
  float acc32 = 0.0f;
  for (int c0 = 0; c0 < 512; c0 += 64) {
    const int ncol = chunk * 512 + c0;
    __syncthreads();
    for (int i = 0, r = tid >> 6; i < 8; ++i, r += 4) {
      sk[r][col] = fmaxf(b2f(kbase[(size_t)r * NPIX + ncol + col]), 0.0f);
      sv[r][col] = b2f(vbase[(size_t)r * NPIX + ncol + col]);
    }
    __syncthreads();
    for (int nn = 0; nn < 64; ++nn) {
      float kv = sk[e][nn];
#pragma unroll
      for (int j = 0; j < 4; ++j) acc[j] += sv[dg * 4 + j][nn] * kv;
      acc32 += kv;
    }
  }
  float* vkbh = vk + ((size_t)(b * 16 + h)) * 33 * 32;
#pragma unroll
  for (int j = 0; j < 4; ++j) atomicAdd(&vkbh[(dg * 4 + j) * 32 + e], acc[j]);
  if (dg == 0) atomicAdd(&vkbh[32 * 32 + e], acc32);
}

// ---------------- attention stage 2 ----------------
__global__ __launch_bounds__(256)
void att_kernel(const u16* __restrict__ qkv, const u16* __restrict__ ag,
                const float* __restrict__ vk, u16* __restrict__ att) {
  const int nblk = blockIdx.x, h = blockIdx.y, b = blockIdx.z;
  const u16* base = (h < 8) ? (qkv + ((size_t)(b * 768 + h * 96)) * NPIX)
                            : (ag + ((size_t)(b * 768 + (h - 8) * 96)) * NPIX);
  __shared__ float sq[32][64];
  __shared__ float svk[33 * 32];
  __shared__ float sden[64];
  const int tid = threadIdx.x;
  const int col = tid & 63;
  for (int i = 0, r = tid >> 6; i < 8; ++i, r += 4)
    sq[r][col] = fmaxf(b2f(base[(size_t)r * NPIX + nblk * 64 + col]), 0.0f);
  const float* vkbh = vk + ((size_t)(b * 16 + h)) * 33 * 32;
  for (int i = tid; i < 33 * 32; i += 256) svk[i] = vkbh[i];
  __syncthreads();
  const int n = tid & 63, dg = tid >> 6;   // dg 0..3
  float acc[8] = {};
  float den = 0.0f;
  for (int ee = 0; ee < 32; ++ee) {
    float qv = sq[ee][n];
#pragma unroll
    for (int j = 0; j < 8; ++j) acc[j] += svk[(dg * 8 + j) * 32 + ee] * qv;
    if (dg == 3) den += svk[32 * 32 + ee] * qv;
  }
  if (dg == 3) sden[n] = den;
  __syncthreads();
  const float inv = 1.0f / (sden[n] + ATT_EPS);
  u16* ob = att + ((size_t)(b * 512 + h * 32)) * NPIX + nblk * 64 + n;
#pragma unroll
  for (int j = 0; j < 8; ++j)
    ob[(size_t)(dg * 8 + j) * NPIX] = f2b(acc[j] * inv);
}

// ---------------- launch ----------------
extern "C" void kernel_launch(void* const* d_in, const int* in_sizes, int n_in,
                              void* d_out, int out_size, void* d_ws, size_t ws_size,
                              hipStream_t stream) {
  const float* x      = (const float*)d_in[0];
  const float* W_qkv  = (const float*)d_in[1];
  const float* W_dw5  = (const float*)d_in[2];
  const float* W_pw   = (const float*)d_in[3];
  const float* W_proj = (const float*)d_in[4];
  const float* g_proj = (const float*)d_in[5];
  const float* b_proj = (const float*)d_in[6];
  const float* W_e    = (const float*)d_in[7];
  const float* b_e    = (const float*)d_in[8];
  const float* W_dw3  = (const float*)d_in[9];
  const float* b_dw3  = (const float*)d_in[10];
  const float* W_p    = (const float*)d_in[11];
  const float* g_p    = (const float*)d_in[12];
  const float* b_p    = (const float*)d_in[13];
  float* out = (float*)d_out;

  // ---- workspace plan (adaptive to ws_size) ----
  // weights f32 @ 0: wqkvT 196608 | wprojT 131072 | weT 262144 | wpT 262144  = 851,968 floats
  // vk f32: nb*16896 floats
  // bf16 arena: per-image 9,437,184 u16 = 18,874,368 B, with liveness aliasing:
  //   qkv @0 (3145728nb) | ag @3145728nb | att @6291456nb | y @8388608nb..9437184nb
  //   e  @0 (4194304nb, over dead qkv+ag)  | d @4194304nb (over dead ag-tail+att)
  int nb = 8;
  while (nb > 1 && (size_t)3407872 + (size_t)nb * 18941952 > ws_size) nb >>= 1;

  float* wqkvT  = (float*)d_ws;
  float* wprojT = wqkvT + 196608;
  float* weT    = wprojT + 131072;
  float* wpT    = weT + 262144;
  float* vkbuf  = wpT + 262144;                       // nb*16896 floats
  u16*   arena  = (u16*)(vkbuf + (size_t)nb * 16896);

  u16* qkv_u = arena;
  u16* ag_u  = arena + (size_t)3145728 * nb;
  u16* att_u = arena + (size_t)6291456 * nb;
  u16* y_u   = arena + (size_t)8388608 * nb;
  u16* e_u   = arena;
  u16* d_u   = arena + (size_t)4194304 * nb;

  transpose_kernel<<<(768 * 256 + 255) / 256, 256, 0, stream>>>(W_qkv, wqkvT, 768, 256);
  transpose_kernel<<<(256 * 512 + 255) / 256, 256, 0, stream>>>(W_proj, wprojT, 256, 512);
  transpose_kernel<<<(1024 * 256 + 255) / 256, 256, 0, stream>>>(W_e, weT, 1024, 256);
  transpose_kernel<<<(256 * 1024 + 255) / 256, 256, 0, stream>>>(W_p, wpT, 256, 1024);

  for (int b0 = 0; b0 < 8; b0 += nb) {
    const float* x_c = x + (size_t)b0 * 256 * NPIX;
    float* out_c = out + (size_t)b0 * 256 * NPIX;

    // qkv = W_qkv @ x   (f32 in, bf16 out)
    gemm_kernel<0, float, u16, float><<<dim3(32, 6, nb), 256, 0, stream>>>(
        wqkvT, x_c, qkv_u, 768, 256, nullptr, nullptr, nullptr);
    // ag = pw(dw5(qkv))
    dw5pw_kernel<<<dim3(16, 24, nb), 256, 0, stream>>>(qkv_u, W_dw5, W_pw, ag_u);
    // attention
    hipMemsetAsync(vkbuf, 0, (size_t)nb * 16896 * sizeof(float), stream);
    vk_kernel<<<dim3(8, 16, nb), 256, 0, stream>>>(qkv_u, ag_u, vkbuf);
    att_kernel<<<dim3(64, 16, nb), 256, 0, stream>>>(qkv_u, ag_u, vkbuf, att_u);
    // y = BN(W_proj @ att) + x
    gemm_kernel<1, u16, u16, float><<<dim3(32, 2, nb), 256, 0, stream>>>(
        wprojT, att_u, y_u, 256, 512, g_proj, b_proj, x_c);
    // e = hswish(W_e @ y + b_e)
    gemm_kernel<2, u16, u16, float><<<dim3(32, 8, nb), 256, 0, stream>>>(
        weT, y_u, e_u, 1024, 256, b_e, nullptr, nullptr);
    // d = hswish(dw3(e) + b_dw3)
    dw3_kernel<<<nb * 16384, 256, 0, stream>>>(e_u, W_dw3, b_dw3, d_u);
    // out = BN(W_p @ d) + y
    gemm_kernel<1, u16, float, u16><<<dim3(32, 2, nb), 256, 0, stream>>>(
        wpT, d_u, out_c, 256, 1024, g_p, b_p, y_u);
  }
}

// Round 3
// 537.846 us; speedup vs baseline: 2.4981x; 2.4981x over previous
//
#include <hip/hip_runtime.h>

typedef __bf16 bf16;
typedef __attribute__((ext_vector_type(8))) __bf16 bf16x8;
typedef __attribute__((ext_vector_type(4))) __bf16 bf16x4;
typedef __attribute__((ext_vector_type(4))) float f32x4;

static constexpr int NPIX = 4096;                    // 64*64
static constexpr float BN_SC = 0.9999950000374997f;  // 1/sqrt(1+1e-5)
static constexpr float ATT_EPS = 1e-15f;

__device__ __forceinline__ float hswish_f(float v) {
  return v * fminf(fmaxf(v + 3.0f, 0.0f), 6.0f) * (1.0f / 6.0f);
}

__device__ __forceinline__ void gload16(const void* g, void* l) {
  __builtin_amdgcn_global_load_lds(
      (const __attribute__((address_space(1))) unsigned int*)g,
      (__attribute__((address_space(3))) unsigned int*)l, 16, 0, 0);
}

// ---------------- x (f32 NCHW) -> x_nhwc (bf16) ----------------
__global__ __launch_bounds__(256)
void x_to_nhwc(const float* __restrict__ x, bf16* __restrict__ xn) {
  __shared__ float t[32][65];
  const int img = blockIdx.z;
  const int n0 = blockIdx.x * 64, c0 = blockIdx.y * 32;
  const int tid = threadIdx.x;
  const float* xb = x + ((size_t)img * 256 + c0) * NPIX + n0;
  {
    const int col = tid & 63, r0 = tid >> 6;
#pragma unroll
    for (int i = 0; i < 8; ++i) {
      const int r = r0 + i * 4;
      t[r][col] = xb[(size_t)r * NPIX + col];
    }
  }
  __syncthreads();
  const int n = tid & 63, cq = tid >> 6;
  bf16x8 v;
#pragma unroll
  for (int j = 0; j < 8; ++j) v[j] = (bf16)t[cq * 8 + j][n];
  *(bf16x8*)(xn + ((size_t)img * NPIX + n0 + n) * 256 + c0 + cq * 8) = v;
}

// ---------------- f32 -> bf16 weight convert ----------------
__global__ void w_to_bf16(const float* __restrict__ w, bf16* __restrict__ o, int n) {
  const int i = blockIdx.x * 256 + threadIdx.x;
  if (i < n) o[i] = (bf16)w[i];
}

// ---------------- MFMA GEMM: D[m][n] = sum_k A[m][k] * B[n][k]  (both K-contig) ----
// A = weights [M][K] bf16; B = activations [img][4096][K] bf16 (NHWC)
// EPI 0: Yb[n][m] = D                      (plain bf16 NHWC)
// EPI 1: Yb[n][m] = p0*BN_SC*D + p1 + res[n][m]   (BN + residual, bf16 NHWC)
// EPI 2: Yb[n][m] = hswish(D + p0[m])      (bias + hswish, bf16 NHWC)
// EPI 3: Yf[m][n] = p0*BN_SC*D + p1 + res[n][m]   (f32 NCHW output)
template<int EPI>
__global__ __launch_bounds__(256, 2)
void mfma_gemm(const bf16* __restrict__ A, const bf16* __restrict__ Bact,
               bf16* __restrict__ Yb, float* __restrict__ Yf,
               const int M, const int K,
               const float* __restrict__ p0, const float* __restrict__ p1,
               const bf16* __restrict__ res)
{
  __shared__ __attribute__((aligned(16))) char ldsA[16384];
  __shared__ __attribute__((aligned(16))) char ldsB[16384];
  const int img = blockIdx.z;
  const int n0 = blockIdx.x * 128;
  const int m0 = blockIdx.y * 128;
  const bf16* Bi = Bact + (size_t)img * NPIX * K;
  const int tid = threadIdx.x;
  const int w = tid >> 6, l = tid & 63;
  const int g = l >> 4, ln = l & 15;
  const int wr = w >> 1, wc = w & 1;
  const int lrow = l >> 3;                       // 0..7
  const int sofs = (((l & 7) ^ lrow) << 4);      // swizzled byte offset in row

  f32x4 acc[4][4];
#pragma unroll
  for (int i = 0; i < 4; ++i)
#pragma unroll
    for (int j = 0; j < 4; ++j) acc[i][j] = (f32x4){0.f, 0.f, 0.f, 0.f};

  const char* Abase = (const char*)(A + (size_t)m0 * K);
  const char* Bbase = (const char*)(Bi + (size_t)n0 * K);
  const size_t rowb = (size_t)K * 2;
  const int swz = (ln & 7) << 4;

  const int nk = K >> 6;
  for (int kt = 0; kt < nk; ++kt) {
    const int k0b = kt << 7;   // kt*64 elems * 2B
#pragma unroll
    for (int i = 0; i < 4; ++i) {
      const int q = (w << 2) + i;
      const int r = q * 8 + lrow;
      gload16(Abase + (size_t)r * rowb + k0b + sofs, ldsA + q * 1024);
    }
#pragma unroll
    for (int i = 0; i < 4; ++i) {
      const int q = (w << 2) + i;
      const int r = q * 8 + lrow;
      gload16(Bbase + (size_t)r * rowb + k0b + sofs, ldsB + q * 1024);
    }
    __syncthreads();
#pragma unroll
    for (int kk = 0; kk < 2; ++kk) {
      bf16x8 av[4], bv[4];
#pragma unroll
      for (int f = 0; f < 4; ++f) {
        const int ra = wr * 64 + f * 16 + ln;
        const int rb = wc * 64 + f * 16 + ln;
        const int kb = kk * 64 + (g << 4);
        av[f] = *(const bf16x8*)(ldsA + ra * 128 + (kb ^ swz));
        bv[f] = *(const bf16x8*)(ldsB + rb * 128 + (kb ^ swz));
      }
#pragma unroll
      for (int fi = 0; fi < 4; ++fi)
#pragma unroll
        for (int fj = 0; fj < 4; ++fj)
          acc[fi][fj] = __builtin_amdgcn_mfma_f32_16x16x32_bf16(
              av[fi], bv[fj], acc[fi][fj], 0, 0, 0);
    }
    __syncthreads();
  }

  // epilogue: lane holds D rows m4..m4+3 (reg r), col n
#pragma unroll
  for (int fi = 0; fi < 4; ++fi) {
    const int m4 = m0 + wr * 64 + fi * 16 + g * 4;
    f32x4 P0 = {0.f, 0.f, 0.f, 0.f}, P1 = {0.f, 0.f, 0.f, 0.f};
    if (EPI == 1 || EPI == 3) { P0 = *(const f32x4*)(p0 + m4); P1 = *(const f32x4*)(p1 + m4); }
    if (EPI == 2) { P0 = *(const f32x4*)(p0 + m4); }
#pragma unroll
    for (int fj = 0; fj < 4; ++fj) {
      const int n = n0 + wc * 64 + fj * 16 + ln;
      if (EPI == 3) {
        const bf16x4 yr = *(const bf16x4*)(res + ((size_t)img * NPIX + n) * 256 + m4);
        float* op = Yf + ((size_t)img * 256 + m4) * NPIX + n;
#pragma unroll
        for (int r = 0; r < 4; ++r)
          op[(size_t)r * NPIX] = P0[r] * BN_SC * acc[fi][fj][r] + P1[r] + (float)yr[r];
      } else {
        bf16x4 sv;
        if (EPI == 0) {
#pragma unroll
          for (int r = 0; r < 4; ++r) sv[r] = (bf16)acc[fi][fj][r];
        } else if (EPI == 1) {
          const bf16x4 xr = *(const bf16x4*)(res + ((size_t)img * NPIX + n) * 256 + m4);
#pragma unroll
          for (int r = 0; r < 4; ++r)
            sv[r] = (bf16)(P0[r] * BN_SC * acc[fi][fj][r] + P1[r] + (float)xr[r]);
        } else {
#pragma unroll
          for (int r = 0; r < 4; ++r)
            sv[r] = (bf16)hswish_f(acc[fi][fj][r] + P0[r]);
        }
        *(bf16x4*)(Yb + ((size_t)img * NPIX + n) * M + m4) = sv;
      }
    }
  }
}

// ---------------- fused dw5x5 + per-group 32x32 pointwise (NHWC) ----------------
// grid (32 pixel-tiles of 128, 24 groups, nb); block 256
__global__ __launch_bounds__(256)
void dw5pw_nhwc(const bf16* __restrict__ qkv, const float* __restrict__ W5,
                const float* __restrict__ Wpw, bf16* __restrict__ ag) {
  const int g = blockIdx.y, img = blockIdx.z;
  const int n0 = blockIdx.x * 128;
  const int r0 = n0 >> 6;                       // 2 image rows per block
  __shared__ __attribute__((aligned(16))) bf16 sIn[6 * 68 * 32];
  __shared__ float sS[128 * 33];
  __shared__ float sW5[32 * 25];
  __shared__ float sPwT[32 * 32];               // [d][e]
  const int tid = threadIdx.x;
  for (int i = tid; i < 800; i += 256) sW5[i] = W5[g * 800 + i];
  for (int i = tid; i < 1024; i += 256) sPwT[(i & 31) * 32 + (i >> 5)] = Wpw[g * 1024 + i];
  for (int i = tid; i < 6 * 68; i += 256) {
    const int hr = i / 68, hc = i - hr * 68;
    const int gr = r0 + hr - 2, gc = hc - 2;
    uint4 z0 = {0, 0, 0, 0}, z1 = z0, z2 = z0, z3 = z0;
    if (gr >= 0 && gr < 64 && gc >= 0 && gc < 64) {
      const uint4* sp = (const uint4*)(qkv + ((size_t)img * NPIX + gr * 64 + gc) * 768 + g * 32);
      z0 = sp[0]; z1 = sp[1]; z2 = sp[2]; z3 = sp[3];
    }
    uint4* dp = (uint4*)(sIn + i * 32);
    dp[0] = z0; dp[1] = z1; dp[2] = z2; dp[3] = z3;
  }
  __syncthreads();
  {  // phase 1: depthwise 5x5, thread = (channel c, pixel-group)
    const int c = tid & 31, pg = tid >> 5;
    float wr_[25];
#pragma unroll
    for (int q = 0; q < 25; ++q) wr_[q] = sW5[c * 25 + q];
    for (int p16 = 0; p16 < 16; ++p16) {
      const int p = pg * 16 + p16;
      const int prow = p >> 6, pcol = p & 63;
      float s = 0.f;
#pragma unroll
      for (int ky = 0; ky < 5; ++ky) {
        const bf16* rp = sIn + ((prow + ky) * 68 + pcol) * 32 + c;
#pragma unroll
        for (int kx = 0; kx < 5; ++kx)
          s += wr_[ky * 5 + kx] * (float)rp[kx * 32];
      }
      sS[p * 33 + c] = s;
    }
  }
  __syncthreads();
  {  // phase 2: 32x32 pointwise mix
    const int e = tid & 31, pg = tid >> 5;
    for (int p16 = 0; p16 < 16; ++p16) {
      const int p = pg * 16 + p16;
      float o = 0.f;
#pragma unroll
      for (int c = 0; c < 32; ++c)
        o += sPwT[c * 32 + e] * sS[p * 33 + c];
      ag[((size_t)img * NPIX + n0 + p) * 768 + g * 32 + e] = (bf16)o;
    }
  }
}

// ---------------- attention stage 1: vk[b][h][33][32] (NHWC inputs) ----------------
__global__ __launch_bounds__(256)
void vk_nhwc(const bf16* __restrict__ qkv, const bf16* __restrict__ ag,
             float* __restrict__ vk) {
  const int chunk = blockIdx.x, h = blockIdx.y, img = blockIdx.z;
  const bf16* base = (h < 8 ? qkv : ag) + (size_t)img * NPIX * 768 + (h & 7) * 96;
  __shared__ float sk[64 * 33];
  __shared__ float sv[64 * 33];
  const int tid = threadIdx.x;
  const int e = tid & 31, dg = tid >> 5;           // e 0..31, dg 0..7
  const int srow = tid >> 4;                        // 0..15
  const int sq = tid & 15;
  const int sch = (sq & 7) * 4;
  const bf16* sptr = base + (sq < 8 ? 32 : 64) + sch;
  float* dst = (sq < 8) ? sk : sv;
  const bool isk = (sq < 8);
  float acc[4] = {0.f, 0.f, 0.f, 0.f};
  float acc1 = 0.f;
  for (int c0 = 0; c0 < 512; c0 += 64) {
    const int nbase = chunk * 512 + c0;
    __syncthreads();
#pragma unroll
    for (int i = 0; i < 4; ++i) {
      const int rr = srow + i * 16;
      const bf16x4 vv = *(const bf16x4*)(sptr + (size_t)(nbase + rr) * 768);
#pragma unroll
      for (int j = 0; j < 4; ++j) {
        const float f = (float)vv[j];
        dst[rr * 33 + sch + j] = isk ? fmaxf(f, 0.f) : f;
      }
    }
    __syncthreads();
    for (int nn = 0; nn < 64; ++nn) {
      const float kv = sk[nn * 33 + e];
#pragma unroll
      for (int j = 0; j < 4; ++j) acc[j] += sv[nn * 33 + dg * 4 + j] * kv;
      acc1 += kv;
    }
  }
  float* vkbh = vk + ((size_t)(img * 16 + h)) * 33 * 32;
#pragma unroll
  for (int j = 0; j < 4; ++j) atomicAdd(&vkbh[(dg * 4 + j) * 32 + e], acc[j]);
  if (dg == 0) atomicAdd(&vkbh[32 * 32 + e], acc1);
}

// ---------------- attention stage 2 (NHWC) ----------------
__global__ __launch_bounds__(256)
void att_nhwc(const bf16* __restrict__ qkv, const bf16* __restrict__ ag,
              const float* __restrict__ vk, bf16* __restrict__ att) {
  const int tb = blockIdx.x, h = blockIdx.y, img = blockIdx.z;
  const bf16* base = (h < 8 ? qkv : ag) + (size_t)img * NPIX * 768 + (h & 7) * 96;
  __shared__ float sq_[64 * 33];
  __shared__ float svk[33 * 32];
  __shared__ float sden[64];
  const int tid = threadIdx.x;
  const int n00 = tb * 64;
  {
    const int qrow = tid >> 3, qq = (tid & 7) * 4;
#pragma unroll
    for (int i = 0; i < 2; ++i) {
      const int rr = qrow + i * 32;
      const bf16x4 vv = *(const bf16x4*)(base + (size_t)(n00 + rr) * 768 + qq);
#pragma unroll
      for (int j = 0; j < 4; ++j) sq_[rr * 33 + qq + j] = fmaxf((float)vv[j], 0.f);
    }
  }
  const float* vkbh = vk + ((size_t)(img * 16 + h)) * 33 * 32;
  for (int i = tid; i < 33 * 32; i += 256) svk[i] = vkbh[i];
  __syncthreads();
  const int n = tid & 63, dg = tid >> 6;            // dg 0..3 -> 8 d each
  float a8[8] = {0.f, 0.f, 0.f, 0.f, 0.f, 0.f, 0.f, 0.f};
  float den = 0.f;
  for (int ee = 0; ee < 32; ++ee) {
    const float qv = sq_[n * 33 + ee];
#pragma unroll
    for (int j = 0; j < 8; ++j) a8[j] += svk[(dg * 8 + j) * 32 + ee] * qv;
    if (dg == 3) den += svk[32 * 32 + ee] * qv;
  }
  if (dg == 3) sden[n] = den;
  __syncthreads();
  const float inv = 1.f / (sden[n] + ATT_EPS);
  bf16x4 o0, o1;
#pragma unroll
  for (int j = 0; j < 4; ++j) { o0[j] = (bf16)(a8[j] * inv); o1[j] = (bf16)(a8[4 + j] * inv); }
  bf16* op = att + ((size_t)img * NPIX + n00 + n) * 512 + h * 32 + dg * 8;
  *(bf16x4*)op = o0;
  *(bf16x4*)(op + 4) = o1;
}

// ---------------- depthwise 3x3 + bias + hswish (NHWC, 1024 ch) ----------------
__global__ __launch_bounds__(256)
void dw3_nhwc(const bf16* __restrict__ ein, const float* __restrict__ w3,
              const float* __restrict__ bias, bf16* __restrict__ dout) {
  const int idx = blockIdx.x * 256 + threadIdx.x;
  const int c8 = idx & 127;
  const int seg = idx >> 7;
  const int img = seg >> 8;               // 256 segs (of 16 px) per image
  const int p0 = (seg & 255) * 16;
  const int ch = c8 * 8;
  float wr_[9][8];
#pragma unroll
  for (int j = 0; j < 8; ++j)
#pragma unroll
    for (int q = 0; q < 9; ++q) wr_[q][j] = w3[(ch + j) * 9 + q];
  const f32x4 b0 = *(const f32x4*)(bias + ch), b1 = *(const f32x4*)(bias + ch + 4);
  const int row = p0 >> 6, col0 = p0 & 63;
  const bf16* ib = ein + (size_t)img * NPIX * 1024 + ch;
  bf16* ob = dout + (size_t)img * NPIX * 1024 + ch;
  for (int pp = 0; pp < 16; ++pp) {
    const int col = col0 + pp;
    float a[8] = {b0[0], b0[1], b0[2], b0[3], b1[0], b1[1], b1[2], b1[3]};
#pragma unroll
    for (int ky = 0; ky < 3; ++ky) {
      const int r = row + ky - 1;
      if (r < 0 || r > 63) continue;
#pragma unroll
      for (int kx = 0; kx < 3; ++kx) {
        const int cc = col + kx - 1;
        if (cc < 0 || cc > 63) continue;
        const bf16x8 v = *(const bf16x8*)(ib + (size_t)(r * 64 + cc) * 1024);
#pragma unroll
        for (int j = 0; j < 8; ++j) a[j] += wr_[ky * 3 + kx][j] * (float)v[j];
      }
    }
    bf16x8 o;
#pragma unroll
    for (int j = 0; j < 8; ++j) o[j] = (bf16)hswish_f(a[j]);
    *(bf16x8*)(ob + (size_t)(row * 64 + col) * 1024) = o;
  }
}

// ---------------- launch ----------------
extern "C" void kernel_launch(void* const* d_in, const int* in_sizes, int n_in,
                              void* d_out, int out_size, void* d_ws, size_t ws_size,
                              hipStream_t stream) {
  const float* x      = (const float*)d_in[0];
  const float* W_qkv  = (const float*)d_in[1];
  const float* W_dw5  = (const float*)d_in[2];
  const float* W_pw   = (const float*)d_in[3];
  const float* W_proj = (const float*)d_in[4];
  const float* g_proj = (const float*)d_in[5];
  const float* b_proj = (const float*)d_in[6];
  const float* W_e    = (const float*)d_in[7];
  const float* b_e    = (const float*)d_in[8];
  const float* W_dw3  = (const float*)d_in[9];
  const float* b_dw3  = (const float*)d_in[10];
  const float* W_p    = (const float*)d_in[11];
  const float* g_p    = (const float*)d_in[12];
  const float* b_p    = (const float*)d_in[13];
  float* out = (float*)d_out;

  // adaptive chunking over batch
  int nb = 8;
  while (nb > 1) {
    size_t need = 851968ull * 2 + (size_t)nb * 16896 * 4 + (size_t)nb * 10485760ull * 2 + 1024;
    if (need <= ws_size) break;
    nb >>= 1;
  }

  char* wsb = (char*)d_ws;
  float* vkbuf = (float*)wsb;                                  // nb*16896 f32
  bf16* wq_bf    = (bf16*)(wsb + (size_t)nb * 16896 * 4);
  bf16* wproj_bf = wq_bf + 196608;
  bf16* we_bf    = wproj_bf + 131072;
  bf16* wp_bf    = we_bf + 262144;
  bf16* arena    = wp_bf + 262144;
  // arena (bf16 elems, per-chunk): [x_nhwc nb*1048576][qkv nb*3145728][ag nb*3145728]
  //                                [att nb*2097152][y nb*1048576]
  bf16* xn   = arena;
  bf16* qkvb = arena + (size_t)nb * 1048576;
  bf16* agb  = qkvb + (size_t)nb * 3145728;
  bf16* attb = agb + (size_t)nb * 3145728;
  bf16* yb   = attb + (size_t)nb * 2097152;
  bf16* eb   = qkvb;                                 // aliases dead qkv (+ag head)
  bf16* db   = qkvb + (size_t)nb * 4194304;          // aliases ag tail + att

  w_to_bf16<<<768, 256, 0, stream>>>(W_qkv, wq_bf, 196608);
  w_to_bf16<<<512, 256, 0, stream>>>(W_proj, wproj_bf, 131072);
  w_to_bf16<<<1024, 256, 0, stream>>>(W_e, we_bf, 262144);
  w_to_bf16<<<1024, 256, 0, stream>>>(W_p, wp_bf, 262144);

  for (int b0 = 0; b0 < 8; b0 += nb) {
    const float* x_c = x + (size_t)b0 * 256 * NPIX;
    float* out_c = out + (size_t)b0 * 256 * NPIX;

    x_to_nhwc<<<dim3(64, 8, nb), 256, 0, stream>>>(x_c, xn);
    // qkv = W_qkv @ x
    mfma_gemm<0><<<dim3(32, 6, nb), 256, 0, stream>>>(wq_bf, xn, qkvb, nullptr,
                                                      768, 256, nullptr, nullptr, nullptr);
    // ag = pw(dw5(qkv))
    dw5pw_nhwc<<<dim3(32, 24, nb), 256, 0, stream>>>(qkvb, W_dw5, W_pw, agb);
    // attention
    hipMemsetAsync(vkbuf, 0, (size_t)nb * 16896 * 4, stream);
    vk_nhwc<<<dim3(8, 16, nb), 256, 0, stream>>>(qkvb, agb, vkbuf);
    att_nhwc<<<dim3(64, 16, nb), 256, 0, stream>>>(qkvb, agb, vkbuf, attb);
    // y = BN(W_proj @ att) + x
    mfma_gemm<1><<<dim3(32, 2, nb), 256, 0, stream>>>(wproj_bf, attb, yb, nullptr,
                                                      256, 512, g_proj, b_proj, xn);
    // e = hswish(W_e @ y + b_e)
    mfma_gemm<2><<<dim3(32, 8, nb), 256, 0, stream>>>(we_bf, yb, eb, nullptr,
                                                      1024, 256, b_e, nullptr, nullptr);
    // d = hswish(dw3(e) + b_dw3)
    dw3_nhwc<<<nb * 128, 256, 0, stream>>>(eb, W_dw3, b_dw3, db);
    // out = BN(W_p @ d) + y   (f32 NCHW)
    mfma_gemm<3><<<dim3(32, 2, nb), 256, 0, stream>>>(wp_bf, db, nullptr, out_c,
                                                      256, 1024, g_p, b_p, yb);
  }
}

// Round 4
// 509.966 us; speedup vs baseline: 2.6347x; 1.0547x over previous
//
#include <hip/hip_runtime.h>

typedef __bf16 bf16;
typedef __attribute__((ext_vector_type(8))) __bf16 bf16x8;
typedef __attribute__((ext_vector_type(4))) __bf16 bf16x4;
typedef __attribute__((ext_vector_type(4))) float f32x4;

static constexpr int NPIX = 4096;                    // 64*64
static constexpr float BN_SC = 0.9999950000374997f;  // 1/sqrt(1+1e-5)
static constexpr float ATT_EPS = 1e-15f;

__device__ __forceinline__ float hswish_f(float v) {
  return v * fminf(fmaxf(v + 3.0f, 0.0f), 6.0f) * (1.0f / 6.0f);
}

__device__ __forceinline__ void gload16(const void* g, void* l) {
  __builtin_amdgcn_global_load_lds(
      (const __attribute__((address_space(1))) unsigned int*)g,
      (__attribute__((address_space(3))) unsigned int*)l, 16, 0, 0);
}

__device__ __forceinline__ float b2f_lo(unsigned int u) {
  union { unsigned int i; float f; } v; v.i = u << 16; return v.f;
}
__device__ __forceinline__ float b2f_hi(unsigned int u) {
  union { unsigned int i; float f; } v; v.i = u & 0xffff0000u; return v.f;
}
__device__ __forceinline__ unsigned short f2b_u(float f) {
  union { float f; unsigned int i; } v; v.f = f;
  unsigned int r = v.i + 0x7FFFu + ((v.i >> 16) & 1u);
  return (unsigned short)(r >> 16);
}

// ---------------- x (f32 NCHW) -> x_nhwc (bf16) ----------------
__global__ __launch_bounds__(256)
void x_to_nhwc(const float* __restrict__ x, bf16* __restrict__ xn) {
  __shared__ float t[32][65];
  const int img = blockIdx.z;
  const int n0 = blockIdx.x * 64, c0 = blockIdx.y * 32;
  const int tid = threadIdx.x;
  const float* xb = x + ((size_t)img * 256 + c0) * NPIX + n0;
  {
    const int col = tid & 63, r0 = tid >> 6;
#pragma unroll
    for (int i = 0; i < 8; ++i) {
      const int r = r0 + i * 4;
      t[r][col] = xb[(size_t)r * NPIX + col];
    }
  }
  __syncthreads();
  const int n = tid & 63, cq = tid >> 6;
  bf16x8 v;
#pragma unroll
  for (int j = 0; j < 8; ++j) v[j] = (bf16)t[cq * 8 + j][n];
  *(bf16x8*)(xn + ((size_t)img * NPIX + n0 + n) * 256 + c0 + cq * 8) = v;
}

// ---------------- f32 -> bf16 weight convert ----------------
__global__ void w_to_bf16(const float* __restrict__ w, bf16* __restrict__ o, int n) {
  const int i = blockIdx.x * 256 + threadIdx.x;
  if (i < n) o[i] = (bf16)w[i];
}

// ---------------- MFMA GEMM: D[m][n] = sum_k A[m][k] * B[n][k]  (both K-contig) ----
template<int EPI>
__global__ __launch_bounds__(256, 2)
void mfma_gemm(const bf16* __restrict__ A, const bf16* __restrict__ Bact,
               bf16* __restrict__ Yb, float* __restrict__ Yf,
               const int M, const int K,
               const float* __restrict__ p0, const float* __restrict__ p1,
               const bf16* __restrict__ res)
{
  __shared__ __attribute__((aligned(16))) char ldsA[16384];
  __shared__ __attribute__((aligned(16))) char ldsB[16384];
  const int img = blockIdx.z;
  const int n0 = blockIdx.x * 128;
  const int m0 = blockIdx.y * 128;
  const bf16* Bi = Bact + (size_t)img * NPIX * K;
  const int tid = threadIdx.x;
  const int w = tid >> 6, l = tid & 63;
  const int g = l >> 4, ln = l & 15;
  const int wr = w >> 1, wc = w & 1;
  const int lrow = l >> 3;                       // 0..7
  const int sofs = (((l & 7) ^ lrow) << 4);      // swizzled byte offset in row

  f32x4 acc[4][4];
#pragma unroll
  for (int i = 0; i < 4; ++i)
#pragma unroll
    for (int j = 0; j < 4; ++j) acc[i][j] = (f32x4){0.f, 0.f, 0.f, 0.f};

  const char* Abase = (const char*)(A + (size_t)m0 * K);
  const char* Bbase = (const char*)(Bi + (size_t)n0 * K);
  const size_t rowb = (size_t)K * 2;
  const int swz = (ln & 7) << 4;

  const int nk = K >> 6;
  for (int kt = 0; kt < nk; ++kt) {
    const int k0b = kt << 7;   // kt*64 elems * 2B
#pragma unroll
    for (int i = 0; i < 4; ++i) {
      const int q = (w << 2) + i;
      const int r = q * 8 + lrow;
      gload16(Abase + (size_t)r * rowb + k0b + sofs, ldsA + q * 1024);
    }
#pragma unroll
    for (int i = 0; i < 4; ++i) {
      const int q = (w << 2) + i;
      const int r = q * 8 + lrow;
      gload16(Bbase + (size_t)r * rowb + k0b + sofs, ldsB + q * 1024);
    }
    __syncthreads();
#pragma unroll
    for (int kk = 0; kk < 2; ++kk) {
      bf16x8 av[4], bv[4];
#pragma unroll
      for (int f = 0; f < 4; ++f) {
        const int ra = wr * 64 + f * 16 + ln;
        const int rb = wc * 64 + f * 16 + ln;
        const int kb = kk * 64 + (g << 4);
        av[f] = *(const bf16x8*)(ldsA + ra * 128 + (kb ^ swz));
        bv[f] = *(const bf16x8*)(ldsB + rb * 128 + (kb ^ swz));
      }
#pragma unroll
      for (int fi = 0; fi < 4; ++fi)
#pragma unroll
        for (int fj = 0; fj < 4; ++fj)
          acc[fi][fj] = __builtin_amdgcn_mfma_f32_16x16x32_bf16(
              av[fi], bv[fj], acc[fi][fj], 0, 0, 0);
    }
    __syncthreads();
  }

#pragma unroll
  for (int fi = 0; fi < 4; ++fi) {
    const int m4 = m0 + wr * 64 + fi * 16 + g * 4;
    f32x4 P0 = {0.f, 0.f, 0.f, 0.f}, P1 = {0.f, 0.f, 0.f, 0.f};
    if (EPI == 1 || EPI == 3) { P0 = *(const f32x4*)(p0 + m4); P1 = *(const f32x4*)(p1 + m4); }
    if (EPI == 2) { P0 = *(const f32x4*)(p0 + m4); }
#pragma unroll
    for (int fj = 0; fj < 4; ++fj) {
      const int n = n0 + wc * 64 + fj * 16 + ln;
      if (EPI == 3) {
        const bf16x4 yr = *(const bf16x4*)(res + ((size_t)img * NPIX + n) * 256 + m4);
        float* op = Yf + ((size_t)img * 256 + m4) * NPIX + n;
#pragma unroll
        for (int r = 0; r < 4; ++r)
          op[(size_t)r * NPIX] = P0[r] * BN_SC * acc[fi][fj][r] + P1[r] + (float)yr[r];
      } else {
        bf16x4 sv;
        if (EPI == 0) {
#pragma unroll
          for (int r = 0; r < 4; ++r) sv[r] = (bf16)acc[fi][fj][r];
        } else if (EPI == 1) {
          const bf16x4 xr = *(const bf16x4*)(res + ((size_t)img * NPIX + n) * 256 + m4);
#pragma unroll
          for (int r = 0; r < 4; ++r)
            sv[r] = (bf16)(P0[r] * BN_SC * acc[fi][fj][r] + P1[r] + (float)xr[r]);
        } else {
#pragma unroll
          for (int r = 0; r < 4; ++r)
            sv[r] = (bf16)hswish_f(acc[fi][fj][r] + P0[r]);
        }
        *(bf16x4*)(Yb + ((size_t)img * NPIX + n) * M + m4) = sv;
      }
    }
  }
}

// ---------------- fused dw5x5 + per-group 32x32 pointwise (NHWC), v2 ----------------
// block: 256 thr, tile = 128 px (2 image rows), group gch, img
// phase 0: stage halo 6x68 px, 32 ch as u32 channel-pairs, kx-contiguous
// phase 1: thread = (ci 0..15 = ch pair, pg 0..15 = 8 px): 3 x b128 window reads / ky
// phase 2: pw 32x32 via MFMA (A = W_pw rows, B = sS [128][40-pad] bf16)
__global__ __launch_bounds__(256)
void dw5pw_nhwc(const bf16* __restrict__ qkv, const float* __restrict__ W5,
                const float* __restrict__ Wpw, bf16* __restrict__ ag) {
  const int gch = blockIdx.y, img = blockIdx.z;
  const int n0 = blockIdx.x * 128;
  const int r0 = n0 >> 6;                        // first of 2 image rows
  __shared__ __attribute__((aligned(16))) unsigned int sInT[16 * 412];  // 26368 B
  __shared__ __attribute__((aligned(16))) unsigned int sS32[128 * 20];  // 10240 B ([128][40] bf16)
  __shared__ float sW5[32 * 25];                                        // 3200 B
  __shared__ __attribute__((aligned(16))) bf16 sPw[32 * 32];            // 2048 B
  const int tid = threadIdx.x;
  for (int i = tid; i < 800; i += 256) sW5[i] = W5[gch * 800 + i];
  for (int i = tid; i < 1024; i += 256) sPw[i] = (bf16)Wpw[gch * 1024 + i];
  // stage halo transposed: sInT[ci][hp] = channels {2ci,2ci+1} of halo pixel hp
  for (int i = tid; i < 408 * 16; i += 256) {
    const int ci = i & 15, hp = i >> 4;
    const int hr = hp / 68, hc = hp - hr * 68;
    const int gr = r0 + hr - 2, gc = hc - 2;
    unsigned int vv = 0;
    if (gr >= 0 && gr < 64 && gc >= 0 && gc < 64)
      vv = *(const unsigned int*)(qkv + ((size_t)img * NPIX + gr * 64 + gc) * 768 + gch * 32 + ci * 2);
    sInT[ci * 412 + hp] = vv;
  }
  __syncthreads();
  {  // phase 1: depthwise 5x5
    const int ci = tid & 15;          // channel pair {2ci, 2ci+1}
    const int pg = tid >> 4;          // 8 pixels each
    const int p0 = pg * 8;
    const int prow = p0 >> 6, pcol = p0 & 63;
    float w0[25], w1[25];
#pragma unroll
    for (int q = 0; q < 25; ++q) {
      w0[q] = sW5[(2 * ci) * 25 + q];
      w1[q] = sW5[(2 * ci + 1) * 25 + q];
    }
    float a0[8] = {}, a1[8] = {};
#pragma unroll
    for (int ky = 0; ky < 5; ++ky) {
      const unsigned int* wp = &sInT[ci * 412 + (prow + ky) * 68 + pcol];
      const uint4 qa = *(const uint4*)wp;
      const uint4 qb = *(const uint4*)(wp + 4);
      const uint4 qc = *(const uint4*)(wp + 8);
      const unsigned int win[12] = {qa.x, qa.y, qa.z, qa.w, qb.x, qb.y, qb.z, qb.w,
                                    qc.x, qc.y, qc.z, qc.w};
      float lo[12], hi[12];
#pragma unroll
      for (int j = 0; j < 12; ++j) { lo[j] = b2f_lo(win[j]); hi[j] = b2f_hi(win[j]); }
#pragma unroll
      for (int px = 0; px < 8; ++px)
#pragma unroll
        for (int kx = 0; kx < 5; ++kx) {
          a0[px] = fmaf(lo[px + kx], w0[ky * 5 + kx], a0[px]);
          a1[px] = fmaf(hi[px + kx], w1[ky * 5 + kx], a1[px]);
        }
    }
#pragma unroll
    for (int px = 0; px < 8; ++px) {
      const unsigned int pk = (unsigned int)f2b_u(a0[px]) | ((unsigned int)f2b_u(a1[px]) << 16);
      sS32[(p0 + px) * 20 + ci] = pk;
    }
  }
  __syncthreads();
  {  // phase 2: pw 32x32 via MFMA. wave w: p-tiles {2w, 2w+1}; e-tiles 0..1
    const int w = tid >> 6, l = tid & 63;
    const int lg = l >> 4, ln = l & 15;
    f32x4 acc[2][2];
#pragma unroll
    for (int i = 0; i < 2; ++i)
#pragma unroll
      for (int j = 0; j < 2; ++j) acc[i][j] = (f32x4){0.f, 0.f, 0.f, 0.f};
    bf16x8 av[2], bv[2];
#pragma unroll
    for (int et = 0; et < 2; ++et)
      av[et] = *(const bf16x8*)((const char*)sPw + (et * 16 + ln) * 64 + lg * 16);
#pragma unroll
    for (int pt = 0; pt < 2; ++pt)
      bv[pt] = *(const bf16x8*)((const char*)sS32 + ((2 * w + pt) * 16 + ln) * 80 + lg * 16);
#pragma unroll
    for (int et = 0; et < 2; ++et)
#pragma unroll
      for (int pt = 0; pt < 2; ++pt)
        acc[et][pt] = __builtin_amdgcn_mfma_f32_16x16x32_bf16(av[et], bv[pt], acc[et][pt], 0, 0, 0);
#pragma unroll
    for (int et = 0; et < 2; ++et)
#pragma unroll
      for (int pt = 0; pt < 2; ++pt) {
        const int e0 = et * 16 + lg * 4;
        const int p = n0 + (2 * w + pt) * 16 + ln;
        bf16x4 sv;
#pragma unroll
        for (int r = 0; r < 4; ++r) sv[r] = (bf16)acc[et][pt][r];
        *(bf16x4*)(ag + ((size_t)img * NPIX + p) * 768 + gch * 32 + e0) = sv;
      }
  }
}

// ---------------- attention stage 1: vk[b][h][33][32] (NHWC inputs) ----------------
__global__ __launch_bounds__(256)
void vk_nhwc(const bf16* __restrict__ qkv, const bf16* __restrict__ ag,
             float* __restrict__ vk) {
  const int chunk = blockIdx.x, h = blockIdx.y, img = blockIdx.z;
  const bf16* base = (h < 8 ? qkv : ag) + (size_t)img * NPIX * 768 + (h & 7) * 96;
  __shared__ float sk[64 * 33];
  __shared__ float sv[64 * 33];
  const int tid = threadIdx.x;
  const int e = tid & 31, dg = tid >> 5;           // e 0..31, dg 0..7
  const int srow = tid >> 4;                        // 0..15
  const int sq = tid & 15;
  const int sch = (sq & 7) * 4;
  const bf16* sptr = base + (sq < 8 ? 32 : 64) + sch;
  float* dst = (sq < 8) ? sk : sv;
  const bool isk = (sq < 8);
  float acc[4] = {0.f, 0.f, 0.f, 0.f};
  float acc1 = 0.f;
  for (int c0 = 0; c0 < 512; c0 += 64) {
    const int nbase = chunk * 512 + c0;
    __syncthreads();
#pragma unroll
    for (int i = 0; i < 4; ++i) {
      const int rr = srow + i * 16;
      const bf16x4 vv = *(const bf16x4*)(sptr + (size_t)(nbase + rr) * 768);
#pragma unroll
      for (int j = 0; j < 4; ++j) {
        const float f = (float)vv[j];
        dst[rr * 33 + sch + j] = isk ? fmaxf(f, 0.f) : f;
      }
    }
    __syncthreads();
    for (int nn = 0; nn < 64; ++nn) {
      const float kv = sk[nn * 33 + e];
#pragma unroll
      for (int j = 0; j < 4; ++j) acc[j] += sv[nn * 33 + dg * 4 + j] * kv;
      acc1 += kv;
    }
  }
  float* vkbh = vk + ((size_t)(img * 16 + h)) * 33 * 32;
#pragma unroll
  for (int j = 0; j < 4; ++j) atomicAdd(&vkbh[(dg * 4 + j) * 32 + e], acc[j]);
  if (dg == 0) atomicAdd(&vkbh[32 * 32 + e], acc1);
}

// ---------------- attention stage 2 (NHWC) ----------------
__global__ __launch_bounds__(256)
void att_nhwc(const bf16* __restrict__ qkv, const bf16* __restrict__ ag,
              const float* __restrict__ vk, bf16* __restrict__ att) {
  const int tb = blockIdx.x, h = blockIdx.y, img = blockIdx.z;
  const bf16* base = (h < 8 ? qkv : ag) + (size_t)img * NPIX * 768 + (h & 7) * 96;
  __shared__ float sq_[64 * 33];
  __shared__ float svk[33 * 32];
  __shared__ float sden[64];
  const int tid = threadIdx.x;
  const int n00 = tb * 64;
  {
    const int qrow = tid >> 3, qq = (tid & 7) * 4;
#pragma unroll
    for (int i = 0; i < 2; ++i) {
      const int rr = qrow + i * 32;
      const bf16x4 vv = *(const bf16x4*)(base + (size_t)(n00 + rr) * 768 + qq);
#pragma unroll
      for (int j = 0; j < 4; ++j) sq_[rr * 33 + qq + j] = fmaxf((float)vv[j], 0.f);
    }
  }
  const float* vkbh = vk + ((size_t)(img * 16 + h)) * 33 * 32;
  for (int i = tid; i < 33 * 32; i += 256) svk[i] = vkbh[i];
  __syncthreads();
  const int n = tid & 63, dg = tid >> 6;            // dg 0..3 -> 8 d each
  float a8[8] = {0.f, 0.f, 0.f, 0.f, 0.f, 0.f, 0.f, 0.f};
  float den = 0.f;
  for (int ee = 0; ee < 32; ++ee) {
    const float qv = sq_[n * 33 + ee];
#pragma unroll
    for (int j = 0; j < 8; ++j) a8[j] += svk[(dg * 8 + j) * 32 + ee] * qv;
    if (dg == 3) den += svk[32 * 32 + ee] * qv;
  }
  if (dg == 3) sden[n] = den;
  __syncthreads();
  const float inv = 1.f / (sden[n] + ATT_EPS);
  bf16x4 o0, o1;
#pragma unroll
  for (int j = 0; j < 4; ++j) { o0[j] = (bf16)(a8[j] * inv); o1[j] = (bf16)(a8[4 + j] * inv); }
  bf16* op = att + ((size_t)img * NPIX + n00 + n) * 512 + h * 32 + dg * 8;
  *(bf16x4*)op = o0;
  *(bf16x4*)(op + 4) = o1;
}

// ---------------- depthwise 3x3 + bias + hswish (NHWC, 1024 ch) ----------------
__global__ __launch_bounds__(256)
void dw3_nhwc(const bf16* __restrict__ ein, const float* __restrict__ w3,
              const float* __restrict__ bias, bf16* __restrict__ dout) {
  const int idx = blockIdx.x * 256 + threadIdx.x;
  const int c8 = idx & 127;
  const int seg = idx >> 7;
  const int img = seg >> 8;               // 256 segs (of 16 px) per image
  const int p0 = (seg & 255) * 16;
  const int ch = c8 * 8;
  float wr_[9][8];
#pragma unroll
  for (int j = 0; j < 8; ++j)
#pragma unroll
    for (int q = 0; q < 9; ++q) wr_[q][j] = w3[(ch + j) * 9 + q];
  const f32x4 b0 = *(const f32x4*)(bias + ch), b1 = *(const f32x4*)(bias + ch + 4);
  const int row = p0 >> 6, col0 = p0 & 63;
  const bf16* ib = ein + (size_t)img * NPIX * 1024 + ch;
  bf16* ob = dout + (size_t)img * NPIX * 1024 + ch;
  for (int pp = 0; pp < 16; ++pp) {
    const int col = col0 + pp;
    float a[8] = {b0[0], b0[1], b0[2], b0[3], b1[0], b1[1], b1[2], b1[3]};
#pragma unroll
    for (int ky = 0; ky < 3; ++ky) {
      const int r = row + ky - 1;
      if (r < 0 || r > 63) continue;
#pragma unroll
      for (int kx = 0; kx < 3; ++kx) {
        const int cc = col + kx - 1;
        if (cc < 0 || cc > 63) continue;
        const bf16x8 v = *(const bf16x8*)(ib + (size_t)(r * 64 + cc) * 1024);
#pragma unroll
        for (int j = 0; j < 8; ++j) a[j] += wr_[ky * 3 + kx][j] * (float)v[j];
      }
    }
    bf16x8 o;
#pragma unroll
    for (int j = 0; j < 8; ++j) o[j] = (bf16)hswish_f(a[j]);
    *(bf16x8*)(ob + (size_t)(row * 64 + col) * 1024) = o;
  }
}

// ---------------- launch ----------------
extern "C" void kernel_launch(void* const* d_in, const int* in_sizes, int n_in,
                              void* d_out, int out_size, void* d_ws, size_t ws_size,
                              hipStream_t stream) {
  const float* x      = (const float*)d_in[0];
  const float* W_qkv  = (const float*)d_in[1];
  const float* W_dw5  = (const float*)d_in[2];
  const float* W_pw   = (const float*)d_in[3];
  const float* W_proj = (const float*)d_in[4];
  const float* g_proj = (const float*)d_in[5];
  const float* b_proj = (const float*)d_in[6];
  const float* W_e    = (const float*)d_in[7];
  const float* b_e    = (const float*)d_in[8];
  const float* W_dw3  = (const float*)d_in[9];
  const float* b_dw3  = (const float*)d_in[10];
  const float* W_p    = (const float*)d_in[11];
  const float* g_p    = (const float*)d_in[12];
  const float* b_p    = (const float*)d_in[13];
  float* out = (float*)d_out;

  // adaptive chunking over batch
  int nb = 8;
  while (nb > 1) {
    size_t need = 851968ull * 2 + (size_t)nb * 16896 * 4 + (size_t)nb * 10485760ull * 2 + 1024;
    if (need <= ws_size) break;
    nb >>= 1;
  }

  char* wsb = (char*)d_ws;
  float* vkbuf = (float*)wsb;                                  // nb*16896 f32
  bf16* wq_bf    = (bf16*)(wsb + (size_t)nb * 16896 * 4);
  bf16* wproj_bf = wq_bf + 196608;
  bf16* we_bf    = wproj_bf + 131072;
  bf16* wp_bf    = we_bf + 262144;
  bf16* arena    = wp_bf + 262144;
  bf16* xn   = arena;
  bf16* qkvb = arena + (size_t)nb * 1048576;
  bf16* agb  = qkvb + (size_t)nb * 3145728;
  bf16* attb = agb + (size_t)nb * 3145728;
  bf16* yb   = attb + (size_t)nb * 2097152;
  bf16* eb   = qkvb;                                 // aliases dead qkv (+ag head)
  bf16* db   = qkvb + (size_t)nb * 4194304;          // aliases ag tail + att

  w_to_bf16<<<768, 256, 0, stream>>>(W_qkv, wq_bf, 196608);
  w_to_bf16<<<512, 256, 0, stream>>>(W_proj, wproj_bf, 131072);
  w_to_bf16<<<1024, 256, 0, stream>>>(W_e, we_bf, 262144);
  w_to_bf16<<<1024, 256, 0, stream>>>(W_p, wp_bf, 262144);

  for (int b0 = 0; b0 < 8; b0 += nb) {
    const float* x_c = x + (size_t)b0 * 256 * NPIX;
    float* out_c = out + (size_t)b0 * 256 * NPIX;

    x_to_nhwc<<<dim3(64, 8, nb), 256, 0, stream>>>(x_c, xn);
    // qkv = W_qkv @ x
    mfma_gemm<0><<<dim3(32, 6, nb), 256, 0, stream>>>(wq_bf, xn, qkvb, nullptr,
                                                      768, 256, nullptr, nullptr, nullptr);
    // ag = pw(dw5(qkv))
    dw5pw_nhwc<<<dim3(32, 24, nb), 256, 0, stream>>>(qkvb, W_dw5, W_pw, agb);
    // attention
    hipMemsetAsync(vkbuf, 0, (size_t)nb * 16896 * 4, stream);
    vk_nhwc<<<dim3(8, 16, nb), 256, 0, stream>>>(qkvb, agb, vkbuf);
    att_nhwc<<<dim3(64, 16, nb), 256, 0, stream>>>(qkvb, agb, vkbuf, attb);
    // y = BN(W_proj @ att) + x
    mfma_gemm<1><<<dim3(32, 2, nb), 256, 0, stream>>>(wproj_bf, attb, yb, nullptr,
                                                      256, 512, g_proj, b_proj, xn);
    // e = hswish(W_e @ y + b_e)
    mfma_gemm<2><<<dim3(32, 8, nb), 256, 0, stream>>>(we_bf, yb, eb, nullptr,
                                                      1024, 256, b_e, nullptr, nullptr);
    // d = hswish(dw3(e) + b_dw3)
    dw3_nhwc<<<nb * 128, 256, 0, stream>>>(eb, W_dw3, b_dw3, db);
    // out = BN(W_p @ d) + y   (f32 NCHW)
    mfma_gemm<3><<<dim3(32, 2, nb), 256, 0, stream>>>(wp_bf, db, nullptr, out_c,
                                                      256, 1024, g_p, b_p, yb);
  }
}

// Round 5
// 467.382 us; speedup vs baseline: 2.8747x; 1.0911x over previous
//
#include <hip/hip_runtime.h>

typedef __bf16 bf16;
typedef __attribute__((ext_vector_type(8))) __bf16 bf16x8;
typedef __attribute__((ext_vector_type(4))) __bf16 bf16x4;
typedef __attribute__((ext_vector_type(2))) __bf16 bf16x2;
typedef __attribute__((ext_vector_type(4))) float f32x4;

static constexpr int NPIX = 4096;                    // 64*64
static constexpr float BN_SC = 0.9999950000374997f;  // 1/sqrt(1+1e-5)
static constexpr float ATT_EPS = 1e-15f;

__device__ __forceinline__ float hswish_f(float v) {
  return v * fminf(fmaxf(v + 3.0f, 0.0f), 6.0f) * (1.0f / 6.0f);
}

__device__ __forceinline__ void gload16(const void* g, void* l) {
  __builtin_amdgcn_global_load_lds(
      (const __attribute__((address_space(1))) unsigned int*)g,
      (__attribute__((address_space(3))) unsigned int*)l, 16, 0, 0);
}

__device__ __forceinline__ float b2f_lo(unsigned int u) {
  union { unsigned int i; float f; } v; v.i = u << 16; return v.f;
}
__device__ __forceinline__ float b2f_hi(unsigned int u) {
  union { unsigned int i; float f; } v; v.i = u & 0xffff0000u; return v.f;
}
__device__ __forceinline__ unsigned short f2b_u(float f) {
  union { float f; unsigned int i; } v; v.f = f;
  unsigned int r = v.i + 0x7FFFu + ((v.i >> 16) & 1u);
  return (unsigned short)(r >> 16);
}

// ---------------- x (f32 NCHW) -> x_nhwc (bf16) ----------------
__global__ __launch_bounds__(256)
void x_to_nhwc(const float* __restrict__ x, bf16* __restrict__ xn) {
  __shared__ float t[32][65];
  const int img = blockIdx.z;
  const int n0 = blockIdx.x * 64, c0 = blockIdx.y * 32;
  const int tid = threadIdx.x;
  const float* xb = x + ((size_t)img * 256 + c0) * NPIX + n0;
  {
    const int col = tid & 63, r0 = tid >> 6;
#pragma unroll
    for (int i = 0; i < 8; ++i) {
      const int r = r0 + i * 4;
      t[r][col] = xb[(size_t)r * NPIX + col];
    }
  }
  __syncthreads();
  const int n = tid & 63, cq = tid >> 6;
  bf16x8 v;
#pragma unroll
  for (int j = 0; j < 8; ++j) v[j] = (bf16)t[cq * 8 + j][n];
  *(bf16x8*)(xn + ((size_t)img * NPIX + n0 + n) * 256 + c0 + cq * 8) = v;
}

// ---------------- f32 -> bf16 weight convert (plain) ----------------
__global__ void w_to_bf16(const float* __restrict__ w, bf16* __restrict__ o, int n) {
  const int i = blockIdx.x * 256 + threadIdx.x;
  if (i < n) o[i] = (bf16)w[i];
}

// ---------------- W_qkv permuted convert: new row t*256+h*32+d <- old h*96+t*32+d --
__global__ void wqkv_perm(const float* __restrict__ w, bf16* __restrict__ o) {
  const int row = blockIdx.x;  // 0..767 (new index)
  const int t = row >> 8, r = row & 255, h = r >> 5, d = r & 31;
  const int oldrow = h * 96 + t * 32 + d;
  o[row * 256 + threadIdx.x] = (bf16)w[oldrow * 256 + threadIdx.x];
}

// ---------------- MFMA GEMM: D[m][n] = sum_k A[m][k] * B[n][k]  (both K-contig) ----
template<int EPI>
__global__ __launch_bounds__(256, 2)
void mfma_gemm(const bf16* __restrict__ A, const bf16* __restrict__ Bact,
               bf16* __restrict__ Yb, float* __restrict__ Yf,
               const int M, const int K,
               const float* __restrict__ p0, const float* __restrict__ p1,
               const bf16* __restrict__ res)
{
  __shared__ __attribute__((aligned(16))) char ldsA[16384];
  __shared__ __attribute__((aligned(16))) char ldsB[16384];
  const int img = blockIdx.z;
  const int n0 = blockIdx.x * 128;
  const int m0 = blockIdx.y * 128;
  const bf16* Bi = Bact + (size_t)img * NPIX * K;
  const int tid = threadIdx.x;
  const int w = tid >> 6, l = tid & 63;
  const int g = l >> 4, ln = l & 15;
  const int wr = w >> 1, wc = w & 1;
  const int lrow = l >> 3;                       // 0..7
  const int sofs = (((l & 7) ^ lrow) << 4);      // swizzled byte offset in row

  f32x4 acc[4][4];
#pragma unroll
  for (int i = 0; i < 4; ++i)
#pragma unroll
    for (int j = 0; j < 4; ++j) acc[i][j] = (f32x4){0.f, 0.f, 0.f, 0.f};

  const char* Abase = (const char*)(A + (size_t)m0 * K);
  const char* Bbase = (const char*)(Bi + (size_t)n0 * K);
  const size_t rowb = (size_t)K * 2;
  const int swz = (ln & 7) << 4;

  const int nk = K >> 6;
  for (int kt = 0; kt < nk; ++kt) {
    const int k0b = kt << 7;
#pragma unroll
    for (int i = 0; i < 4; ++i) {
      const int q = (w << 2) + i;
      const int r = q * 8 + lrow;
      gload16(Abase + (size_t)r * rowb + k0b + sofs, ldsA + q * 1024);
    }
#pragma unroll
    for (int i = 0; i < 4; ++i) {
      const int q = (w << 2) + i;
      const int r = q * 8 + lrow;
      gload16(Bbase + (size_t)r * rowb + k0b + sofs, ldsB + q * 1024);
    }
    __syncthreads();
#pragma unroll
    for (int kk = 0; kk < 2; ++kk) {
      bf16x8 av[4], bv[4];
#pragma unroll
      for (int f = 0; f < 4; ++f) {
        const int ra = wr * 64 + f * 16 + ln;
        const int rb = wc * 64 + f * 16 + ln;
        const int kb = kk * 64 + (g << 4);
        av[f] = *(const bf16x8*)(ldsA + ra * 128 + (kb ^ swz));
        bv[f] = *(const bf16x8*)(ldsB + rb * 128 + (kb ^ swz));
      }
#pragma unroll
      for (int fi = 0; fi < 4; ++fi)
#pragma unroll
        for (int fj = 0; fj < 4; ++fj)
          acc[fi][fj] = __builtin_amdgcn_mfma_f32_16x16x32_bf16(
              av[fi], bv[fj], acc[fi][fj], 0, 0, 0);
    }
    __syncthreads();
  }

#pragma unroll
  for (int fi = 0; fi < 4; ++fi) {
    const int m4 = m0 + wr * 64 + fi * 16 + g * 4;
    f32x4 P0 = {0.f, 0.f, 0.f, 0.f}, P1 = {0.f, 0.f, 0.f, 0.f};
    if (EPI == 1 || EPI == 3) { P0 = *(const f32x4*)(p0 + m4); P1 = *(const f32x4*)(p1 + m4); }
    if (EPI == 2) { P0 = *(const f32x4*)(p0 + m4); }
#pragma unroll
    for (int fj = 0; fj < 4; ++fj) {
      const int n = n0 + wc * 64 + fj * 16 + ln;
      if (EPI == 3) {
        const bf16x4 yr = *(const bf16x4*)(res + ((size_t)img * NPIX + n) * 256 + m4);
        float* op = Yf + ((size_t)img * 256 + m4) * NPIX + n;
#pragma unroll
        for (int r = 0; r < 4; ++r)
          op[(size_t)r * NPIX] = P0[r] * BN_SC * acc[fi][fj][r] + P1[r] + (float)yr[r];
      } else {
        bf16x4 sv;
        if (EPI == 0) {
#pragma unroll
          for (int r = 0; r < 4; ++r) sv[r] = (bf16)acc[fi][fj][r];
        } else if (EPI == 1) {
          const bf16x4 xr = *(const bf16x4*)(res + ((size_t)img * NPIX + n) * 256 + m4);
#pragma unroll
          for (int r = 0; r < 4; ++r)
            sv[r] = (bf16)(P0[r] * BN_SC * acc[fi][fj][r] + P1[r] + (float)xr[r]);
        } else {
#pragma unroll
          for (int r = 0; r < 4; ++r)
            sv[r] = (bf16)hswish_f(acc[fi][fj][r] + P0[r]);
        }
        *(bf16x4*)(Yb + ((size_t)img * NPIX + n) * M + m4) = sv;
      }
    }
  }
}

// ---------------- fused dw5x5 + per-group 32x32 pointwise (NHWC, permuted groups) --
// gch = g_new = t*8+h ; input channels qkv[px][gch*32..], weights via old indices
__global__ __launch_bounds__(256)
void dw5pw_nhwc(const bf16* __restrict__ qkv, const float* __restrict__ W5,
                const float* __restrict__ Wpw, bf16* __restrict__ ag) {
  const int gch = blockIdx.y, img = blockIdx.z;
  const int t_ = gch >> 3, hh_ = gch & 7;
  const int n0 = blockIdx.x * 128;
  const int r0 = n0 >> 6;
  __shared__ __attribute__((aligned(16))) unsigned int sInT[16 * 412];
  __shared__ __attribute__((aligned(16))) unsigned int sS32[128 * 20];
  __shared__ float sW5[32 * 25];
  __shared__ __attribute__((aligned(16))) bf16 sPw[32 * 32];
  const int tid = threadIdx.x;
  for (int i = tid; i < 800; i += 256) {
    const int c = i / 25, q = i - c * 25;
    sW5[i] = W5[(hh_ * 96 + t_ * 32 + c) * 25 + q];
  }
  for (int i = tid; i < 1024; i += 256) sPw[i] = (bf16)Wpw[(hh_ * 3 + t_) * 1024 + i];
  for (int i = tid; i < 408 * 16; i += 256) {
    const int ci = i & 15, hp = i >> 4;
    const int hr = hp / 68, hc = hp - hr * 68;
    const int gr = r0 + hr - 2, gc = hc - 2;
    unsigned int vv = 0;
    if (gr >= 0 && gr < 64 && gc >= 0 && gc < 64)
      vv = *(const unsigned int*)(qkv + ((size_t)img * NPIX + gr * 64 + gc) * 768 + gch * 32 + ci * 2);
    sInT[ci * 412 + hp] = vv;
  }
  __syncthreads();
  {  // phase 1: depthwise 5x5
    const int ci = tid & 15;
    const int pg = tid >> 4;
    const int p0 = pg * 8;
    const int prow = p0 >> 6, pcol = p0 & 63;
    float w0[25], w1[25];
#pragma unroll
    for (int q = 0; q < 25; ++q) {
      w0[q] = sW5[(2 * ci) * 25 + q];
      w1[q] = sW5[(2 * ci + 1) * 25 + q];
    }
    float a0[8] = {}, a1[8] = {};
#pragma unroll
    for (int ky = 0; ky < 5; ++ky) {
      const unsigned int* wp = &sInT[ci * 412 + (prow + ky) * 68 + pcol];
      const uint4 qa = *(const uint4*)wp;
      const uint4 qb = *(const uint4*)(wp + 4);
      const uint4 qc = *(const uint4*)(wp + 8);
      const unsigned int win[12] = {qa.x, qa.y, qa.z, qa.w, qb.x, qb.y, qb.z, qb.w,
                                    qc.x, qc.y, qc.z, qc.w};
      float lo[12], hi[12];
#pragma unroll
      for (int j = 0; j < 12; ++j) { lo[j] = b2f_lo(win[j]); hi[j] = b2f_hi(win[j]); }
#pragma unroll
      for (int px = 0; px < 8; ++px)
#pragma unroll
        for (int kx = 0; kx < 5; ++kx) {
          a0[px] = fmaf(lo[px + kx], w0[ky * 5 + kx], a0[px]);
          a1[px] = fmaf(hi[px + kx], w1[ky * 5 + kx], a1[px]);
        }
    }
#pragma unroll
    for (int px = 0; px < 8; ++px) {
      const unsigned int pk = (unsigned int)f2b_u(a0[px]) | ((unsigned int)f2b_u(a1[px]) << 16);
      sS32[(p0 + px) * 20 + ci] = pk;
    }
  }
  __syncthreads();
  {  // phase 2: pw 32x32 via MFMA
    const int w = tid >> 6, l = tid & 63;
    const int lg = l >> 4, ln = l & 15;
    f32x4 acc[2][2];
#pragma unroll
    for (int i = 0; i < 2; ++i)
#pragma unroll
      for (int j = 0; j < 2; ++j) acc[i][j] = (f32x4){0.f, 0.f, 0.f, 0.f};
    bf16x8 av[2], bv[2];
#pragma unroll
    for (int et = 0; et < 2; ++et)
      av[et] = *(const bf16x8*)((const char*)sPw + (et * 16 + ln) * 64 + lg * 16);
#pragma unroll
    for (int pt = 0; pt < 2; ++pt)
      bv[pt] = *(const bf16x8*)((const char*)sS32 + ((2 * w + pt) * 16 + ln) * 80 + lg * 16);
#pragma unroll
    for (int et = 0; et < 2; ++et)
#pragma unroll
      for (int pt = 0; pt < 2; ++pt)
        acc[et][pt] = __builtin_amdgcn_mfma_f32_16x16x32_bf16(av[et], bv[pt], acc[et][pt], 0, 0, 0);
#pragma unroll
    for (int et = 0; et < 2; ++et)
#pragma unroll
      for (int pt = 0; pt < 2; ++pt) {
        const int e0 = et * 16 + lg * 4;
        const int p = n0 + (2 * w + pt) * 16 + ln;
        bf16x4 sv;
#pragma unroll
        for (int r = 0; r < 4; ++r) sv[r] = (bf16)acc[et][pt][r];
        *(bf16x4*)(ag + ((size_t)img * NPIX + p) * 768 + gch * 32 + e0) = sv;
      }
  }
}

// ---------------- vk partial: per (chunk128, src, img) ----------------
// partial[(img*2+src)*32+chunk][8h][33][32] f32
__global__ __launch_bounds__(256)
void vk_part(const bf16* __restrict__ qkv, const bf16* __restrict__ ag,
             float* __restrict__ partial) {
  const int chunk = blockIdx.x, src = blockIdx.y, img = blockIdx.z;
  const bf16* base = (src == 0 ? qkv : ag) + (size_t)img * NPIX * 768 + 256;
  __shared__ __attribute__((aligned(16))) char tile[32 * 1024];  // [32px][512ch] swizzled
  const int tid = threadIdx.x;
  const int e2 = tid & 15, sd = tid >> 4;       // e-pair base e2*2, d-pair base sd*2
  const int spx = tid >> 3, sseg = tid & 7;
  float acc[8][2][2] = {};
  float accd[8][2] = {};
  for (int sub = 0; sub < 4; ++sub) {
    __syncthreads();
    {
      const int px0 = chunk * 128 + sub * 32;
      const char* gp = (const char*)(base + (size_t)(px0 + spx) * 768) + sseg * 128;
      char* lp = tile + spx * 1024;
      const int swz = (spx & 7) << 4;
#pragma unroll
      for (int i = 0; i < 8; ++i) {
        const uint4 v = *(const uint4*)(gp + i * 16);
        *(uint4*)(lp + ((sseg * 128 + i * 16) ^ swz)) = v;
      }
    }
    __syncthreads();
    for (int nn = 0; nn < 32; ++nn) {
      const char* row = tile + nn * 1024;
      const int swzn = (nn & 7) << 4;
#pragma unroll
      for (int h = 0; h < 8; ++h) {
        const unsigned int kk = *(const unsigned int*)(row + ((h * 64 + e2 * 4) ^ swzn));
        const float k0 = fmaxf(b2f_lo(kk), 0.f), k1 = fmaxf(b2f_hi(kk), 0.f);
        const unsigned int vv = *(const unsigned int*)(row + ((512 + h * 64 + sd * 4) ^ swzn));
        const float v0 = b2f_lo(vv), v1 = b2f_hi(vv);
        acc[h][0][0] = fmaf(v0, k0, acc[h][0][0]);
        acc[h][0][1] = fmaf(v0, k1, acc[h][0][1]);
        acc[h][1][0] = fmaf(v1, k0, acc[h][1][0]);
        acc[h][1][1] = fmaf(v1, k1, acc[h][1][1]);
        accd[h][0] += k0; accd[h][1] += k1;
      }
    }
  }
  float* pb = partial + ((size_t)((img * 2 + src) * 32 + chunk)) * 8448;
#pragma unroll
  for (int h = 0; h < 8; ++h) {
#pragma unroll
    for (int dj = 0; dj < 2; ++dj)
#pragma unroll
      for (int ej = 0; ej < 2; ++ej)
        pb[h * 1056 + (sd * 2 + dj) * 32 + e2 * 2 + ej] = acc[h][dj][ej];
    if (sd == 0) {
      pb[h * 1056 + 1024 + e2 * 2]     = accd[h][0];
      pb[h * 1056 + 1024 + e2 * 2 + 1] = accd[h][1];
    }
  }
}

// ---------------- vk reduce: sum 32 chunk-partials -> svkT bf16 [img][h][e][d], dvec f32
__global__ __launch_bounds__(256)
void vk_reduce(const float* __restrict__ partial, bf16* __restrict__ svkT,
               float* __restrict__ dvec) {
  const int h = blockIdx.x & 15, img = blockIdx.x >> 4;
  const int tid = threadIdx.x;
  const int e = tid & 31, dq = tid >> 5;
  const int src = h >> 3, hh = h & 7;
  const float* pb = partial + (size_t)((img * 2 + src) * 32) * 8448 + hh * 1056;
  float a[4] = {};
  for (int c = 0; c < 32; ++c) {
    const float* pc = pb + (size_t)c * 8448;
#pragma unroll
    for (int j = 0; j < 4; ++j) a[j] += pc[(dq * 4 + j) * 32 + e];
  }
  bf16x4 o;
#pragma unroll
  for (int j = 0; j < 4; ++j) o[j] = (bf16)a[j];
  *(bf16x4*)(svkT + (((size_t)img * 16 + h) * 32 + e) * 32 + dq * 4) = o;
  if (dq == 0) {
    float ds = 0.f;
    for (int c = 0; c < 32; ++c) ds += pb[(size_t)c * 8448 + 1024 + e];
    dvec[((size_t)img * 16 + h) * 32 + e] = ds;
  }
}

// ---------------- attention apply: out[px][h*32+d] = (q . svkT[:,d]) / (q . dvec) --
__global__ __launch_bounds__(256)
void att_pix(const bf16* __restrict__ qkv, const bf16* __restrict__ ag,
             const bf16* __restrict__ svkT, const float* __restrict__ dvec,
             bf16* __restrict__ att) {
  const int pc = blockIdx.x;     // 8 px each
  const int img = blockIdx.z;
  __shared__ float sq[8][516];
  __shared__ __attribute__((aligned(16))) bf16 ssvk[16 * 1024];  // [h][e][d]
  __shared__ float sdv[16 * 32];
  const int tid = threadIdx.x;
  const int px0 = pc * 8;
  {
    const int px = tid >> 5, part = tid & 31;
    const bf16* srcp = (part < 16 ? qkv : ag) + (size_t)(img * NPIX + px0 + px) * 768 + (part & 15) * 16;
    const bf16x8 v0 = *(const bf16x8*)srcp;
    const bf16x8 v1 = *(const bf16x8*)(srcp + 8);
    const int c0 = (part < 16 ? 0 : 256) + (part & 15) * 16;
#pragma unroll
    for (int j = 0; j < 8; ++j) {
      sq[px][c0 + j]     = fmaxf((float)v0[j], 0.f);
      sq[px][c0 + 8 + j] = fmaxf((float)v1[j], 0.f);
    }
  }
  {
    const bf16* sb = svkT + (size_t)img * 16384;
    for (int i = tid; i < 2048; i += 256)
      *(bf16x8*)(ssvk + i * 8) = *(const bf16x8*)(sb + i * 8);
    const float* db = dvec + (size_t)img * 512;
    for (int i = tid; i < 512; i += 256) sdv[i] = db[i];
  }
  __syncthreads();
  const int s = tid & 31, px = tid >> 5;
  const int shalf = s >> 4, sd = s & 15, d0 = sd * 2;
  const unsigned int* sv32 = (const unsigned int*)ssvk;
  bf16* ob = att + (size_t)(img * NPIX + px0 + px) * 512;
#pragma unroll
  for (int hh = 0; hh < 8; ++hh) {
    const int h = shalf * 8 + hh;
    const float* qp = &sq[px][h * 32];
    const unsigned int* kp = sv32 + h * 512 + sd;
    const float* dp = &sdv[h * 32];
    float a0 = 0.f, a1 = 0.f, den = 0.f;
#pragma unroll
    for (int ee = 0; ee < 32; ++ee) {
      const float qf = qp[ee];
      const unsigned int wv = kp[ee * 16];
      a0 = fmaf(qf, b2f_lo(wv), a0);
      a1 = fmaf(qf, b2f_hi(wv), a1);
      den = fmaf(qf, dp[ee], den);
    }
    const float inv = 1.f / (den + ATT_EPS);
    bf16x2 o; o[0] = (bf16)(a0 * inv); o[1] = (bf16)(a1 * inv);
    *(bf16x2*)(ob + h * 32 + d0) = o;
  }
}

// ---------------- depthwise 3x3 + bias + hswish (NHWC, 1024 ch) ----------------
__global__ __launch_bounds__(256)
void dw3_nhwc(const bf16* __restrict__ ein, const float* __restrict__ w3,
              const float* __restrict__ bias, bf16* __restrict__ dout) {
  const int idx = blockIdx.x * 256 + threadIdx.x;
  const int c8 = idx & 127;
  const int seg = idx >> 7;
  const int img = seg >> 8;
  const int p0 = (seg & 255) * 16;
  const int ch = c8 * 8;
  float wr_[9][8];
#pragma unroll
  for (int j = 0; j < 8; ++j)
#pragma unroll
    for (int q = 0; q < 9; ++q) wr_[q][j] = w3[(ch + j) * 9 + q];
  const f32x4 b0 = *(const f32x4*)(bias + ch), b1 = *(const f32x4*)(bias + ch + 4);
  const int row = p0 >> 6, col0 = p0 & 63;
  const bf16* ib = ein + (size_t)img * NPIX * 1024 + ch;
  bf16* ob = dout + (size_t)img * NPIX * 1024 + ch;
  for (int pp = 0; pp < 16; ++pp) {
    const int col = col0 + pp;
    float a[8] = {b0[0], b0[1], b0[2], b0[3], b1[0], b1[1], b1[2], b1[3]};
#pragma unroll
    for (int ky = 0; ky < 3; ++ky) {
      const int r = row + ky - 1;
      if (r < 0 || r > 63) continue;
#pragma unroll
      for (int kx = 0; kx < 3; ++kx) {
        const int cc = col + kx - 1;
        if (cc < 0 || cc > 63) continue;
        const bf16x8 v = *(const bf16x8*)(ib + (size_t)(r * 64 + cc) * 1024);
#pragma unroll
        for (int j = 0; j < 8; ++j) a[j] += wr_[ky * 3 + kx][j] * (float)v[j];
      }
    }
    bf16x8 o;
#pragma unroll
    for (int j = 0; j < 8; ++j) o[j] = (bf16)hswish_f(a[j]);
    *(bf16x8*)(ob + (size_t)(row * 64 + col) * 1024) = o;
  }
}

// ---------------- launch ----------------
extern "C" void kernel_launch(void* const* d_in, const int* in_sizes, int n_in,
                              void* d_out, int out_size, void* d_ws, size_t ws_size,
                              hipStream_t stream) {
  const float* x      = (const float*)d_in[0];
  const float* W_qkv  = (const float*)d_in[1];
  const float* W_dw5  = (const float*)d_in[2];
  const float* W_pw   = (const float*)d_in[3];
  const float* W_proj = (const float*)d_in[4];
  const float* g_proj = (const float*)d_in[5];
  const float* b_proj = (const float*)d_in[6];
  const float* W_e    = (const float*)d_in[7];
  const float* b_e    = (const float*)d_in[8];
  const float* W_dw3  = (const float*)d_in[9];
  const float* b_dw3  = (const float*)d_in[10];
  const float* W_p    = (const float*)d_in[11];
  const float* g_p    = (const float*)d_in[12];
  const float* b_p    = (const float*)d_in[13];
  float* out = (float*)d_out;

  // adaptive chunking over batch
  int nb = 8;
  while (nb > 1) {
    size_t need = (size_t)nb * 23169024ull + 1703936ull + 1024;
    if (need <= ws_size) break;
    nb >>= 1;
  }

  char* p = (char*)d_ws;
  float* partial = (float*)p;                 p += (size_t)nb * 2162688;   // nb*540672 f32
  float* dvec    = (float*)p;                 p += (size_t)nb * 2048;      // nb*512 f32
  bf16* wq_bf    = (bf16*)p;                  p += 196608ull * 2;
  bf16* wproj_bf = (bf16*)p;                  p += 131072ull * 2;
  bf16* we_bf    = (bf16*)p;                  p += 262144ull * 2;
  bf16* wp_bf    = (bf16*)p;                  p += 262144ull * 2;
  bf16* svkT     = (bf16*)p;                  p += (size_t)nb * 32768;     // nb*16384 bf16
  bf16* arena    = (bf16*)p;
  bf16* xn   = arena;
  bf16* qkvb = arena + (size_t)nb * 1048576;
  bf16* agb  = qkvb + (size_t)nb * 3145728;
  bf16* attb = agb + (size_t)nb * 3145728;
  bf16* yb   = attb + (size_t)nb * 2097152;
  bf16* eb   = qkvb;
  bf16* db   = qkvb + (size_t)nb * 4194304;

  wqkv_perm<<<768, 256, 0, stream>>>(W_qkv, wq_bf);
  w_to_bf16<<<512, 256, 0, stream>>>(W_proj, wproj_bf, 131072);
  w_to_bf16<<<1024, 256, 0, stream>>>(W_e, we_bf, 262144);
  w_to_bf16<<<1024, 256, 0, stream>>>(W_p, wp_bf, 262144);

  for (int b0 = 0; b0 < 8; b0 += nb) {
    const float* x_c = x + (size_t)b0 * 256 * NPIX;
    float* out_c = out + (size_t)b0 * 256 * NPIX;

    x_to_nhwc<<<dim3(64, 8, nb), 256, 0, stream>>>(x_c, xn);
    mfma_gemm<0><<<dim3(32, 6, nb), 256, 0, stream>>>(wq_bf, xn, qkvb, nullptr,
                                                      768, 256, nullptr, nullptr, nullptr);
    dw5pw_nhwc<<<dim3(32, 24, nb), 256, 0, stream>>>(qkvb, W_dw5, W_pw, agb);
    vk_part<<<dim3(32, 2, nb), 256, 0, stream>>>(qkvb, agb, partial);
    vk_reduce<<<nb * 16, 256, 0, stream>>>(partial, svkT, dvec);
    att_pix<<<dim3(512, 1, nb), 256, 0, stream>>>(qkvb, agb, svkT, dvec, attb);
    mfma_gemm<1><<<dim3(32, 2, nb), 256, 0, stream>>>(wproj_bf, attb, yb, nullptr,
                                                      256, 512, g_proj, b_proj, xn);
    mfma_gemm<2><<<dim3(32, 8, nb), 256, 0, stream>>>(we_bf, yb, eb, nullptr,
                                                      1024, 256, b_e, nullptr, nullptr);
    dw3_nhwc<<<nb * 128, 256, 0, stream>>>(eb, W_dw3, b_dw3, db);
    mfma_gemm<3><<<dim3(32, 2, nb), 256, 0, stream>>>(wp_bf, db, nullptr, out_c,
                                                      256, 1024, g_p, b_p, yb);
  }
}

// Round 6
// 447.931 us; speedup vs baseline: 2.9996x; 1.0434x over previous
//
#include <hip/hip_runtime.h>

typedef __bf16 bf16;
typedef __attribute__((ext_vector_type(8))) __bf16 bf16x8;
typedef __attribute__((ext_vector_type(4))) __bf16 bf16x4;
typedef __attribute__((ext_vector_type(2))) __bf16 bf16x2;
typedef __attribute__((ext_vector_type(4))) float f32x4;
typedef __attribute__((ext_vector_type(2))) float f32x2;

static constexpr int NPIX = 4096;                    // 64*64
static constexpr float BN_SC = 0.9999950000374997f;  // 1/sqrt(1+1e-5)
static constexpr float ATT_EPS = 1e-15f;

__device__ __forceinline__ float hswish_f(float v) {
  return v * fminf(fmaxf(v + 3.0f, 0.0f), 6.0f) * (1.0f / 6.0f);
}

__device__ __forceinline__ void gload16(const void* g, void* l) {
  __builtin_amdgcn_global_load_lds(
      (const __attribute__((address_space(1))) unsigned int*)g,
      (__attribute__((address_space(3))) unsigned int*)l, 16, 0, 0);
}

__device__ __forceinline__ float b2f_lo(unsigned int u) {
  union { unsigned int i; float f; } v; v.i = u << 16; return v.f;
}
__device__ __forceinline__ float b2f_hi(unsigned int u) {
  union { unsigned int i; float f; } v; v.i = u & 0xffff0000u; return v.f;
}
__device__ __forceinline__ unsigned short f2b_u(float f) {
  union { float f; unsigned int i; } v; v.f = f;
  unsigned int r = v.i + 0x7FFFu + ((v.i >> 16) & 1u);
  return (unsigned short)(r >> 16);
}

// ---------------- x (f32 NCHW) -> x_nhwc (bf16) ----------------
__global__ __launch_bounds__(256)
void x_to_nhwc(const float* __restrict__ x, bf16* __restrict__ xn) {
  __shared__ float t[32][65];
  const int img = blockIdx.z;
  const int n0 = blockIdx.x * 64, c0 = blockIdx.y * 32;
  const int tid = threadIdx.x;
  const float* xb = x + ((size_t)img * 256 + c0) * NPIX + n0;
  {
    const int col = tid & 63, r0 = tid >> 6;
#pragma unroll
    for (int i = 0; i < 8; ++i) {
      const int r = r0 + i * 4;
      t[r][col] = xb[(size_t)r * NPIX + col];
    }
  }
  __syncthreads();
  const int n = tid & 63, cq = tid >> 6;
  bf16x8 v;
#pragma unroll
  for (int j = 0; j < 8; ++j) v[j] = (bf16)t[cq * 8 + j][n];
  *(bf16x8*)(xn + ((size_t)img * NPIX + n0 + n) * 256 + c0 + cq * 8) = v;
}

// ---------------- f32 -> bf16 weight convert (plain) ----------------
__global__ void w_to_bf16(const float* __restrict__ w, bf16* __restrict__ o, int n) {
  const int i = blockIdx.x * 256 + threadIdx.x;
  if (i < n) o[i] = (bf16)w[i];
}

// ---------------- W_qkv permuted convert: new row t*256+h*32+d <- old h*96+t*32+d --
__global__ void wqkv_perm(const float* __restrict__ w, bf16* __restrict__ o) {
  const int row = blockIdx.x;  // 0..767 (new index)
  const int t = row >> 8, r = row & 255, h = r >> 5, d = r & 31;
  const int oldrow = h * 96 + t * 32 + d;
  o[row * 256 + threadIdx.x] = (bf16)w[oldrow * 256 + threadIdx.x];
}

// ---------------- MFMA GEMM: D[m][n] = sum_k A[m][k] * B[n][k]  (both K-contig) ----
template<int EPI>
__global__ __launch_bounds__(256, 3)
void mfma_gemm(const bf16* __restrict__ A, const bf16* __restrict__ Bact,
               bf16* __restrict__ Yb, float* __restrict__ Yf,
               const int M, const int K,
               const float* __restrict__ p0, const float* __restrict__ p1,
               const bf16* __restrict__ res)
{
  __shared__ __attribute__((aligned(16))) char ldsA[16384];
  __shared__ __attribute__((aligned(16))) char ldsB[16384];
  const int img = blockIdx.z;
  const int n0 = blockIdx.x * 128;
  const int m0 = blockIdx.y * 128;
  const bf16* Bi = Bact + (size_t)img * NPIX * K;
  const int tid = threadIdx.x;
  const int w = tid >> 6, l = tid & 63;
  const int g = l >> 4, ln = l & 15;
  const int wr = w >> 1, wc = w & 1;
  const int lrow = l >> 3;                       // 0..7
  const int sofs = (((l & 7) ^ lrow) << 4);      // swizzled byte offset in row

  f32x4 acc[4][4];
#pragma unroll
  for (int i = 0; i < 4; ++i)
#pragma unroll
    for (int j = 0; j < 4; ++j) acc[i][j] = (f32x4){0.f, 0.f, 0.f, 0.f};

  const char* Abase = (const char*)(A + (size_t)m0 * K);
  const char* Bbase = (const char*)(Bi + (size_t)n0 * K);
  const size_t rowb = (size_t)K * 2;
  const int swz = (ln & 7) << 4;

  const int nk = K >> 6;
  for (int kt = 0; kt < nk; ++kt) {
    const int k0b = kt << 7;
#pragma unroll
    for (int i = 0; i < 4; ++i) {
      const int q = (w << 2) + i;
      const int r = q * 8 + lrow;
      gload16(Abase + (size_t)r * rowb + k0b + sofs, ldsA + q * 1024);
    }
#pragma unroll
    for (int i = 0; i < 4; ++i) {
      const int q = (w << 2) + i;
      const int r = q * 8 + lrow;
      gload16(Bbase + (size_t)r * rowb + k0b + sofs, ldsB + q * 1024);
    }
    __syncthreads();
#pragma unroll
    for (int kk = 0; kk < 2; ++kk) {
      bf16x8 av[4], bv[4];
#pragma unroll
      for (int f = 0; f < 4; ++f) {
        const int ra = wr * 64 + f * 16 + ln;
        const int rb = wc * 64 + f * 16 + ln;
        const int kb = kk * 64 + (g << 4);
        av[f] = *(const bf16x8*)(ldsA + ra * 128 + (kb ^ swz));
        bv[f] = *(const bf16x8*)(ldsB + rb * 128 + (kb ^ swz));
      }
#pragma unroll
      for (int fi = 0; fi < 4; ++fi)
#pragma unroll
        for (int fj = 0; fj < 4; ++fj)
          acc[fi][fj] = __builtin_amdgcn_mfma_f32_16x16x32_bf16(
              av[fi], bv[fj], acc[fi][fj], 0, 0, 0);
    }
    __syncthreads();
  }

#pragma unroll
  for (int fi = 0; fi < 4; ++fi) {
    const int m4 = m0 + wr * 64 + fi * 16 + g * 4;
    f32x4 P0 = {0.f, 0.f, 0.f, 0.f}, P1 = {0.f, 0.f, 0.f, 0.f};
    if (EPI == 1 || EPI == 3) { P0 = *(const f32x4*)(p0 + m4); P1 = *(const f32x4*)(p1 + m4); }
    if (EPI == 2) { P0 = *(const f32x4*)(p0 + m4); }
#pragma unroll
    for (int fj = 0; fj < 4; ++fj) {
      const int n = n0 + wc * 64 + fj * 16 + ln;
      if (EPI == 3) {
        const bf16x4 yr = *(const bf16x4*)(res + ((size_t)img * NPIX + n) * 256 + m4);
        float* op = Yf + ((size_t)img * 256 + m4) * NPIX + n;
#pragma unroll
        for (int r = 0; r < 4; ++r)
          op[(size_t)r * NPIX] = P0[r] * BN_SC * acc[fi][fj][r] + P1[r] + (float)yr[r];
      } else {
        bf16x4 sv;
        if (EPI == 0) {
#pragma unroll
          for (int r = 0; r < 4; ++r) sv[r] = (bf16)acc[fi][fj][r];
        } else if (EPI == 1) {
          const bf16x4 xr = *(const bf16x4*)(res + ((size_t)img * NPIX + n) * 256 + m4);
#pragma unroll
          for (int r = 0; r < 4; ++r)
            sv[r] = (bf16)(P0[r] * BN_SC * acc[fi][fj][r] + P1[r] + (float)xr[r]);
        } else {
#pragma unroll
          for (int r = 0; r < 4; ++r)
            sv[r] = (bf16)hswish_f(acc[fi][fj][r] + P0[r]);
        }
        *(bf16x4*)(Yb + ((size_t)img * NPIX + n) * M + m4) = sv;
      }
    }
  }
}

// ---------------- fused dw5x5 + per-group 32x32 pointwise (NHWC, permuted groups) --
// v3: pk_fma float2 math, weights direct from global (LDS 38.7KB -> 4 blocks/CU)
__global__ __launch_bounds__(256)
void dw5pw_nhwc(const bf16* __restrict__ qkv, const float* __restrict__ W5,
                const float* __restrict__ Wpw, bf16* __restrict__ ag) {
  const int gch = blockIdx.y, img = blockIdx.z;
  const int t_ = gch >> 3, hh_ = gch & 7;
  const int n0 = blockIdx.x * 128;
  const int r0 = n0 >> 6;
  __shared__ __attribute__((aligned(16))) unsigned int sInT[16 * 412];  // 26368 B
  __shared__ __attribute__((aligned(16))) unsigned int sS32[128 * 20];  // 10240 B
  __shared__ __attribute__((aligned(16))) bf16 sPw[32 * 32];            // 2048 B
  const int tid = threadIdx.x;
  for (int i = tid; i < 1024; i += 256) sPw[i] = (bf16)Wpw[(hh_ * 3 + t_) * 1024 + i];
  for (int i = tid; i < 408 * 16; i += 256) {
    const int ci = i & 15, hp = i >> 4;
    const int hr = hp / 68, hc = hp - hr * 68;
    const int gr = r0 + hr - 2, gc = hc - 2;
    unsigned int vv = 0;
    if (gr >= 0 && gr < 64 && gc >= 0 && gc < 64)
      vv = *(const unsigned int*)(qkv + ((size_t)img * NPIX + gr * 64 + gc) * 768 + gch * 32 + ci * 2);
    sInT[ci * 412 + hp] = vv;
  }
  // per-thread dw weights for channels {2ci, 2ci+1} as float2
  const int ci = tid & 15;
  f32x2 w2[25];
  {
    const float* wp0 = W5 + (size_t)(hh_ * 96 + t_ * 32 + 2 * ci) * 25;
#pragma unroll
    for (int q = 0; q < 25; ++q) w2[q] = (f32x2){wp0[q], wp0[25 + q]};
  }
  __syncthreads();
  {  // phase 1: depthwise 5x5 in packed-f32 pairs
    const int pg = tid >> 4;
    const int p0 = pg * 8;
    const int prow = p0 >> 6, pcol = p0 & 63;
    f32x2 a2[8];
#pragma unroll
    for (int px = 0; px < 8; ++px) a2[px] = (f32x2){0.f, 0.f};
#pragma unroll
    for (int ky = 0; ky < 5; ++ky) {
      const unsigned int* wp = &sInT[ci * 412 + (prow + ky) * 68 + pcol];
      const uint4 qa = *(const uint4*)wp;
      const uint4 qb = *(const uint4*)(wp + 4);
      const uint4 qc = *(const uint4*)(wp + 8);
      const unsigned int win[12] = {qa.x, qa.y, qa.z, qa.w, qb.x, qb.y, qb.z, qb.w,
                                    qc.x, qc.y, qc.z, qc.w};
      f32x2 val[12];
#pragma unroll
      for (int j = 0; j < 12; ++j) val[j] = (f32x2){b2f_lo(win[j]), b2f_hi(win[j])};
#pragma unroll
      for (int px = 0; px < 8; ++px)
#pragma unroll
        for (int kx = 0; kx < 5; ++kx)
          a2[px] = val[px + kx] * w2[ky * 5 + kx] + a2[px];   // v_pk_fma_f32
    }
#pragma unroll
    for (int px = 0; px < 8; ++px) {
      const unsigned int pk = (unsigned int)f2b_u(a2[px][0]) | ((unsigned int)f2b_u(a2[px][1]) << 16);
      sS32[(p0 + px) * 20 + ci] = pk;
    }
  }
  __syncthreads();
  {  // phase 2: pw 32x32 via MFMA
    const int w = tid >> 6, l = tid & 63;
    const int lg = l >> 4, ln = l & 15;
    f32x4 acc[2][2];
#pragma unroll
    for (int i = 0; i < 2; ++i)
#pragma unroll
      for (int j = 0; j < 2; ++j) acc[i][j] = (f32x4){0.f, 0.f, 0.f, 0.f};
    bf16x8 av[2], bv[2];
#pragma unroll
    for (int et = 0; et < 2; ++et)
      av[et] = *(const bf16x8*)((const char*)sPw + (et * 16 + ln) * 64 + lg * 16);
#pragma unroll
    for (int pt = 0; pt < 2; ++pt)
      bv[pt] = *(const bf16x8*)((const char*)sS32 + ((2 * w + pt) * 16 + ln) * 80 + lg * 16);
#pragma unroll
    for (int et = 0; et < 2; ++et)
#pragma unroll
      for (int pt = 0; pt < 2; ++pt)
        acc[et][pt] = __builtin_amdgcn_mfma_f32_16x16x32_bf16(av[et], bv[pt], acc[et][pt], 0, 0, 0);
#pragma unroll
    for (int et = 0; et < 2; ++et)
#pragma unroll
      for (int pt = 0; pt < 2; ++pt) {
        const int e0 = et * 16 + lg * 4;
        const int p = n0 + (2 * w + pt) * 16 + ln;
        bf16x4 sv;
#pragma unroll
        for (int r = 0; r < 4; ++r) sv[r] = (bf16)acc[et][pt][r];
        *(bf16x4*)(ag + ((size_t)img * NPIX + p) * 768 + gch * 32 + e0) = sv;
      }
  }
}

// ---------------- vk partial: per (chunk128, src, img) ----------------
__global__ __launch_bounds__(256)
void vk_part(const bf16* __restrict__ qkv, const bf16* __restrict__ ag,
             float* __restrict__ partial) {
  const int chunk = blockIdx.x, src = blockIdx.y, img = blockIdx.z;
  const bf16* base = (src == 0 ? qkv : ag) + (size_t)img * NPIX * 768 + 256;
  __shared__ __attribute__((aligned(16))) char tile[32 * 1024];
  const int tid = threadIdx.x;
  const int e2 = tid & 15, sd = tid >> 4;
  const int spx = tid >> 3, sseg = tid & 7;
  float acc[8][2][2] = {};
  float accd[8][2] = {};
  for (int sub = 0; sub < 4; ++sub) {
    __syncthreads();
    {
      const int px0 = chunk * 128 + sub * 32;
      const char* gp = (const char*)(base + (size_t)(px0 + spx) * 768) + sseg * 128;
      char* lp = tile + spx * 1024;
      const int swz = (spx & 7) << 4;
#pragma unroll
      for (int i = 0; i < 8; ++i) {
        const uint4 v = *(const uint4*)(gp + i * 16);
        *(uint4*)(lp + ((sseg * 128 + i * 16) ^ swz)) = v;
      }
    }
    __syncthreads();
    for (int nn = 0; nn < 32; ++nn) {
      const char* row = tile + nn * 1024;
      const int swzn = (nn & 7) << 4;
#pragma unroll
      for (int h = 0; h < 8; ++h) {
        const unsigned int kk = *(const unsigned int*)(row + ((h * 64 + e2 * 4) ^ swzn));
        const float k0 = fmaxf(b2f_lo(kk), 0.f), k1 = fmaxf(b2f_hi(kk), 0.f);
        const unsigned int vv = *(const unsigned int*)(row + ((512 + h * 64 + sd * 4) ^ swzn));
        const float v0 = b2f_lo(vv), v1 = b2f_hi(vv);
        acc[h][0][0] = fmaf(v0, k0, acc[h][0][0]);
        acc[h][0][1] = fmaf(v0, k1, acc[h][0][1]);
        acc[h][1][0] = fmaf(v1, k0, acc[h][1][0]);
        acc[h][1][1] = fmaf(v1, k1, acc[h][1][1]);
        accd[h][0] += k0; accd[h][1] += k1;
      }
    }
  }
  float* pb = partial + ((size_t)((img * 2 + src) * 32 + chunk)) * 8448;
#pragma unroll
  for (int h = 0; h < 8; ++h) {
#pragma unroll
    for (int dj = 0; dj < 2; ++dj)
#pragma unroll
      for (int ej = 0; ej < 2; ++ej)
        pb[h * 1056 + (sd * 2 + dj) * 32 + e2 * 2 + ej] = acc[h][dj][ej];
    if (sd == 0) {
      pb[h * 1056 + 1024 + e2 * 2]     = accd[h][0];
      pb[h * 1056 + 1024 + e2 * 2 + 1] = accd[h][1];
    }
  }
}

// ---------------- vk reduce ----------------
__global__ __launch_bounds__(256)
void vk_reduce(const float* __restrict__ partial, bf16* __restrict__ svkT,
               float* __restrict__ dvec) {
  const int h = blockIdx.x & 15, img = blockIdx.x >> 4;
  const int tid = threadIdx.x;
  const int e = tid & 31, dq = tid >> 5;
  const int src = h >> 3, hh = h & 7;
  const float* pb = partial + (size_t)((img * 2 + src) * 32) * 8448 + hh * 1056;
  float a[4] = {};
  for (int c = 0; c < 32; ++c) {
    const float* pc = pb + (size_t)c * 8448;
#pragma unroll
    for (int j = 0; j < 4; ++j) a[j] += pc[(dq * 4 + j) * 32 + e];
  }
  bf16x4 o;
#pragma unroll
  for (int j = 0; j < 4; ++j) o[j] = (bf16)a[j];
  *(bf16x4*)(svkT + (((size_t)img * 16 + h) * 32 + e) * 32 + dq * 4) = o;
  if (dq == 0) {
    float ds = 0.f;
    for (int c = 0; c < 32; ++c) ds += pb[(size_t)c * 8448 + 1024 + e];
    dvec[((size_t)img * 16 + h) * 32 + e] = ds;
  }
}

// ---------------- attention apply ----------------
__global__ __launch_bounds__(256)
void att_pix(const bf16* __restrict__ qkv, const bf16* __restrict__ ag,
             const bf16* __restrict__ svkT, const float* __restrict__ dvec,
             bf16* __restrict__ att) {
  const int pc = blockIdx.x;
  const int img = blockIdx.z;
  __shared__ float sq[8][516];
  __shared__ __attribute__((aligned(16))) bf16 ssvk[16 * 1024];
  __shared__ float sdv[16 * 32];
  const int tid = threadIdx.x;
  const int px0 = pc * 8;
  {
    const int px = tid >> 5, part = tid & 31;
    const bf16* srcp = (part < 16 ? qkv : ag) + (size_t)(img * NPIX + px0 + px) * 768 + (part & 15) * 16;
    const bf16x8 v0 = *(const bf16x8*)srcp;
    const bf16x8 v1 = *(const bf16x8*)(srcp + 8);
    const int c0 = (part < 16 ? 0 : 256) + (part & 15) * 16;
#pragma unroll
    for (int j = 0; j < 8; ++j) {
      sq[px][c0 + j]     = fmaxf((float)v0[j], 0.f);
      sq[px][c0 + 8 + j] = fmaxf((float)v1[j], 0.f);
    }
  }
  {
    const bf16* sb = svkT + (size_t)img * 16384;
    for (int i = tid; i < 2048; i += 256)
      *(bf16x8*)(ssvk + i * 8) = *(const bf16x8*)(sb + i * 8);
    const float* db = dvec + (size_t)img * 512;
    for (int i = tid; i < 512; i += 256) sdv[i] = db[i];
  }
  __syncthreads();
  const int s = tid & 31, px = tid >> 5;
  const int shalf = s >> 4, sd = s & 15, d0 = sd * 2;
  const unsigned int* sv32 = (const unsigned int*)ssvk;
  bf16* ob = att + (size_t)(img * NPIX + px0 + px) * 512;
#pragma unroll
  for (int hh = 0; hh < 8; ++hh) {
    const int h = shalf * 8 + hh;
    const float* qp = &sq[px][h * 32];
    const unsigned int* kp = sv32 + h * 512 + sd;
    const float* dp = &sdv[h * 32];
    float a0 = 0.f, a1 = 0.f, den = 0.f;
#pragma unroll
    for (int ee = 0; ee < 32; ++ee) {
      const float qf = qp[ee];
      const unsigned int wv = kp[ee * 16];
      a0 = fmaf(qf, b2f_lo(wv), a0);
      a1 = fmaf(qf, b2f_hi(wv), a1);
      den = fmaf(qf, dp[ee], den);
    }
    const float inv = 1.f / (den + ATT_EPS);
    bf16x2 o; o[0] = (bf16)(a0 * inv); o[1] = (bf16)(a1 * inv);
    *(bf16x2*)(ob + h * 32 + d0) = o;
  }
}

// ---------------- depthwise 3x3 + bias + hswish (NHWC, 1024 ch) ----------------
__global__ __launch_bounds__(256)
void dw3_nhwc(const bf16* __restrict__ ein, const float* __restrict__ w3,
              const float* __restrict__ bias, bf16* __restrict__ dout) {
  const int idx = blockIdx.x * 256 + threadIdx.x;
  const int c8 = idx & 127;
  const int seg = idx >> 7;
  const int img = seg >> 8;
  const int p0 = (seg & 255) * 16;
  const int ch = c8 * 8;
  float wr_[9][8];
#pragma unroll
  for (int j = 0; j < 8; ++j)
#pragma unroll
    for (int q = 0; q < 9; ++q) wr_[q][j] = w3[(ch + j) * 9 + q];
  const f32x4 b0 = *(const f32x4*)(bias + ch), b1 = *(const f32x4*)(bias + ch + 4);
  const int row = p0 >> 6, col0 = p0 & 63;
  const bf16* ib = ein + (size_t)img * NPIX * 1024 + ch;
  bf16* ob = dout + (size_t)img * NPIX * 1024 + ch;
  for (int pp = 0; pp < 16; ++pp) {
    const int col = col0 + pp;
    float a[8] = {b0[0], b0[1], b0[2], b0[3], b1[0], b1[1], b1[2], b1[3]};
#pragma unroll
    for (int ky = 0; ky < 3; ++ky) {
      const int r = row + ky - 1;
      if (r < 0 || r > 63) continue;
#pragma unroll
      for (int kx = 0; kx < 3; ++kx) {
        const int cc = col + kx - 1;
        if (cc < 0 || cc > 63) continue;
        const bf16x8 v = *(const bf16x8*)(ib + (size_t)(r * 64 + cc) * 1024);
#pragma unroll
        for (int j = 0; j < 8; ++j) a[j] += wr_[ky * 3 + kx][j] * (float)v[j];
      }
    }
    bf16x8 o;
#pragma unroll
    for (int j = 0; j < 8; ++j) o[j] = (bf16)hswish_f(a[j]);
    *(bf16x8*)(ob + (size_t)(row * 64 + col) * 1024) = o;
  }
}

// ---------------- launch ----------------
extern "C" void kernel_launch(void* const* d_in, const int* in_sizes, int n_in,
                              void* d_out, int out_size, void* d_ws, size_t ws_size,
                              hipStream_t stream) {
  const float* x      = (const float*)d_in[0];
  const float* W_qkv  = (const float*)d_in[1];
  const float* W_dw5  = (const float*)d_in[2];
  const float* W_pw   = (const float*)d_in[3];
  const float* W_proj = (const float*)d_in[4];
  const float* g_proj = (const float*)d_in[5];
  const float* b_proj = (const float*)d_in[6];
  const float* W_e    = (const float*)d_in[7];
  const float* b_e    = (const float*)d_in[8];
  const float* W_dw3  = (const float*)d_in[9];
  const float* b_dw3  = (const float*)d_in[10];
  const float* W_p    = (const float*)d_in[11];
  const float* g_p    = (const float*)d_in[12];
  const float* b_p    = (const float*)d_in[13];
  float* out = (float*)d_out;

  int nb = 8;
  while (nb > 1) {
    size_t need = (size_t)nb * 23169024ull + 1703936ull + 1024;
    if (need <= ws_size) break;
    nb >>= 1;
  }

  char* p = (char*)d_ws;
  float* partial = (float*)p;                 p += (size_t)nb * 2162688;
  float* dvec    = (float*)p;                 p += (size_t)nb * 2048;
  bf16* wq_bf    = (bf16*)p;                  p += 196608ull * 2;
  bf16* wproj_bf = (bf16*)p;                  p += 131072ull * 2;
  bf16* we_bf    = (bf16*)p;                  p += 262144ull * 2;
  bf16* wp_bf    = (bf16*)p;                  p += 262144ull * 2;
  bf16* svkT     = (bf16*)p;                  p += (size_t)nb * 32768;
  bf16* arena    = (bf16*)p;
  bf16* xn   = arena;
  bf16* qkvb = arena + (size_t)nb * 1048576;
  bf16* agb  = qkvb + (size_t)nb * 3145728;
  bf16* attb = agb + (size_t)nb * 3145728;
  bf16* yb   = attb + (size_t)nb * 2097152;
  bf16* eb   = qkvb;
  bf16* db   = qkvb + (size_t)nb * 4194304;

  wqkv_perm<<<768, 256, 0, stream>>>(W_qkv, wq_bf);
  w_to_bf16<<<512, 256, 0, stream>>>(W_proj, wproj_bf, 131072);
  w_to_bf16<<<1024, 256, 0, stream>>>(W_e, we_bf, 262144);
  w_to_bf16<<<1024, 256, 0, stream>>>(W_p, wp_bf, 262144);

  for (int b0 = 0; b0 < 8; b0 += nb) {
    const float* x_c = x + (size_t)b0 * 256 * NPIX;
    float* out_c = out + (size_t)b0 * 256 * NPIX;

    x_to_nhwc<<<dim3(64, 8, nb), 256, 0, stream>>>(x_c, xn);
    mfma_gemm<0><<<dim3(32, 6, nb), 256, 0, stream>>>(wq_bf, xn, qkvb, nullptr,
                                                      768, 256, nullptr, nullptr, nullptr);
    dw5pw_nhwc<<<dim3(32, 24, nb), 256, 0, stream>>>(qkvb, W_dw5, W_pw, agb);
    vk_part<<<dim3(32, 2, nb), 256, 0, stream>>>(qkvb, agb, partial);
    vk_reduce<<<nb * 16, 256, 0, stream>>>(partial, svkT, dvec);
    att_pix<<<dim3(512, 1, nb), 256, 0, stream>>>(qkvb, agb, svkT, dvec, attb);
    mfma_gemm<1><<<dim3(32, 2, nb), 256, 0, stream>>>(wproj_bf, attb, yb, nullptr,
                                                      256, 512, g_proj, b_proj, xn);
    mfma_gemm<2><<<dim3(32, 8, nb), 256, 0, stream>>>(we_bf, yb, eb, nullptr,
                                                      1024, 256, b_e, nullptr, nullptr);
    dw3_nhwc<<<nb * 128, 256, 0, stream>>>(eb, W_dw3, b_dw3, db);
    mfma_gemm<3><<<dim3(32, 2, nb), 256, 0, stream>>>(wp_bf, db, nullptr, out_c,
                                                      256, 1024, g_p, b_p, yb);
  }
}

// Round 7
// 405.305 us; speedup vs baseline: 3.3150x; 1.1052x over previous
//
#include <hip/hip_runtime.h>

typedef __bf16 bf16;
typedef __attribute__((ext_vector_type(8))) __bf16 bf16x8;
typedef __attribute__((ext_vector_type(4))) __bf16 bf16x4;
typedef __attribute__((ext_vector_type(2))) __bf16 bf16x2;
typedef __attribute__((ext_vector_type(4))) float f32x4;
typedef __attribute__((ext_vector_type(2))) float f32x2;

static constexpr int NPIX = 4096;                    // 64*64
static constexpr float BN_SC = 0.9999950000374997f;  // 1/sqrt(1+1e-5)
static constexpr float ATT_EPS = 1e-15f;

__device__ __forceinline__ float hswish_f(float v) {
  return v * fminf(fmaxf(v + 3.0f, 0.0f), 6.0f) * (1.0f / 6.0f);
}

__device__ __forceinline__ void gload16(const void* g, void* l) {
  __builtin_amdgcn_global_load_lds(
      (const __attribute__((address_space(1))) unsigned int*)g,
      (__attribute__((address_space(3))) unsigned int*)l, 16, 0, 0);
}

__device__ __forceinline__ float b2f_lo(unsigned int u) {
  union { unsigned int i; float f; } v; v.i = u << 16; return v.f;
}
__device__ __forceinline__ float b2f_hi(unsigned int u) {
  union { unsigned int i; float f; } v; v.i = u & 0xffff0000u; return v.f;
}
__device__ __forceinline__ unsigned short f2b_u(float f) {
  union { float f; unsigned int i; } v; v.f = f;
  unsigned int r = v.i + 0x7FFFu + ((v.i >> 16) & 1u);
  return (unsigned short)(r >> 16);
}

// ---------------- x (f32 NCHW) -> x_nhwc (bf16) ----------------
__global__ __launch_bounds__(256)
void x_to_nhwc(const float* __restrict__ x, bf16* __restrict__ xn) {
  __shared__ float t[32][65];
  const int img = blockIdx.z;
  const int n0 = blockIdx.x * 64, c0 = blockIdx.y * 32;
  const int tid = threadIdx.x;
  const float* xb = x + ((size_t)img * 256 + c0) * NPIX + n0;
  {
    const int col = tid & 63, r0 = tid >> 6;
#pragma unroll
    for (int i = 0; i < 8; ++i) {
      const int r = r0 + i * 4;
      t[r][col] = xb[(size_t)r * NPIX + col];
    }
  }
  __syncthreads();
  const int n = tid & 63, cq = tid >> 6;
  bf16x8 v;
#pragma unroll
  for (int j = 0; j < 8; ++j) v[j] = (bf16)t[cq * 8 + j][n];
  *(bf16x8*)(xn + ((size_t)img * NPIX + n0 + n) * 256 + c0 + cq * 8) = v;
}

// ---------------- merged f32 -> bf16 weight convert (proj | e | p) ----------------
__global__ void wcvt3(const float* __restrict__ W_proj, const float* __restrict__ W_e,
                      const float* __restrict__ W_p, bf16* __restrict__ o_proj,
                      bf16* __restrict__ o_e, bf16* __restrict__ o_p) {
  const int i = blockIdx.x * 256 + threadIdx.x;
  if (i < 131072) o_proj[i] = (bf16)W_proj[i];
  else if (i < 393216) o_e[i - 131072] = (bf16)W_e[i - 131072];
  else o_p[i - 393216] = (bf16)W_p[i - 393216];
}

// ---------------- W_qkv permuted convert: new row t*256+h*32+d <- old h*96+t*32+d --
__global__ void wqkv_perm(const float* __restrict__ w, bf16* __restrict__ o) {
  const int row = blockIdx.x;  // 0..767 (new index)
  const int t = row >> 8, r = row & 255, h = r >> 5, d = r & 31;
  const int oldrow = h * 96 + t * 32 + d;
  o[row * 256 + threadIdx.x] = (bf16)w[oldrow * 256 + threadIdx.x];
}

// ---------------- MFMA GEMM: D[m][n] = sum_k A[m][k] * B[n][k]  (both K-contig) ----
template<int EPI>
__global__ __launch_bounds__(256, 3)
void mfma_gemm(const bf16* __restrict__ A, const bf16* __restrict__ Bact,
               bf16* __restrict__ Yb, float* __restrict__ Yf,
               const int M, const int K,
               const float* __restrict__ p0, const float* __restrict__ p1,
               const bf16* __restrict__ res)
{
  __shared__ __attribute__((aligned(16))) char ldsA[16384];
  __shared__ __attribute__((aligned(16))) char ldsB[16384];
  const int img = blockIdx.z;
  const int n0 = blockIdx.x * 128;
  const int m0 = blockIdx.y * 128;
  const bf16* Bi = Bact + (size_t)img * NPIX * K;
  const int tid = threadIdx.x;
  const int w = tid >> 6, l = tid & 63;
  const int g = l >> 4, ln = l & 15;
  const int wr = w >> 1, wc = w & 1;
  const int lrow = l >> 3;                       // 0..7
  const int sofs = (((l & 7) ^ lrow) << 4);      // swizzled byte offset in row

  f32x4 acc[4][4];
#pragma unroll
  for (int i = 0; i < 4; ++i)
#pragma unroll
    for (int j = 0; j < 4; ++j) acc[i][j] = (f32x4){0.f, 0.f, 0.f, 0.f};

  const char* Abase = (const char*)(A + (size_t)m0 * K);
  const char* Bbase = (const char*)(Bi + (size_t)n0 * K);
  const size_t rowb = (size_t)K * 2;
  const int swz = (ln & 7) << 4;

  const int nk = K >> 6;
  for (int kt = 0; kt < nk; ++kt) {
    const int k0b = kt << 7;
#pragma unroll
    for (int i = 0; i < 4; ++i) {
      const int q = (w << 2) + i;
      const int r = q * 8 + lrow;
      gload16(Abase + (size_t)r * rowb + k0b + sofs, ldsA + q * 1024);
    }
#pragma unroll
    for (int i = 0; i < 4; ++i) {
      const int q = (w << 2) + i;
      const int r = q * 8 + lrow;
      gload16(Bbase + (size_t)r * rowb + k0b + sofs, ldsB + q * 1024);
    }
    __syncthreads();
#pragma unroll
    for (int kk = 0; kk < 2; ++kk) {
      bf16x8 av[4], bv[4];
#pragma unroll
      for (int f = 0; f < 4; ++f) {
        const int ra = wr * 64 + f * 16 + ln;
        const int rb = wc * 64 + f * 16 + ln;
        const int kb = kk * 64 + (g << 4);
        av[f] = *(const bf16x8*)(ldsA + ra * 128 + (kb ^ swz));
        bv[f] = *(const bf16x8*)(ldsB + rb * 128 + (kb ^ swz));
      }
#pragma unroll
      for (int fi = 0; fi < 4; ++fi)
#pragma unroll
        for (int fj = 0; fj < 4; ++fj)
          acc[fi][fj] = __builtin_amdgcn_mfma_f32_16x16x32_bf16(
              av[fi], bv[fj], acc[fi][fj], 0, 0, 0);
    }
    __syncthreads();
  }

#pragma unroll
  for (int fi = 0; fi < 4; ++fi) {
    const int m4 = m0 + wr * 64 + fi * 16 + g * 4;
    f32x4 P0 = {0.f, 0.f, 0.f, 0.f}, P1 = {0.f, 0.f, 0.f, 0.f};
    if (EPI == 1 || EPI == 3) { P0 = *(const f32x4*)(p0 + m4); P1 = *(const f32x4*)(p1 + m4); }
    if (EPI == 2) { P0 = *(const f32x4*)(p0 + m4); }
#pragma unroll
    for (int fj = 0; fj < 4; ++fj) {
      const int n = n0 + wc * 64 + fj * 16 + ln;
      if (EPI == 3) {
        const bf16x4 yr = *(const bf16x4*)(res + ((size_t)img * NPIX + n) * 256 + m4);
        float* op = Yf + ((size_t)img * 256 + m4) * NPIX + n;
#pragma unroll
        for (int r = 0; r < 4; ++r)
          op[(size_t)r * NPIX] = P0[r] * BN_SC * acc[fi][fj][r] + P1[r] + (float)yr[r];
      } else {
        bf16x4 sv;
        if (EPI == 0) {
#pragma unroll
          for (int r = 0; r < 4; ++r) sv[r] = (bf16)acc[fi][fj][r];
        } else if (EPI == 1) {
          const bf16x4 xr = *(const bf16x4*)(res + ((size_t)img * NPIX + n) * 256 + m4);
#pragma unroll
          for (int r = 0; r < 4; ++r)
            sv[r] = (bf16)(P0[r] * BN_SC * acc[fi][fj][r] + P1[r] + (float)xr[r]);
        } else {
#pragma unroll
          for (int r = 0; r < 4; ++r)
            sv[r] = (bf16)hswish_f(acc[fi][fj][r] + P0[r]);
        }
        *(bf16x4*)(Yb + ((size_t)img * NPIX + n) * M + m4) = sv;
      }
    }
  }
}

// ---------------- fused dw5x5 + per-group 32x32 pointwise (NHWC), v4 ----------------
// 512 thr, tile = 256 px (4 image rows), halo 8x68.  uint4 staging.
__global__ __launch_bounds__(512)
void dw5pw_nhwc(const bf16* __restrict__ qkv, const float* __restrict__ W5,
                const float* __restrict__ Wpw, bf16* __restrict__ ag) {
  const int gch = blockIdx.y, img = blockIdx.z;
  const int t_ = gch >> 3, hh_ = gch & 7;
  const int n0 = blockIdx.x * 256;
  const int r0 = n0 >> 6;                        // first of 4 image rows
  __shared__ __attribute__((aligned(16))) unsigned int sInT[16 * 548];  // 35072 B
  __shared__ __attribute__((aligned(16))) unsigned int sS32[256 * 20];  // 20480 B
  __shared__ __attribute__((aligned(16))) bf16 sPw[32 * 32];            // 2048 B
  const int tid = threadIdx.x;
  for (int i = tid; i < 1024; i += 512) sPw[i] = (bf16)Wpw[(hh_ * 3 + t_) * 1024 + i];
  // halo staging: 544 px * 4 uint4-segments; row r of sInT = channel pair {2r,2r+1}
  for (int i = tid; i < 2176; i += 512) {
    const int s = i & 3, hp = i >> 2;
    const int hr = hp / 68, hc = hp - hr * 68;
    const int gr = r0 + hr - 2, gc = hc - 2;
    uint4 vv = {0u, 0u, 0u, 0u};
    if (gr >= 0 && gr < 64 && gc >= 0 && gc < 64)
      vv = *(const uint4*)(qkv + ((size_t)img * NPIX + gr * 64 + gc) * 768 + gch * 32 + s * 8);
    unsigned int* rp = sInT + (s * 4) * 548 + hp;
    rp[0] = vv.x; rp[548] = vv.y; rp[1096] = vv.z; rp[1644] = vv.w;
  }
  // per-thread dw weights for channels {2ci, 2ci+1}
  const int ci = tid & 15;
  f32x2 w2[25];
  {
    const float* wp0 = W5 + (size_t)(hh_ * 96 + t_ * 32 + 2 * ci) * 25;
#pragma unroll
    for (int q = 0; q < 25; ++q) w2[q] = (f32x2){wp0[q], wp0[25 + q]};
  }
  __syncthreads();
  {  // phase 1: depthwise 5x5, packed f32 pairs; pg 0..31, 8 px each
    const int pg = tid >> 4;
    const int p0 = pg * 8;
    const int prow = p0 >> 6, pcol = p0 & 63;
    f32x2 a2[8];
#pragma unroll
    for (int px = 0; px < 8; ++px) a2[px] = (f32x2){0.f, 0.f};
#pragma unroll
    for (int ky = 0; ky < 5; ++ky) {
      const unsigned int* wp = &sInT[ci * 548 + (prow + ky) * 68 + pcol];
      const uint4 qa = *(const uint4*)wp;
      const uint4 qb = *(const uint4*)(wp + 4);
      const uint4 qc = *(const uint4*)(wp + 8);
      const unsigned int win[12] = {qa.x, qa.y, qa.z, qa.w, qb.x, qb.y, qb.z, qb.w,
                                    qc.x, qc.y, qc.z, qc.w};
      f32x2 val[12];
#pragma unroll
      for (int j = 0; j < 12; ++j) val[j] = (f32x2){b2f_lo(win[j]), b2f_hi(win[j])};
#pragma unroll
      for (int px = 0; px < 8; ++px)
#pragma unroll
        for (int kx = 0; kx < 5; ++kx)
          a2[px] = val[px + kx] * w2[ky * 5 + kx] + a2[px];   // v_pk_fma_f32
    }
#pragma unroll
    for (int px = 0; px < 8; ++px) {
      const unsigned int pk = (unsigned int)f2b_u(a2[px][0]) | ((unsigned int)f2b_u(a2[px][1]) << 16);
      sS32[(p0 + px) * 20 + ci] = pk;
    }
  }
  __syncthreads();
  {  // phase 2: pw 32x32 via MFMA; wave w handles p-tiles {2w, 2w+1}
    const int w = tid >> 6, l = tid & 63;
    const int lg = l >> 4, ln = l & 15;
    f32x4 acc[2][2];
#pragma unroll
    for (int i = 0; i < 2; ++i)
#pragma unroll
      for (int j = 0; j < 2; ++j) acc[i][j] = (f32x4){0.f, 0.f, 0.f, 0.f};
    bf16x8 av[2], bv[2];
#pragma unroll
    for (int et = 0; et < 2; ++et)
      av[et] = *(const bf16x8*)((const char*)sPw + (et * 16 + ln) * 64 + lg * 16);
#pragma unroll
    for (int pt = 0; pt < 2; ++pt)
      bv[pt] = *(const bf16x8*)((const char*)sS32 + ((2 * w + pt) * 16 + ln) * 80 + lg * 16);
#pragma unroll
    for (int et = 0; et < 2; ++et)
#pragma unroll
      for (int pt = 0; pt < 2; ++pt)
        acc[et][pt] = __builtin_amdgcn_mfma_f32_16x16x32_bf16(av[et], bv[pt], acc[et][pt], 0, 0, 0);
#pragma unroll
    for (int et = 0; et < 2; ++et)
#pragma unroll
      for (int pt = 0; pt < 2; ++pt) {
        const int e0 = et * 16 + lg * 4;
        const int p = n0 + (2 * w + pt) * 16 + ln;
        bf16x4 sv;
#pragma unroll
        for (int r = 0; r < 4; ++r) sv[r] = (bf16)acc[et][pt][r];
        *(bf16x4*)(ag + ((size_t)img * NPIX + p) * 768 + gch * 32 + e0) = sv;
      }
  }
}

// ---------------- vk partial: per (chunk128, src, img) ----------------
__global__ __launch_bounds__(256)
void vk_part(const bf16* __restrict__ qkv, const bf16* __restrict__ ag,
             float* __restrict__ partial) {
  const int chunk = blockIdx.x, src = blockIdx.y, img = blockIdx.z;
  const bf16* base = (src == 0 ? qkv : ag) + (size_t)img * NPIX * 768 + 256;
  __shared__ __attribute__((aligned(16))) char tile[32 * 1024];
  const int tid = threadIdx.x;
  const int e2 = tid & 15, sd = tid >> 4;
  const int spx = tid >> 3, sseg = tid & 7;
  float acc[8][2][2] = {};
  float accd[8][2] = {};
  for (int sub = 0; sub < 4; ++sub) {
    __syncthreads();
    {
      const int px0 = chunk * 128 + sub * 32;
      const char* gp = (const char*)(base + (size_t)(px0 + spx) * 768) + sseg * 128;
      char* lp = tile + spx * 1024;
      const int swz = (spx & 7) << 4;
#pragma unroll
      for (int i = 0; i < 8; ++i) {
        const uint4 v = *(const uint4*)(gp + i * 16);
        *(uint4*)(lp + ((sseg * 128 + i * 16) ^ swz)) = v;
      }
    }
    __syncthreads();
    for (int nn = 0; nn < 32; ++nn) {
      const char* row = tile + nn * 1024;
      const int swzn = (nn & 7) << 4;
#pragma unroll
      for (int h = 0; h < 8; ++h) {
        const unsigned int kk = *(const unsigned int*)(row + ((h * 64 + e2 * 4) ^ swzn));
        const float k0 = fmaxf(b2f_lo(kk), 0.f), k1 = fmaxf(b2f_hi(kk), 0.f);
        const unsigned int vv = *(const unsigned int*)(row + ((512 + h * 64 + sd * 4) ^ swzn));
        const float v0 = b2f_lo(vv), v1 = b2f_hi(vv);
        acc[h][0][0] = fmaf(v0, k0, acc[h][0][0]);
        acc[h][0][1] = fmaf(v0, k1, acc[h][0][1]);
        acc[h][1][0] = fmaf(v1, k0, acc[h][1][0]);
        acc[h][1][1] = fmaf(v1, k1, acc[h][1][1]);
        accd[h][0] += k0; accd[h][1] += k1;
      }
    }
  }
  float* pb = partial + ((size_t)((img * 2 + src) * 32 + chunk)) * 8448;
#pragma unroll
  for (int h = 0; h < 8; ++h) {
#pragma unroll
    for (int dj = 0; dj < 2; ++dj)
#pragma unroll
      for (int ej = 0; ej < 2; ++ej)
        pb[h * 1056 + (sd * 2 + dj) * 32 + e2 * 2 + ej] = acc[h][dj][ej];
    if (sd == 0) {
      pb[h * 1056 + 1024 + e2 * 2]     = accd[h][0];
      pb[h * 1056 + 1024 + e2 * 2 + 1] = accd[h][1];
    }
  }
}

// ---------------- vk reduce ----------------
__global__ __launch_bounds__(256)
void vk_reduce(const float* __restrict__ partial, bf16* __restrict__ svkT,
               float* __restrict__ dvec) {
  const int h = blockIdx.x & 15, img = blockIdx.x >> 4;
  const int tid = threadIdx.x;
  const int e = tid & 31, dq = tid >> 5;
  const int src = h >> 3, hh = h & 7;
  const float* pb = partial + (size_t)((img * 2 + src) * 32) * 8448 + hh * 1056;
  float a[4] = {};
  for (int c = 0; c < 32; ++c) {
    const float* pc = pb + (size_t)c * 8448;
#pragma unroll
    for (int j = 0; j < 4; ++j) a[j] += pc[(dq * 4 + j) * 32 + e];
  }
  bf16x4 o;
#pragma unroll
  for (int j = 0; j < 4; ++j) o[j] = (bf16)a[j];
  *(bf16x4*)(svkT + (((size_t)img * 16 + h) * 32 + e) * 32 + dq * 4) = o;
  if (dq == 0) {
    float ds = 0.f;
    for (int c = 0; c < 32; ++c) ds += pb[(size_t)c * 8448 + 1024 + e];
    dvec[((size_t)img * 16 + h) * 32 + e] = ds;
  }
}

// ---------------- attention apply ----------------
__global__ __launch_bounds__(256)
void att_pix(const bf16* __restrict__ qkv, const bf16* __restrict__ ag,
             const bf16* __restrict__ svkT, const float* __restrict__ dvec,
             bf16* __restrict__ att) {
  const int pc = blockIdx.x;
  const int img = blockIdx.z;
  __shared__ float sq[8][516];
  __shared__ __attribute__((aligned(16))) bf16 ssvk[16 * 1024];
  __shared__ float sdv[16 * 32];
  const int tid = threadIdx.x;
  const int px0 = pc * 8;
  {
    const int px = tid >> 5, part = tid & 31;
    const bf16* srcp = (part < 16 ? qkv : ag) + (size_t)(img * NPIX + px0 + px) * 768 + (part & 15) * 16;
    const bf16x8 v0 = *(const bf16x8*)srcp;
    const bf16x8 v1 = *(const bf16x8*)(srcp + 8);
    const int c0 = (part < 16 ? 0 : 256) + (part & 15) * 16;
#pragma unroll
    for (int j = 0; j < 8; ++j) {
      sq[px][c0 + j]     = fmaxf((float)v0[j], 0.f);
      sq[px][c0 + 8 + j] = fmaxf((float)v1[j], 0.f);
    }
  }
  {
    const bf16* sb = svkT + (size_t)img * 16384;
    for (int i = tid; i < 2048; i += 256)
      *(bf16x8*)(ssvk + i * 8) = *(const bf16x8*)(sb + i * 8);
    const float* db = dvec + (size_t)img * 512;
    for (int i = tid; i < 512; i += 256) sdv[i] = db[i];
  }
  __syncthreads();
  const int s = tid & 31, px = tid >> 5;
  const int shalf = s >> 4, sd = s & 15, d0 = sd * 2;
  const unsigned int* sv32 = (const unsigned int*)ssvk;
  bf16* ob = att + (size_t)(img * NPIX + px0 + px) * 512;
#pragma unroll
  for (int hh = 0; hh < 8; ++hh) {
    const int h = shalf * 8 + hh;
    const float* qp = &sq[px][h * 32];
    const unsigned int* kp = sv32 + h * 512 + sd;
    const float* dp = &sdv[h * 32];
    float a0 = 0.f, a1 = 0.f, den = 0.f;
#pragma unroll
    for (int ee = 0; ee < 32; ++ee) {
      const float qf = qp[ee];
      const unsigned int wv = kp[ee * 16];
      a0 = fmaf(qf, b2f_lo(wv), a0);
      a1 = fmaf(qf, b2f_hi(wv), a1);
      den = fmaf(qf, dp[ee], den);
    }
    const float inv = 1.f / (den + ATT_EPS);
    bf16x2 o; o[0] = (bf16)(a0 * inv); o[1] = (bf16)(a1 * inv);
    *(bf16x2*)(ob + h * 32 + d0) = o;
  }
}

// ---------------- depthwise 3x3 + bias + hswish (NHWC, 1024 ch) ----------------
__global__ __launch_bounds__(256)
void dw3_nhwc(const bf16* __restrict__ ein, const float* __restrict__ w3,
              const float* __restrict__ bias, bf16* __restrict__ dout) {
  const int idx = blockIdx.x * 256 + threadIdx.x;
  const int c8 = idx & 127;
  const int seg = idx >> 7;
  const int img = seg >> 8;
  const int p0 = (seg & 255) * 16;
  const int ch = c8 * 8;
  float wr_[9][8];
#pragma unroll
  for (int j = 0; j < 8; ++j)
#pragma unroll
    for (int q = 0; q < 9; ++q) wr_[q][j] = w3[(ch + j) * 9 + q];
  const f32x4 b0 = *(const f32x4*)(bias + ch), b1 = *(const f32x4*)(bias + ch + 4);
  const int row = p0 >> 6, col0 = p0 & 63;
  const bf16* ib = ein + (size_t)img * NPIX * 1024 + ch;
  bf16* ob = dout + (size_t)img * NPIX * 1024 + ch;
  for (int pp = 0; pp < 16; ++pp) {
    const int col = col0 + pp;
    float a[8] = {b0[0], b0[1], b0[2], b0[3], b1[0], b1[1], b1[2], b1[3]};
#pragma unroll
    for (int ky = 0; ky < 3; ++ky) {
      const int r = row + ky - 1;
      if (r < 0 || r > 63) continue;
#pragma unroll
      for (int kx = 0; kx < 3; ++kx) {
        const int cc = col + kx - 1;
        if (cc < 0 || cc > 63) continue;
        const bf16x8 v = *(const bf16x8*)(ib + (size_t)(r * 64 + cc) * 1024);
#pragma unroll
        for (int j = 0; j < 8; ++j) a[j] += wr_[ky * 3 + kx][j] * (float)v[j];
      }
    }
    bf16x8 o;
#pragma unroll
    for (int j = 0; j < 8; ++j) o[j] = (bf16)hswish_f(a[j]);
    *(bf16x8*)(ob + (size_t)(row * 64 + col) * 1024) = o;
  }
}

// ---------------- launch ----------------
extern "C" void kernel_launch(void* const* d_in, const int* in_sizes, int n_in,
                              void* d_out, int out_size, void* d_ws, size_t ws_size,
                              hipStream_t stream) {
  const float* x      = (const float*)d_in[0];
  const float* W_qkv  = (const float*)d_in[1];
  const float* W_dw5  = (const float*)d_in[2];
  const float* W_pw   = (const float*)d_in[3];
  const float* W_proj = (const float*)d_in[4];
  const float* g_proj = (const float*)d_in[5];
  const float* b_proj = (const float*)d_in[6];
  const float* W_e    = (const float*)d_in[7];
  const float* b_e    = (const float*)d_in[8];
  const float* W_dw3  = (const float*)d_in[9];
  const float* b_dw3  = (const float*)d_in[10];
  const float* W_p    = (const float*)d_in[11];
  const float* g_p    = (const float*)d_in[12];
  const float* b_p    = (const float*)d_in[13];
  float* out = (float*)d_out;

  int nb = 8;
  while (nb > 1) {
    size_t need = (size_t)nb * 23169024ull + 1703936ull + 1024;
    if (need <= ws_size) break;
    nb >>= 1;
  }

  char* p = (char*)d_ws;
  float* partial = (float*)p;                 p += (size_t)nb * 2162688;
  float* dvec    = (float*)p;                 p += (size_t)nb * 2048;
  bf16* wq_bf    = (bf16*)p;                  p += 196608ull * 2;
  bf16* wproj_bf = (bf16*)p;                  p += 131072ull * 2;
  bf16* we_bf    = (bf16*)p;                  p += 262144ull * 2;
  bf16* wp_bf    = (bf16*)p;                  p += 262144ull * 2;
  bf16* svkT     = (bf16*)p;                  p += (size_t)nb * 32768;
  bf16* arena    = (bf16*)p;
  bf16* xn   = arena;
  bf16* qkvb = arena + (size_t)nb * 1048576;
  bf16* agb  = qkvb + (size_t)nb * 3145728;
  bf16* attb = agb + (size_t)nb * 3145728;
  bf16* yb   = attb + (size_t)nb * 2097152;
  bf16* eb   = qkvb;
  bf16* db   = qkvb + (size_t)nb * 4194304;

  wqkv_perm<<<768, 256, 0, stream>>>(W_qkv, wq_bf);
  wcvt3<<<2560, 256, 0, stream>>>(W_proj, W_e, W_p, wproj_bf, we_bf, wp_bf);

  for (int b0 = 0; b0 < 8; b0 += nb) {
    const float* x_c = x + (size_t)b0 * 256 * NPIX;
    float* out_c = out + (size_t)b0 * 256 * NPIX;

    x_to_nhwc<<<dim3(64, 8, nb), 256, 0, stream>>>(x_c, xn);
    mfma_gemm<0><<<dim3(32, 6, nb), 256, 0, stream>>>(wq_bf, xn, qkvb, nullptr,
                                                      768, 256, nullptr, nullptr, nullptr);
    dw5pw_nhwc<<<dim3(16, 24, nb), 512, 0, stream>>>(qkvb, W_dw5, W_pw, agb);
    vk_part<<<dim3(32, 2, nb), 256, 0, stream>>>(qkvb, agb, partial);
    vk_reduce<<<nb * 16, 256, 0, stream>>>(partial, svkT, dvec);
    att_pix<<<dim3(512, 1, nb), 256, 0, stream>>>(qkvb, agb, svkT, dvec, attb);
    mfma_gemm<1><<<dim3(32, 2, nb), 256, 0, stream>>>(wproj_bf, attb, yb, nullptr,
                                                      256, 512, g_proj, b_proj, xn);
    mfma_gemm<2><<<dim3(32, 8, nb), 256, 0, stream>>>(we_bf, yb, eb, nullptr,
                                                      1024, 256, b_e, nullptr, nullptr);
    dw3_nhwc<<<nb * 128, 256, 0, stream>>>(eb, W_dw3, b_dw3, db);
    mfma_gemm<3><<<dim3(32, 2, nb), 256, 0, stream>>>(wp_bf, db, nullptr, out_c,
                                                      256, 1024, g_p, b_p, yb);
  }
}

// Round 8
// 365.325 us; speedup vs baseline: 3.6778x; 1.1094x over previous
//
#include <hip/hip_runtime.h>

typedef __bf16 bf16;
typedef __attribute__((ext_vector_type(8))) __bf16 bf16x8;
typedef __attribute__((ext_vector_type(4))) __bf16 bf16x4;
typedef __attribute__((ext_vector_type(2))) __bf16 bf16x2;
typedef __attribute__((ext_vector_type(4))) float f32x4;
typedef __attribute__((ext_vector_type(2))) float f32x2;

static constexpr int NPIX = 4096;                    // 64*64
static constexpr float BN_SC = 0.9999950000374997f;  // 1/sqrt(1+1e-5)
static constexpr float ATT_EPS = 1e-15f;

__device__ __forceinline__ float hswish_f(float v) {
  return v * fminf(fmaxf(v + 3.0f, 0.0f), 6.0f) * (1.0f / 6.0f);
}

__device__ __forceinline__ void gload16(const void* g, void* l) {
  __builtin_amdgcn_global_load_lds(
      (const __attribute__((address_space(1))) unsigned int*)g,
      (__attribute__((address_space(3))) unsigned int*)l, 16, 0, 0);
}

__device__ __forceinline__ float b2f_lo(unsigned int u) {
  union { unsigned int i; float f; } v; v.i = u << 16; return v.f;
}
__device__ __forceinline__ float b2f_hi(unsigned int u) {
  union { unsigned int i; float f; } v; v.i = u & 0xffff0000u; return v.f;
}
__device__ __forceinline__ unsigned short f2b_u(float f) {
  union { float f; unsigned int i; } v; v.f = f;
  unsigned int r = v.i + 0x7FFFu + ((v.i >> 16) & 1u);
  return (unsigned short)(r >> 16);
}
// relu on 2 packed bf16 in a u32: zero each 16-bit half whose sign bit is set
__device__ __forceinline__ unsigned int relu2(unsigned int v) {
  const unsigned int s = v & 0x80008000u;
  const unsigned int m = (s >> 15) * 0xFFFFu;
  return v & ~m;
}

// ---------------- x (f32 NCHW) -> x_nhwc (bf16) ----------------
__global__ __launch_bounds__(256)
void x_to_nhwc(const float* __restrict__ x, bf16* __restrict__ xn) {
  __shared__ float t[32][65];
  const int img = blockIdx.z;
  const int n0 = blockIdx.x * 64, c0 = blockIdx.y * 32;
  const int tid = threadIdx.x;
  const float* xb = x + ((size_t)img * 256 + c0) * NPIX + n0;
  {
    const int col = tid & 63, r0 = tid >> 6;
#pragma unroll
    for (int i = 0; i < 8; ++i) {
      const int r = r0 + i * 4;
      t[r][col] = xb[(size_t)r * NPIX + col];
    }
  }
  __syncthreads();
  const int n = tid & 63, cq = tid >> 6;
  bf16x8 v;
#pragma unroll
  for (int j = 0; j < 8; ++j) v[j] = (bf16)t[cq * 8 + j][n];
  *(bf16x8*)(xn + ((size_t)img * NPIX + n0 + n) * 256 + c0 + cq * 8) = v;
}

// ---------------- merged f32 -> bf16 weight convert (proj | e | p) ----------------
__global__ void wcvt3(const float* __restrict__ W_proj, const float* __restrict__ W_e,
                      const float* __restrict__ W_p, bf16* __restrict__ o_proj,
                      bf16* __restrict__ o_e, bf16* __restrict__ o_p) {
  const int i = blockIdx.x * 256 + threadIdx.x;
  if (i < 131072) o_proj[i] = (bf16)W_proj[i];
  else if (i < 393216) o_e[i - 131072] = (bf16)W_e[i - 131072];
  else o_p[i - 393216] = (bf16)W_p[i - 393216];
}

// ---------------- W_qkv permuted convert: new row t*256+h*32+d <- old h*96+t*32+d --
__global__ void wqkv_perm(const float* __restrict__ w, bf16* __restrict__ o) {
  const int row = blockIdx.x;  // 0..767 (new index)
  const int t = row >> 8, r = row & 255, h = r >> 5, d = r & 31;
  const int oldrow = h * 96 + t * 32 + d;
  o[row * 256 + threadIdx.x] = (bf16)w[oldrow * 256 + threadIdx.x];
}

// ---------------- MFMA GEMM: D[m][n] = sum_k A[m][k] * B[n][k]  (both K-contig) ----
template<int EPI>
__global__ __launch_bounds__(256, 3)
void mfma_gemm(const bf16* __restrict__ A, const bf16* __restrict__ Bact,
               bf16* __restrict__ Yb, float* __restrict__ Yf,
               const int M, const int K,
               const float* __restrict__ p0, const float* __restrict__ p1,
               const bf16* __restrict__ res)
{
  __shared__ __attribute__((aligned(16))) char ldsA[16384];
  __shared__ __attribute__((aligned(16))) char ldsB[16384];
  const int img = blockIdx.z;
  const int n0 = blockIdx.x * 128;
  const int m0 = blockIdx.y * 128;
  const bf16* Bi = Bact + (size_t)img * NPIX * K;
  const int tid = threadIdx.x;
  const int w = tid >> 6, l = tid & 63;
  const int g = l >> 4, ln = l & 15;
  const int wr = w >> 1, wc = w & 1;
  const int lrow = l >> 3;                       // 0..7
  const int sofs = (((l & 7) ^ lrow) << 4);      // swizzled byte offset in row

  f32x4 acc[4][4];
#pragma unroll
  for (int i = 0; i < 4; ++i)
#pragma unroll
    for (int j = 0; j < 4; ++j) acc[i][j] = (f32x4){0.f, 0.f, 0.f, 0.f};

  const char* Abase = (const char*)(A + (size_t)m0 * K);
  const char* Bbase = (const char*)(Bi + (size_t)n0 * K);
  const size_t rowb = (size_t)K * 2;
  const int swz = (ln & 7) << 4;

  const int nk = K >> 6;
  for (int kt = 0; kt < nk; ++kt) {
    const int k0b = kt << 7;
#pragma unroll
    for (int i = 0; i < 4; ++i) {
      const int q = (w << 2) + i;
      const int r = q * 8 + lrow;
      gload16(Abase + (size_t)r * rowb + k0b + sofs, ldsA + q * 1024);
    }
#pragma unroll
    for (int i = 0; i < 4; ++i) {
      const int q = (w << 2) + i;
      const int r = q * 8 + lrow;
      gload16(Bbase + (size_t)r * rowb + k0b + sofs, ldsB + q * 1024);
    }
    __syncthreads();
#pragma unroll
    for (int kk = 0; kk < 2; ++kk) {
      bf16x8 av[4], bv[4];
#pragma unroll
      for (int f = 0; f < 4; ++f) {
        const int ra = wr * 64 + f * 16 + ln;
        const int rb = wc * 64 + f * 16 + ln;
        const int kb = kk * 64 + (g << 4);
        av[f] = *(const bf16x8*)(ldsA + ra * 128 + (kb ^ swz));
        bv[f] = *(const bf16x8*)(ldsB + rb * 128 + (kb ^ swz));
      }
#pragma unroll
      for (int fi = 0; fi < 4; ++fi)
#pragma unroll
        for (int fj = 0; fj < 4; ++fj)
          acc[fi][fj] = __builtin_amdgcn_mfma_f32_16x16x32_bf16(
              av[fi], bv[fj], acc[fi][fj], 0, 0, 0);
    }
    __syncthreads();
  }

#pragma unroll
  for (int fi = 0; fi < 4; ++fi) {
    const int m4 = m0 + wr * 64 + fi * 16 + g * 4;
    f32x4 P0 = {0.f, 0.f, 0.f, 0.f}, P1 = {0.f, 0.f, 0.f, 0.f};
    if (EPI == 1 || EPI == 3) { P0 = *(const f32x4*)(p0 + m4); P1 = *(const f32x4*)(p1 + m4); }
    if (EPI == 2) { P0 = *(const f32x4*)(p0 + m4); }
#pragma unroll
    for (int fj = 0; fj < 4; ++fj) {
      const int n = n0 + wc * 64 + fj * 16 + ln;
      if (EPI == 3) {
        const bf16x4 yr = *(const bf16x4*)(res + ((size_t)img * NPIX + n) * 256 + m4);
        float* op = Yf + ((size_t)img * 256 + m4) * NPIX + n;
#pragma unroll
        for (int r = 0; r < 4; ++r)
          op[(size_t)r * NPIX] = P0[r] * BN_SC * acc[fi][fj][r] + P1[r] + (float)yr[r];
      } else {
        bf16x4 sv;
        if (EPI == 0) {
#pragma unroll
          for (int r = 0; r < 4; ++r) sv[r] = (bf16)acc[fi][fj][r];
        } else if (EPI == 1) {
          const bf16x4 xr = *(const bf16x4*)(res + ((size_t)img * NPIX + n) * 256 + m4);
#pragma unroll
          for (int r = 0; r < 4; ++r)
            sv[r] = (bf16)(P0[r] * BN_SC * acc[fi][fj][r] + P1[r] + (float)xr[r]);
        } else {
#pragma unroll
          for (int r = 0; r < 4; ++r)
            sv[r] = (bf16)hswish_f(acc[fi][fj][r] + P0[r]);
        }
        *(bf16x4*)(Yb + ((size_t)img * NPIX + n) * M + m4) = sv;
      }
    }
  }
}

// ---------------- fused dw5x5 + per-group 32x32 pointwise (NHWC), v4 ----------------
__global__ __launch_bounds__(512)
void dw5pw_nhwc(const bf16* __restrict__ qkv, const float* __restrict__ W5,
                const float* __restrict__ Wpw, bf16* __restrict__ ag) {
  const int gch = blockIdx.y, img = blockIdx.z;
  const int t_ = gch >> 3, hh_ = gch & 7;
  const int n0 = blockIdx.x * 256;
  const int r0 = n0 >> 6;                        // first of 4 image rows
  __shared__ __attribute__((aligned(16))) unsigned int sInT[16 * 548];  // 35072 B
  __shared__ __attribute__((aligned(16))) unsigned int sS32[256 * 20];  // 20480 B
  __shared__ __attribute__((aligned(16))) bf16 sPw[32 * 32];            // 2048 B
  const int tid = threadIdx.x;
  for (int i = tid; i < 1024; i += 512) sPw[i] = (bf16)Wpw[(hh_ * 3 + t_) * 1024 + i];
  for (int i = tid; i < 2176; i += 512) {
    const int s = i & 3, hp = i >> 2;
    const int hr = hp / 68, hc = hp - hr * 68;
    const int gr = r0 + hr - 2, gc = hc - 2;
    uint4 vv = {0u, 0u, 0u, 0u};
    if (gr >= 0 && gr < 64 && gc >= 0 && gc < 64)
      vv = *(const uint4*)(qkv + ((size_t)img * NPIX + gr * 64 + gc) * 768 + gch * 32 + s * 8);
    unsigned int* rp = sInT + (s * 4) * 548 + hp;
    rp[0] = vv.x; rp[548] = vv.y; rp[1096] = vv.z; rp[1644] = vv.w;
  }
  const int ci = tid & 15;
  f32x2 w2[25];
  {
    const float* wp0 = W5 + (size_t)(hh_ * 96 + t_ * 32 + 2 * ci) * 25;
#pragma unroll
    for (int q = 0; q < 25; ++q) w2[q] = (f32x2){wp0[q], wp0[25 + q]};
  }
  __syncthreads();
  {
    const int pg = tid >> 4;
    const int p0 = pg * 8;
    const int prow = p0 >> 6, pcol = p0 & 63;
    f32x2 a2[8];
#pragma unroll
    for (int px = 0; px < 8; ++px) a2[px] = (f32x2){0.f, 0.f};
#pragma unroll
    for (int ky = 0; ky < 5; ++ky) {
      const unsigned int* wp = &sInT[ci * 548 + (prow + ky) * 68 + pcol];
      const uint4 qa = *(const uint4*)wp;
      const uint4 qb = *(const uint4*)(wp + 4);
      const uint4 qc = *(const uint4*)(wp + 8);
      const unsigned int win[12] = {qa.x, qa.y, qa.z, qa.w, qb.x, qb.y, qb.z, qb.w,
                                    qc.x, qc.y, qc.z, qc.w};
      f32x2 val[12];
#pragma unroll
      for (int j = 0; j < 12; ++j) val[j] = (f32x2){b2f_lo(win[j]), b2f_hi(win[j])};
#pragma unroll
      for (int px = 0; px < 8; ++px)
#pragma unroll
        for (int kx = 0; kx < 5; ++kx)
          a2[px] = val[px + kx] * w2[ky * 5 + kx] + a2[px];   // v_pk_fma_f32
    }
#pragma unroll
    for (int px = 0; px < 8; ++px) {
      const unsigned int pk = (unsigned int)f2b_u(a2[px][0]) | ((unsigned int)f2b_u(a2[px][1]) << 16);
      sS32[(p0 + px) * 20 + ci] = pk;
    }
  }
  __syncthreads();
  {
    const int w = tid >> 6, l = tid & 63;
    const int lg = l >> 4, ln = l & 15;
    f32x4 acc[2][2];
#pragma unroll
    for (int i = 0; i < 2; ++i)
#pragma unroll
      for (int j = 0; j < 2; ++j) acc[i][j] = (f32x4){0.f, 0.f, 0.f, 0.f};
    bf16x8 av[2], bv[2];
#pragma unroll
    for (int et = 0; et < 2; ++et)
      av[et] = *(const bf16x8*)((const char*)sPw + (et * 16 + ln) * 64 + lg * 16);
#pragma unroll
    for (int pt = 0; pt < 2; ++pt)
      bv[pt] = *(const bf16x8*)((const char*)sS32 + ((2 * w + pt) * 16 + ln) * 80 + lg * 16);
#pragma unroll
    for (int et = 0; et < 2; ++et)
#pragma unroll
      for (int pt = 0; pt < 2; ++pt)
        acc[et][pt] = __builtin_amdgcn_mfma_f32_16x16x32_bf16(av[et], bv[pt], acc[et][pt], 0, 0, 0);
#pragma unroll
    for (int et = 0; et < 2; ++et)
#pragma unroll
      for (int pt = 0; pt < 2; ++pt) {
        const int e0 = et * 16 + lg * 4;
        const int p = n0 + (2 * w + pt) * 16 + ln;
        bf16x4 sv;
#pragma unroll
        for (int r = 0; r < 4; ++r) sv[r] = (bf16)acc[et][pt][r];
        *(bf16x4*)(ag + ((size_t)img * NPIX + p) * 768 + gch * 32 + e0) = sv;
      }
  }
}

// ---------------- vk partial v2: per (chunk64, src, img); one head per thread ----
// partial[(img*2+src)*64+chunk][8h][33][32] f32
__global__ __launch_bounds__(256)
void vk_part(const bf16* __restrict__ qkv, const bf16* __restrict__ ag,
             float* __restrict__ partial) {
  const int chunk = blockIdx.x, src = blockIdx.y, img = blockIdx.z;
  const bf16* base = (src == 0 ? qkv : ag) + (size_t)img * NPIX * 768 + 256;
  __shared__ __attribute__((aligned(16))) char tile[32 * 1024];  // [32px][512ch u32-pairs]
  const int tid = threadIdx.x;
  const int h = tid >> 5;            // 0..7
  const int r5 = tid & 31;
  const int et = r5 & 3;             // e-oct: e-pairs et*4..et*4+3
  const int dq = r5 >> 2;            // d-quad: d = dq*4..dq*4+3
  const int spx = tid >> 3, sseg = tid & 7;
  f32x2 acc[4][4];                   // [d in quad][e-pair]
#pragma unroll
  for (int i = 0; i < 4; ++i)
#pragma unroll
    for (int j = 0; j < 4; ++j) acc[i][j] = (f32x2){0.f, 0.f};
  f32x2 dsum[4] = {(f32x2){0.f,0.f},(f32x2){0.f,0.f},(f32x2){0.f,0.f},(f32x2){0.f,0.f}};
  for (int sub = 0; sub < 2; ++sub) {
    __syncthreads();
    {
      const int px0 = chunk * 64 + sub * 32;
      const char* gp = (const char*)(base + (size_t)(px0 + spx) * 768) + sseg * 128;
      char* lp = tile + spx * 1024;
      const int swz = (spx & 7) << 4;
#pragma unroll
      for (int i = 0; i < 8; ++i) {
        uint4 v = *(const uint4*)(gp + i * 16);
        if (sseg < 4) {  // k half: apply relu once at staging
          v.x = relu2(v.x); v.y = relu2(v.y); v.z = relu2(v.z); v.w = relu2(v.w);
        }
        *(uint4*)(lp + ((sseg * 128 + i * 16) ^ swz)) = v;
      }
    }
    __syncthreads();
    for (int nn = 0; nn < 32; ++nn) {
      const char* row = tile + nn * 1024;
      const int swzn = (nn & 7) << 4;
      f32x2 kp[4];
#pragma unroll
      for (int j = 0; j < 4; ++j) {
        const unsigned int kk = *(const unsigned int*)(row + ((h * 64 + (et * 4 + j) * 4) ^ swzn));
        kp[j] = (f32x2){b2f_lo(kk), b2f_hi(kk)};
      }
      const unsigned int v0 = *(const unsigned int*)(row + ((512 + h * 64 + dq * 8) ^ swzn));
      const unsigned int v1 = *(const unsigned int*)(row + ((512 + h * 64 + dq * 8 + 4) ^ swzn));
      const float vd[4] = {b2f_lo(v0), b2f_hi(v0), b2f_lo(v1), b2f_hi(v1)};
#pragma unroll
      for (int i = 0; i < 4; ++i)
#pragma unroll
        for (int j = 0; j < 4; ++j)
          acc[i][j] = (f32x2){vd[i], vd[i]} * kp[j] + acc[i][j];   // v_pk_fma_f32
      if (dq == 0) {
#pragma unroll
        for (int j = 0; j < 4; ++j) dsum[j] = dsum[j] + kp[j];
      }
    }
  }
  float* pb = partial + ((size_t)((img * 2 + src) * 64 + chunk)) * 8448;
#pragma unroll
  for (int i = 0; i < 4; ++i) {
    const int d = dq * 4 + i;
#pragma unroll
    for (int j = 0; j < 4; ++j) {
      pb[h * 1056 + d * 32 + et * 8 + j * 2]     = acc[i][j][0];
      pb[h * 1056 + d * 32 + et * 8 + j * 2 + 1] = acc[i][j][1];
    }
  }
  if (dq == 0) {
#pragma unroll
    for (int j = 0; j < 4; ++j) {
      pb[h * 1056 + 1024 + et * 8 + j * 2]     = dsum[j][0];
      pb[h * 1056 + 1024 + et * 8 + j * 2 + 1] = dsum[j][1];
    }
  }
}

// ---------------- vk reduce: sum 64 chunk-partials ----------------
__global__ __launch_bounds__(256)
void vk_reduce(const float* __restrict__ partial, bf16* __restrict__ svkT,
               float* __restrict__ dvec) {
  const int h = blockIdx.x & 15, img = blockIdx.x >> 4;
  const int tid = threadIdx.x;
  const int e = tid & 31, dq = tid >> 5;
  const int src = h >> 3, hh = h & 7;
  const float* pb = partial + (size_t)((img * 2 + src) * 64) * 8448 + hh * 1056;
  float a[4] = {};
  for (int c = 0; c < 64; ++c) {
    const float* pc = pb + (size_t)c * 8448;
#pragma unroll
    for (int j = 0; j < 4; ++j) a[j] += pc[(dq * 4 + j) * 32 + e];
  }
  bf16x4 o;
#pragma unroll
  for (int j = 0; j < 4; ++j) o[j] = (bf16)a[j];
  *(bf16x4*)(svkT + (((size_t)img * 16 + h) * 32 + e) * 32 + dq * 4) = o;
  if (dq == 0) {
    float ds = 0.f;
    for (int c = 0; c < 64; ++c) ds += pb[(size_t)c * 8448 + 1024 + e];
    dvec[((size_t)img * 16 + h) * 32 + e] = ds;
  }
}

// ---------------- attention apply v2: 16 px per block, bf16-packed q ----------------
__global__ __launch_bounds__(256)
void att_pix(const bf16* __restrict__ qkv, const bf16* __restrict__ ag,
             const bf16* __restrict__ svkT, const float* __restrict__ dvec,
             bf16* __restrict__ att) {
  const int pc = blockIdx.x;      // 16 px each
  const int img = blockIdx.z;
  __shared__ __attribute__((aligned(16))) unsigned int squ[16][264];  // q ch-pairs (relu'd)
  __shared__ __attribute__((aligned(16))) bf16 ssvk[16 * 1024];       // [h][e][d]
  __shared__ float sdv[512];
  const int tid = threadIdx.x;
  const int px0 = pc * 16;
  const int px = tid >> 4, s = tid & 15;
  {
    const bf16* srcp = (s < 8 ? qkv : ag) + (size_t)(img * NPIX + px0 + px) * 768 + (s & 7) * 32;
#pragma unroll
    for (int i = 0; i < 4; ++i) {
      uint4 v = *(const uint4*)((const char*)srcp + i * 16);
      v.x = relu2(v.x); v.y = relu2(v.y); v.z = relu2(v.z); v.w = relu2(v.w);
      *(uint4*)&squ[px][s * 16 + i * 4] = v;
    }
  }
  {
    const bf16* sb = svkT + (size_t)img * 16384;
    for (int i = tid; i < 2048; i += 256)
      *(bf16x8*)(ssvk + i * 8) = *(const bf16x8*)(sb + i * 8);
    const float* db = dvec + (size_t)img * 512;
    for (int i = tid; i < 512; i += 256) sdv[i] = db[i];
  }
  __syncthreads();
  const int sd = s, d0 = sd * 2;
  const unsigned int* sv32 = (const unsigned int*)ssvk;
  bf16* ob = att + (size_t)(img * NPIX + px0 + px) * 512;
#pragma unroll
  for (int h = 0; h < 16; ++h) {
    const unsigned int* qp = &squ[px][h * 16];
    const unsigned int* kp = sv32 + h * 512 + sd;
    const float* dp = &sdv[h * 32];
    float a0 = 0.f, a1 = 0.f, den = 0.f;
#pragma unroll
    for (int e2 = 0; e2 < 16; ++e2) {
      const unsigned int qq = qp[e2];
      const float q0 = b2f_lo(qq), q1 = b2f_hi(qq);
      const unsigned int w0 = kp[(2 * e2) * 16];
      const unsigned int w1 = kp[(2 * e2 + 1) * 16];
      a0 = fmaf(q0, b2f_lo(w0), a0); a0 = fmaf(q1, b2f_lo(w1), a0);
      a1 = fmaf(q0, b2f_hi(w0), a1); a1 = fmaf(q1, b2f_hi(w1), a1);
      den = fmaf(q0, dp[2 * e2], den); den = fmaf(q1, dp[2 * e2 + 1], den);
    }
    const float inv = 1.f / (den + ATT_EPS);
    bf16x2 o; o[0] = (bf16)(a0 * inv); o[1] = (bf16)(a1 * inv);
    *(bf16x2*)(ob + h * 32 + d0) = o;
  }
}

// ---------------- depthwise 3x3 + bias + hswish (NHWC, 1024 ch) ----------------
__global__ __launch_bounds__(256)
void dw3_nhwc(const bf16* __restrict__ ein, const float* __restrict__ w3,
              const float* __restrict__ bias, bf16* __restrict__ dout) {
  const int idx = blockIdx.x * 256 + threadIdx.x;
  const int c8 = idx & 127;
  const int seg = idx >> 7;
  const int img = seg >> 8;
  const int p0 = (seg & 255) * 16;
  const int ch = c8 * 8;
  float wr_[9][8];
#pragma unroll
  for (int j = 0; j < 8; ++j)
#pragma unroll
    for (int q = 0; q < 9; ++q) wr_[q][j] = w3[(ch + j) * 9 + q];
  const f32x4 b0 = *(const f32x4*)(bias + ch), b1 = *(const f32x4*)(bias + ch + 4);
  const int row = p0 >> 6, col0 = p0 & 63;
  const bf16* ib = ein + (size_t)img * NPIX * 1024 + ch;
  bf16* ob = dout + (size_t)img * NPIX * 1024 + ch;
  for (int pp = 0; pp < 16; ++pp) {
    const int col = col0 + pp;
    float a[8] = {b0[0], b0[1], b0[2], b0[3], b1[0], b1[1], b1[2], b1[3]};
#pragma unroll
    for (int ky = 0; ky < 3; ++ky) {
      const int r = row + ky - 1;
      if (r < 0 || r > 63) continue;
#pragma unroll
      for (int kx = 0; kx < 3; ++kx) {
        const int cc = col + kx - 1;
        if (cc < 0 || cc > 63) continue;
        const bf16x8 v = *(const bf16x8*)(ib + (size_t)(r * 64 + cc) * 1024);
#pragma unroll
        for (int j = 0; j < 8; ++j) a[j] += wr_[ky * 3 + kx][j] * (float)v[j];
      }
    }
    bf16x8 o;
#pragma unroll
    for (int j = 0; j < 8; ++j) o[j] = (bf16)hswish_f(a[j]);
    *(bf16x8*)(ob + (size_t)(row * 64 + col) * 1024) = o;
  }
}

// ---------------- launch ----------------
extern "C" void kernel_launch(void* const* d_in, const int* in_sizes, int n_in,
                              void* d_out, int out_size, void* d_ws, size_t ws_size,
                              hipStream_t stream) {
  const float* x      = (const float*)d_in[0];
  const float* W_qkv  = (const float*)d_in[1];
  const float* W_dw5  = (const float*)d_in[2];
  const float* W_pw   = (const float*)d_in[3];
  const float* W_proj = (const float*)d_in[4];
  const float* g_proj = (const float*)d_in[5];
  const float* b_proj = (const float*)d_in[6];
  const float* W_e    = (const float*)d_in[7];
  const float* b_e    = (const float*)d_in[8];
  const float* W_dw3  = (const float*)d_in[9];
  const float* b_dw3  = (const float*)d_in[10];
  const float* W_p    = (const float*)d_in[11];
  const float* g_p    = (const float*)d_in[12];
  const float* b_p    = (const float*)d_in[13];
  float* out = (float*)d_out;

  int nb = 8;
  while (nb > 1) {
    size_t need = (size_t)nb * 25331712ull + 1703936ull + 1024;
    if (need <= ws_size) break;
    nb >>= 1;
  }

  char* p = (char*)d_ws;
  float* partial = (float*)p;                 p += (size_t)nb * 4325376;   // nb*2*64*8448 f32
  float* dvec    = (float*)p;                 p += (size_t)nb * 2048;
  bf16* wq_bf    = (bf16*)p;                  p += 196608ull * 2;
  bf16* wproj_bf = (bf16*)p;                  p += 131072ull * 2;
  bf16* we_bf    = (bf16*)p;                  p += 262144ull * 2;
  bf16* wp_bf    = (bf16*)p;                  p += 262144ull * 2;
  bf16* svkT     = (bf16*)p;                  p += (size_t)nb * 32768;
  bf16* arena    = (bf16*)p;
  bf16* xn   = arena;
  bf16* qkvb = arena + (size_t)nb * 1048576;
  bf16* agb  = qkvb + (size_t)nb * 3145728;
  bf16* attb = agb + (size_t)nb * 3145728;
  bf16* yb   = attb + (size_t)nb * 2097152;
  bf16* eb   = qkvb;
  bf16* db   = qkvb + (size_t)nb * 4194304;

  wqkv_perm<<<768, 256, 0, stream>>>(W_qkv, wq_bf);
  wcvt3<<<2560, 256, 0, stream>>>(W_proj, W_e, W_p, wproj_bf, we_bf, wp_bf);

  for (int b0 = 0; b0 < 8; b0 += nb) {
    const float* x_c = x + (size_t)b0 * 256 * NPIX;
    float* out_c = out + (size_t)b0 * 256 * NPIX;

    x_to_nhwc<<<dim3(64, 8, nb), 256, 0, stream>>>(x_c, xn);
    mfma_gemm<0><<<dim3(32, 6, nb), 256, 0, stream>>>(wq_bf, xn, qkvb, nullptr,
                                                      768, 256, nullptr, nullptr, nullptr);
    dw5pw_nhwc<<<dim3(16, 24, nb), 512, 0, stream>>>(qkvb, W_dw5, W_pw, agb);
    vk_part<<<dim3(64, 2, nb), 256, 0, stream>>>(qkvb, agb, partial);
    vk_reduce<<<nb * 16, 256, 0, stream>>>(partial, svkT, dvec);
    att_pix<<<dim3(256, 1, nb), 256, 0, stream>>>(qkvb, agb, svkT, dvec, attb);
    mfma_gemm<1><<<dim3(32, 2, nb), 256, 0, stream>>>(wproj_bf, attb, yb, nullptr,
                                                      256, 512, g_proj, b_proj, xn);
    mfma_gemm<2><<<dim3(32, 8, nb), 256, 0, stream>>>(we_bf, yb, eb, nullptr,
                                                      1024, 256, b_e, nullptr, nullptr);
    dw3_nhwc<<<nb * 128, 256, 0, stream>>>(eb, W_dw3, b_dw3, db);
    mfma_gemm<3><<<dim3(32, 2, nb), 256, 0, stream>>>(wp_bf, db, nullptr, out_c,
                                                      256, 1024, g_p, b_p, yb);
  }
}

// Round 9
// 360.600 us; speedup vs baseline: 3.7260x; 1.0131x over previous
//
#include <hip/hip_runtime.h>

typedef __bf16 bf16;
typedef __attribute__((ext_vector_type(8))) __bf16 bf16x8;
typedef __attribute__((ext_vector_type(4))) __bf16 bf16x4;
typedef __attribute__((ext_vector_type(2))) __bf16 bf16x2;
typedef __attribute__((ext_vector_type(4))) float f32x4;
typedef __attribute__((ext_vector_type(2))) float f32x2;

static constexpr int NPIX = 4096;                    // 64*64
static constexpr float BN_SC = 0.9999950000374997f;  // 1/sqrt(1+1e-5)
static constexpr float ATT_EPS = 1e-15f;

__device__ __forceinline__ float hswish_f(float v) {
  return v * fminf(fmaxf(v + 3.0f, 0.0f), 6.0f) * (1.0f / 6.0f);
}

__device__ __forceinline__ void gload16(const void* g, void* l) {
  __builtin_amdgcn_global_load_lds(
      (const __attribute__((address_space(1))) unsigned int*)g,
      (__attribute__((address_space(3))) unsigned int*)l, 16, 0, 0);
}

__device__ __forceinline__ float b2f_lo(unsigned int u) {
  union { unsigned int i; float f; } v; v.i = u << 16; return v.f;
}
__device__ __forceinline__ float b2f_hi(unsigned int u) {
  union { unsigned int i; float f; } v; v.i = u & 0xffff0000u; return v.f;
}
__device__ __forceinline__ unsigned short f2b_u(float f) {
  union { float f; unsigned int i; } v; v.f = f;
  unsigned int r = v.i + 0x7FFFu + ((v.i >> 16) & 1u);
  return (unsigned short)(r >> 16);
}
// relu on 2 packed bf16 in a u32: zero each 16-bit half whose sign bit is set
__device__ __forceinline__ unsigned int relu2(unsigned int v) {
  const unsigned int s = v & 0x80008000u;
  const unsigned int m = (s >> 15) * 0xFFFFu;
  return v & ~m;
}

// ---------------- x (f32 NCHW) -> x_nhwc (bf16) ----------------
__global__ __launch_bounds__(256)
void x_to_nhwc(const float* __restrict__ x, bf16* __restrict__ xn) {
  __shared__ float t[32][65];
  const int img = blockIdx.z;
  const int n0 = blockIdx.x * 64, c0 = blockIdx.y * 32;
  const int tid = threadIdx.x;
  const float* xb = x + ((size_t)img * 256 + c0) * NPIX + n0;
  {
    const int col = tid & 63, r0 = tid >> 6;
#pragma unroll
    for (int i = 0; i < 8; ++i) {
      const int r = r0 + i * 4;
      t[r][col] = xb[(size_t)r * NPIX + col];
    }
  }
  __syncthreads();
  const int n = tid & 63, cq = tid >> 6;
  bf16x8 v;
#pragma unroll
  for (int j = 0; j < 8; ++j) v[j] = (bf16)t[cq * 8 + j][n];
  *(bf16x8*)(xn + ((size_t)img * NPIX + n0 + n) * 256 + c0 + cq * 8) = v;
}

// ---------------- merged f32 -> bf16 weight convert (proj | e | p) ----------------
__global__ void wcvt3(const float* __restrict__ W_proj, const float* __restrict__ W_e,
                      const float* __restrict__ W_p, bf16* __restrict__ o_proj,
                      bf16* __restrict__ o_e, bf16* __restrict__ o_p) {
  const int i = blockIdx.x * 256 + threadIdx.x;
  if (i < 131072) o_proj[i] = (bf16)W_proj[i];
  else if (i < 393216) o_e[i - 131072] = (bf16)W_e[i - 131072];
  else o_p[i - 393216] = (bf16)W_p[i - 393216];
}

// ---------------- W_qkv permuted convert: new row t*256+h*32+d <- old h*96+t*32+d --
__global__ void wqkv_perm(const float* __restrict__ w, bf16* __restrict__ o) {
  const int row = blockIdx.x;  // 0..767 (new index)
  const int t = row >> 8, r = row & 255, h = r >> 5, d = r & 31;
  const int oldrow = h * 96 + t * 32 + d;
  o[row * 256 + threadIdx.x] = (bf16)w[oldrow * 256 + threadIdx.x];
}

// ---------------- MFMA GEMM: D[m][n] = sum_k A[m][k] * B[n][k]  (both K-contig) ----
template<int EPI>
__global__ __launch_bounds__(256, 3)
void mfma_gemm(const bf16* __restrict__ A, const bf16* __restrict__ Bact,
               bf16* __restrict__ Yb, float* __restrict__ Yf,
               const int M, const int K,
               const float* __restrict__ p0, const float* __restrict__ p1,
               const bf16* __restrict__ res)
{
  __shared__ __attribute__((aligned(16))) char ldsA[16384];
  __shared__ __attribute__((aligned(16))) char ldsB[16384];
  const int img = blockIdx.z;
  const int n0 = blockIdx.x * 128;
  const int m0 = blockIdx.y * 128;
  const bf16* Bi = Bact + (size_t)img * NPIX * K;
  const int tid = threadIdx.x;
  const int w = tid >> 6, l = tid & 63;
  const int g = l >> 4, ln = l & 15;
  const int wr = w >> 1, wc = w & 1;
  const int lrow = l >> 3;                       // 0..7
  const int sofs = (((l & 7) ^ lrow) << 4);      // swizzled byte offset in row

  f32x4 acc[4][4];
#pragma unroll
  for (int i = 0; i < 4; ++i)
#pragma unroll
    for (int j = 0; j < 4; ++j) acc[i][j] = (f32x4){0.f, 0.f, 0.f, 0.f};

  const char* Abase = (const char*)(A + (size_t)m0 * K);
  const char* Bbase = (const char*)(Bi + (size_t)n0 * K);
  const size_t rowb = (size_t)K * 2;
  const int swz = (ln & 7) << 4;

  const int nk = K >> 6;
  for (int kt = 0; kt < nk; ++kt) {
    const int k0b = kt << 7;
#pragma unroll
    for (int i = 0; i < 4; ++i) {
      const int q = (w << 2) + i;
      const int r = q * 8 + lrow;
      gload16(Abase + (size_t)r * rowb + k0b + sofs, ldsA + q * 1024);
    }
#pragma unroll
    for (int i = 0; i < 4; ++i) {
      const int q = (w << 2) + i;
      const int r = q * 8 + lrow;
      gload16(Bbase + (size_t)r * rowb + k0b + sofs, ldsB + q * 1024);
    }
    __syncthreads();
#pragma unroll
    for (int kk = 0; kk < 2; ++kk) {
      bf16x8 av[4], bv[4];
#pragma unroll
      for (int f = 0; f < 4; ++f) {
        const int ra = wr * 64 + f * 16 + ln;
        const int rb = wc * 64 + f * 16 + ln;
        const int kb = kk * 64 + (g << 4);
        av[f] = *(const bf16x8*)(ldsA + ra * 128 + (kb ^ swz));
        bv[f] = *(const bf16x8*)(ldsB + rb * 128 + (kb ^ swz));
      }
#pragma unroll
      for (int fi = 0; fi < 4; ++fi)
#pragma unroll
        for (int fj = 0; fj < 4; ++fj)
          acc[fi][fj] = __builtin_amdgcn_mfma_f32_16x16x32_bf16(
              av[fi], bv[fj], acc[fi][fj], 0, 0, 0);
    }
    __syncthreads();
  }

#pragma unroll
  for (int fi = 0; fi < 4; ++fi) {
    const int m4 = m0 + wr * 64 + fi * 16 + g * 4;
    f32x4 P0 = {0.f, 0.f, 0.f, 0.f}, P1 = {0.f, 0.f, 0.f, 0.f};
    if (EPI == 1 || EPI == 3) { P0 = *(const f32x4*)(p0 + m4); P1 = *(const f32x4*)(p1 + m4); }
    if (EPI == 2) { P0 = *(const f32x4*)(p0 + m4); }
#pragma unroll
    for (int fj = 0; fj < 4; ++fj) {
      const int n = n0 + wc * 64 + fj * 16 + ln;
      if (EPI == 3) {
        const bf16x4 yr = *(const bf16x4*)(res + ((size_t)img * NPIX + n) * 256 + m4);
        float* op = Yf + ((size_t)img * 256 + m4) * NPIX + n;
#pragma unroll
        for (int r = 0; r < 4; ++r)
          op[(size_t)r * NPIX] = P0[r] * BN_SC * acc[fi][fj][r] + P1[r] + (float)yr[r];
      } else {
        bf16x4 sv;
        if (EPI == 0) {
#pragma unroll
          for (int r = 0; r < 4; ++r) sv[r] = (bf16)acc[fi][fj][r];
        } else if (EPI == 1) {
          const bf16x4 xr = *(const bf16x4*)(res + ((size_t)img * NPIX + n) * 256 + m4);
#pragma unroll
          for (int r = 0; r < 4; ++r)
            sv[r] = (bf16)(P0[r] * BN_SC * acc[fi][fj][r] + P1[r] + (float)xr[r]);
        } else {
#pragma unroll
          for (int r = 0; r < 4; ++r)
            sv[r] = (bf16)hswish_f(acc[fi][fj][r] + P0[r]);
        }
        *(bf16x4*)(Yb + ((size_t)img * NPIX + n) * M + m4) = sv;
      }
    }
  }
}

// ---------------- fused dw5x5 + per-group 32x32 pointwise (NHWC), v4 ----------------
__global__ __launch_bounds__(512)
void dw5pw_nhwc(const bf16* __restrict__ qkv, const float* __restrict__ W5,
                const float* __restrict__ Wpw, bf16* __restrict__ ag) {
  const int gch = blockIdx.y, img = blockIdx.z;
  const int t_ = gch >> 3, hh_ = gch & 7;
  const int n0 = blockIdx.x * 256;
  const int r0 = n0 >> 6;                        // first of 4 image rows
  __shared__ __attribute__((aligned(16))) unsigned int sInT[16 * 548];  // 35072 B
  __shared__ __attribute__((aligned(16))) unsigned int sS32[256 * 20];  // 20480 B
  __shared__ __attribute__((aligned(16))) bf16 sPw[32 * 32];            // 2048 B
  const int tid = threadIdx.x;
  for (int i = tid; i < 1024; i += 512) sPw[i] = (bf16)Wpw[(hh_ * 3 + t_) * 1024 + i];
  for (int i = tid; i < 2176; i += 512) {
    const int s = i & 3, hp = i >> 2;
    const int hr = hp / 68, hc = hp - hr * 68;
    const int gr = r0 + hr - 2, gc = hc - 2;
    uint4 vv = {0u, 0u, 0u, 0u};
    if (gr >= 0 && gr < 64 && gc >= 0 && gc < 64)
      vv = *(const uint4*)(qkv + ((size_t)img * NPIX + gr * 64 + gc) * 768 + gch * 32 + s * 8);
    unsigned int* rp = sInT + (s * 4) * 548 + hp;
    rp[0] = vv.x; rp[548] = vv.y; rp[1096] = vv.z; rp[1644] = vv.w;
  }
  const int ci = tid & 15;
  f32x2 w2[25];
  {
    const float* wp0 = W5 + (size_t)(hh_ * 96 + t_ * 32 + 2 * ci) * 25;
#pragma unroll
    for (int q = 0; q < 25; ++q) w2[q] = (f32x2){wp0[q], wp0[25 + q]};
  }
  __syncthreads();
  {
    const int pg = tid >> 4;
    const int p0 = pg * 8;
    const int prow = p0 >> 6, pcol = p0 & 63;
    f32x2 a2[8];
#pragma unroll
    for (int px = 0; px < 8; ++px) a2[px] = (f32x2){0.f, 0.f};
#pragma unroll
    for (int ky = 0; ky < 5; ++ky) {
      const unsigned int* wp = &sInT[ci * 548 + (prow + ky) * 68 + pcol];
      const uint4 qa = *(const uint4*)wp;
      const uint4 qb = *(const uint4*)(wp + 4);
      const uint4 qc = *(const uint4*)(wp + 8);
      const unsigned int win[12] = {qa.x, qa.y, qa.z, qa.w, qb.x, qb.y, qb.z, qb.w,
                                    qc.x, qc.y, qc.z, qc.w};
      f32x2 val[12];
#pragma unroll
      for (int j = 0; j < 12; ++j) val[j] = (f32x2){b2f_lo(win[j]), b2f_hi(win[j])};
#pragma unroll
      for (int px = 0; px < 8; ++px)
#pragma unroll
        for (int kx = 0; kx < 5; ++kx)
          a2[px] = val[px + kx] * w2[ky * 5 + kx] + a2[px];   // v_pk_fma_f32
    }
#pragma unroll
    for (int px = 0; px < 8; ++px) {
      const unsigned int pk = (unsigned int)f2b_u(a2[px][0]) | ((unsigned int)f2b_u(a2[px][1]) << 16);
      sS32[(p0 + px) * 20 + ci] = pk;
    }
  }
  __syncthreads();
  {
    const int w = tid >> 6, l = tid & 63;
    const int lg = l >> 4, ln = l & 15;
    f32x4 acc[2][2];
#pragma unroll
    for (int i = 0; i < 2; ++i)
#pragma unroll
      for (int j = 0; j < 2; ++j) acc[i][j] = (f32x4){0.f, 0.f, 0.f, 0.f};
    bf16x8 av[2], bv[2];
#pragma unroll
    for (int et = 0; et < 2; ++et)
      av[et] = *(const bf16x8*)((const char*)sPw + (et * 16 + ln) * 64 + lg * 16);
#pragma unroll
    for (int pt = 0; pt < 2; ++pt)
      bv[pt] = *(const bf16x8*)((const char*)sS32 + ((2 * w + pt) * 16 + ln) * 80 + lg * 16);
#pragma unroll
    for (int et = 0; et < 2; ++et)
#pragma unroll
      for (int pt = 0; pt < 2; ++pt)
        acc[et][pt] = __builtin_amdgcn_mfma_f32_16x16x32_bf16(av[et], bv[pt], acc[et][pt], 0, 0, 0);
#pragma unroll
    for (int et = 0; et < 2; ++et)
#pragma unroll
      for (int pt = 0; pt < 2; ++pt) {
        const int e0 = et * 16 + lg * 4;
        const int p = n0 + (2 * w + pt) * 16 + ln;
        bf16x4 sv;
#pragma unroll
        for (int r = 0; r < 4; ++r) sv[r] = (bf16)acc[et][pt][r];
        *(bf16x4*)(ag + ((size_t)img * NPIX + p) * 768 + gch * 32 + e0) = sv;
      }
  }
}

// ---------------- vk partial v2: per (chunk64, src, img); one head per thread ----
__global__ __launch_bounds__(256)
void vk_part(const bf16* __restrict__ qkv, const bf16* __restrict__ ag,
             float* __restrict__ partial) {
  const int chunk = blockIdx.x, src = blockIdx.y, img = blockIdx.z;
  const bf16* base = (src == 0 ? qkv : ag) + (size_t)img * NPIX * 768 + 256;
  __shared__ __attribute__((aligned(16))) char tile[32 * 1024];
  const int tid = threadIdx.x;
  const int h = tid >> 5;            // 0..7
  const int r5 = tid & 31;
  const int et = r5 & 3;             // e-oct
  const int dq = r5 >> 2;            // d-quad
  const int spx = tid >> 3, sseg = tid & 7;
  f32x2 acc[4][4];
#pragma unroll
  for (int i = 0; i < 4; ++i)
#pragma unroll
    for (int j = 0; j < 4; ++j) acc[i][j] = (f32x2){0.f, 0.f};
  f32x2 dsum[4] = {(f32x2){0.f,0.f},(f32x2){0.f,0.f},(f32x2){0.f,0.f},(f32x2){0.f,0.f}};
  for (int sub = 0; sub < 2; ++sub) {
    __syncthreads();
    {
      const int px0 = chunk * 64 + sub * 32;
      const char* gp = (const char*)(base + (size_t)(px0 + spx) * 768) + sseg * 128;
      char* lp = tile + spx * 1024;
      const int swz = (spx & 7) << 4;
#pragma unroll
      for (int i = 0; i < 8; ++i) {
        uint4 v = *(const uint4*)(gp + i * 16);
        if (sseg < 4) {
          v.x = relu2(v.x); v.y = relu2(v.y); v.z = relu2(v.z); v.w = relu2(v.w);
        }
        *(uint4*)(lp + ((sseg * 128 + i * 16) ^ swz)) = v;
      }
    }
    __syncthreads();
    for (int nn = 0; nn < 32; ++nn) {
      const char* row = tile + nn * 1024;
      const int swzn = (nn & 7) << 4;
      f32x2 kp[4];
#pragma unroll
      for (int j = 0; j < 4; ++j) {
        const unsigned int kk = *(const unsigned int*)(row + ((h * 64 + (et * 4 + j) * 4) ^ swzn));
        kp[j] = (f32x2){b2f_lo(kk), b2f_hi(kk)};
      }
      const unsigned int v0 = *(const unsigned int*)(row + ((512 + h * 64 + dq * 8) ^ swzn));
      const unsigned int v1 = *(const unsigned int*)(row + ((512 + h * 64 + dq * 8 + 4) ^ swzn));
      const float vd[4] = {b2f_lo(v0), b2f_hi(v0), b2f_lo(v1), b2f_hi(v1)};
#pragma unroll
      for (int i = 0; i < 4; ++i)
#pragma unroll
        for (int j = 0; j < 4; ++j)
          acc[i][j] = (f32x2){vd[i], vd[i]} * kp[j] + acc[i][j];   // v_pk_fma_f32
      if (dq == 0) {
#pragma unroll
        for (int j = 0; j < 4; ++j) dsum[j] = dsum[j] + kp[j];
      }
    }
  }
  float* pb = partial + ((size_t)((img * 2 + src) * 64 + chunk)) * 8448;
#pragma unroll
  for (int i = 0; i < 4; ++i) {
    const int d = dq * 4 + i;
#pragma unroll
    for (int j = 0; j < 4; ++j) {
      pb[h * 1056 + d * 32 + et * 8 + j * 2]     = acc[i][j][0];
      pb[h * 1056 + d * 32 + et * 8 + j * 2 + 1] = acc[i][j][1];
    }
  }
  if (dq == 0) {
#pragma unroll
    for (int j = 0; j < 4; ++j) {
      pb[h * 1056 + 1024 + et * 8 + j * 2]     = dsum[j][0];
      pb[h * 1056 + 1024 + et * 8 + j * 2 + 1] = dsum[j][1];
    }
  }
}

// ---------------- vk reduce: sum 64 chunk-partials ----------------
__global__ __launch_bounds__(256)
void vk_reduce(const float* __restrict__ partial, bf16* __restrict__ svkT,
               float* __restrict__ dvec) {
  const int h = blockIdx.x & 15, img = blockIdx.x >> 4;
  const int tid = threadIdx.x;
  const int e = tid & 31, dq = tid >> 5;
  const int src = h >> 3, hh = h & 7;
  const float* pb = partial + (size_t)((img * 2 + src) * 64) * 8448 + hh * 1056;
  float a[4] = {};
  for (int c = 0; c < 64; ++c) {
    const float* pc = pb + (size_t)c * 8448;
#pragma unroll
    for (int j = 0; j < 4; ++j) a[j] += pc[(dq * 4 + j) * 32 + e];
  }
  bf16x4 o;
#pragma unroll
  for (int j = 0; j < 4; ++j) o[j] = (bf16)a[j];
  *(bf16x4*)(svkT + (((size_t)img * 16 + h) * 32 + e) * 32 + dq * 4) = o;
  if (dq == 0) {
    float ds = 0.f;
    for (int c = 0; c < 64; ++c) ds += pb[(size_t)c * 8448 + 1024 + e];
    dvec[((size_t)img * 16 + h) * 32 + e] = ds;
  }
}

// ---------------- attention apply v2: 16 px per block, bf16-packed q ----------------
__global__ __launch_bounds__(256)
void att_pix(const bf16* __restrict__ qkv, const bf16* __restrict__ ag,
             const bf16* __restrict__ svkT, const float* __restrict__ dvec,
             bf16* __restrict__ att) {
  const int pc = blockIdx.x;      // 16 px each
  const int img = blockIdx.z;
  __shared__ __attribute__((aligned(16))) unsigned int squ[16][264];
  __shared__ __attribute__((aligned(16))) bf16 ssvk[16 * 1024];
  __shared__ float sdv[512];
  const int tid = threadIdx.x;
  const int px0 = pc * 16;
  const int px = tid >> 4, s = tid & 15;
  {
    const bf16* srcp = (s < 8 ? qkv : ag) + (size_t)(img * NPIX + px0 + px) * 768 + (s & 7) * 32;
#pragma unroll
    for (int i = 0; i < 4; ++i) {
      uint4 v = *(const uint4*)((const char*)srcp + i * 16);
      v.x = relu2(v.x); v.y = relu2(v.y); v.z = relu2(v.z); v.w = relu2(v.w);
      *(uint4*)&squ[px][s * 16 + i * 4] = v;
    }
  }
  {
    const bf16* sb = svkT + (size_t)img * 16384;
    for (int i = tid; i < 2048; i += 256)
      *(bf16x8*)(ssvk + i * 8) = *(const bf16x8*)(sb + i * 8);
    const float* db = dvec + (size_t)img * 512;
    for (int i = tid; i < 512; i += 256) sdv[i] = db[i];
  }
  __syncthreads();
  const int sd = s, d0 = sd * 2;
  const unsigned int* sv32 = (const unsigned int*)ssvk;
  bf16* ob = att + (size_t)(img * NPIX + px0 + px) * 512;
#pragma unroll
  for (int h = 0; h < 16; ++h) {
    const unsigned int* qp = &squ[px][h * 16];
    const unsigned int* kp = sv32 + h * 512 + sd;
    const float* dp = &sdv[h * 32];
    float a0 = 0.f, a1 = 0.f, den = 0.f;
#pragma unroll
    for (int e2 = 0; e2 < 16; ++e2) {
      const unsigned int qq = qp[e2];
      const float q0 = b2f_lo(qq), q1 = b2f_hi(qq);
      const unsigned int w0 = kp[(2 * e2) * 16];
      const unsigned int w1 = kp[(2 * e2 + 1) * 16];
      a0 = fmaf(q0, b2f_lo(w0), a0); a0 = fmaf(q1, b2f_lo(w1), a0);
      a1 = fmaf(q0, b2f_hi(w0), a1); a1 = fmaf(q1, b2f_hi(w1), a1);
      den = fmaf(q0, dp[2 * e2], den); den = fmaf(q1, dp[2 * e2 + 1], den);
    }
    const float inv = 1.f / (den + ATT_EPS);
    bf16x2 o; o[0] = (bf16)(a0 * inv); o[1] = (bf16)(a1 * inv);
    *(bf16x2*)(ob + h * 32 + d0) = o;
  }
}

// ---------------- depthwise 3x3 + bias + hswish (NHWC), v2 register-rolling ----
// thread = (4 channels, 1 column); walks 16 rows keeping 3x3 window in registers.
#define DW3_LOADROW(r, sl)                                                     \
  {                                                                            \
    for (int cs = 0; cs < 3; ++cs) {                                           \
      const int cc = col + cs - 1;                                             \
      if ((unsigned)(r) < 64u && (unsigned)cc < 64u) {                         \
        const uint2 v = *(const uint2*)(ib + (size_t)((r) * 64 + cc) * 1024);  \
        rr[sl][cs][0] = (f32x2){b2f_lo(v.x), b2f_hi(v.x)};                     \
        rr[sl][cs][1] = (f32x2){b2f_lo(v.y), b2f_hi(v.y)};                     \
      } else {                                                                 \
        rr[sl][cs][0] = (f32x2){0.f, 0.f};                                     \
        rr[sl][cs][1] = (f32x2){0.f, 0.f};                                     \
      }                                                                        \
    }                                                                          \
  }

__global__ __launch_bounds__(256)
void dw3_nhwc(const bf16* __restrict__ ein, const float* __restrict__ w3,
              const float* __restrict__ bias, bf16* __restrict__ dout) {
  const int img = blockIdx.z;
  const int r0 = blockIdx.y * 16;          // row band
  const int col = blockIdx.x;              // 0..63
  const int tid = threadIdx.x;             // channel-quad 0..255
  const int ch = tid * 4;
  f32x2 wv[9][2];
#pragma unroll
  for (int p = 0; p < 2; ++p)
#pragma unroll
    for (int q = 0; q < 9; ++q)
      wv[q][p] = (f32x2){w3[(ch + 2 * p) * 9 + q], w3[(ch + 2 * p + 1) * 9 + q]};
  f32x2 bv[2];
  bv[0] = (f32x2){bias[ch], bias[ch + 1]};
  bv[1] = (f32x2){bias[ch + 2], bias[ch + 3]};
  const bf16* ib = ein + (size_t)img * NPIX * 1024 + ch;
  bf16* ob = dout + (size_t)img * NPIX * 1024 + ch;
  f32x2 rr[3][3][2];
  DW3_LOADROW(r0 - 1, 0);
  DW3_LOADROW(r0, 1);
#pragma unroll
  for (int i = 0; i < 16; ++i) {
    const int slm = i % 3, sl0 = (i + 1) % 3, slp = (i + 2) % 3;
    DW3_LOADROW(r0 + i + 1, slp);
    f32x2 a[2] = {bv[0], bv[1]};
#pragma unroll
    for (int kx = 0; kx < 3; ++kx)
#pragma unroll
      for (int p = 0; p < 2; ++p) {
        a[p] = rr[slm][kx][p] * wv[0 * 3 + kx][p] + a[p];
        a[p] = rr[sl0][kx][p] * wv[1 * 3 + kx][p] + a[p];
        a[p] = rr[slp][kx][p] * wv[2 * 3 + kx][p] + a[p];
      }
    uint2 o;
    o.x = (unsigned)f2b_u(hswish_f(a[0][0])) | ((unsigned)f2b_u(hswish_f(a[0][1])) << 16);
    o.y = (unsigned)f2b_u(hswish_f(a[1][0])) | ((unsigned)f2b_u(hswish_f(a[1][1])) << 16);
    *(uint2*)(ob + (size_t)((r0 + i) * 64 + col) * 1024) = o;
  }
}

// ---------------- launch ----------------
extern "C" void kernel_launch(void* const* d_in, const int* in_sizes, int n_in,
                              void* d_out, int out_size, void* d_ws, size_t ws_size,
                              hipStream_t stream) {
  const float* x      = (const float*)d_in[0];
  const float* W_qkv  = (const float*)d_in[1];
  const float* W_dw5  = (const float*)d_in[2];
  const float* W_pw   = (const float*)d_in[3];
  const float* W_proj = (const float*)d_in[4];
  const float* g_proj = (const float*)d_in[5];
  const float* b_proj = (const float*)d_in[6];
  const float* W_e    = (const float*)d_in[7];
  const float* b_e    = (const float*)d_in[8];
  const float* W_dw3  = (const float*)d_in[9];
  const float* b_dw3  = (const float*)d_in[10];
  const float* W_p    = (const float*)d_in[11];
  const float* g_p    = (const float*)d_in[12];
  const float* b_p    = (const float*)d_in[13];
  float* out = (float*)d_out;

  int nb = 8;
  while (nb > 1) {
    size_t need = (size_t)nb * 25331712ull + 1703936ull + 1024;
    if (need <= ws_size) break;
    nb >>= 1;
  }

  char* p = (char*)d_ws;
  float* partial = (float*)p;                 p += (size_t)nb * 4325376;
  float* dvec    = (float*)p;                 p += (size_t)nb * 2048;
  bf16* wq_bf    = (bf16*)p;                  p += 196608ull * 2;
  bf16* wproj_bf = (bf16*)p;                  p += 131072ull * 2;
  bf16* we_bf    = (bf16*)p;                  p += 262144ull * 2;
  bf16* wp_bf    = (bf16*)p;                  p += 262144ull * 2;
  bf16* svkT     = (bf16*)p;                  p += (size_t)nb * 32768;
  bf16* arena    = (bf16*)p;
  bf16* xn   = arena;
  bf16* qkvb = arena + (size_t)nb * 1048576;
  bf16* agb  = qkvb + (size_t)nb * 3145728;
  bf16* attb = agb + (size_t)nb * 3145728;
  bf16* yb   = attb + (size_t)nb * 2097152;
  bf16* eb   = qkvb;
  bf16* db   = qkvb + (size_t)nb * 4194304;

  wqkv_perm<<<768, 256, 0, stream>>>(W_qkv, wq_bf);
  wcvt3<<<2560, 256, 0, stream>>>(W_proj, W_e, W_p, wproj_bf, we_bf, wp_bf);

  for (int b0 = 0; b0 < 8; b0 += nb) {
    const float* x_c = x + (size_t)b0 * 256 * NPIX;
    float* out_c = out + (size_t)b0 * 256 * NPIX;

    x_to_nhwc<<<dim3(64, 8, nb), 256, 0, stream>>>(x_c, xn);
    mfma_gemm<0><<<dim3(32, 6, nb), 256, 0, stream>>>(wq_bf, xn, qkvb, nullptr,
                                                      768, 256, nullptr, nullptr, nullptr);
    dw5pw_nhwc<<<dim3(16, 24, nb), 512, 0, stream>>>(qkvb, W_dw5, W_pw, agb);
    vk_part<<<dim3(64, 2, nb), 256, 0, stream>>>(qkvb, agb, partial);
    vk_reduce<<<nb * 16, 256, 0, stream>>>(partial, svkT, dvec);
    att_pix<<<dim3(256, 1, nb), 256, 0, stream>>>(qkvb, agb, svkT, dvec, attb);
    mfma_gemm<1><<<dim3(32, 2, nb), 256, 0, stream>>>(wproj_bf, attb, yb, nullptr,
                                                      256, 512, g_proj, b_proj, xn);
    mfma_gemm<2><<<dim3(32, 8, nb), 256, 0, stream>>>(we_bf, yb, eb, nullptr,
                                                      1024, 256, b_e, nullptr, nullptr);
    dw3_nhwc<<<dim3(64, 4, nb), 256, 0, stream>>>(eb, W_dw3, b_dw3, db);
    mfma_gemm<3><<<dim3(32, 2, nb), 256, 0, stream>>>(wp_bf, db, nullptr, out_c,
                                                      256, 1024, g_p, b_p, yb);
  }
}